// Round 2
// baseline (3584.446 us; speedup 1.0000x reference)
//
#include <hip/hip_runtime.h>
#include <hip/hip_bf16.h>

typedef long long ll;

static inline int cdiv_ll(ll a, int b) { return (int)((a + (ll)b - 1) / (ll)b); }

// ---------------- dtype detection ----------------
// Samples dwords of user_feat. If data is bf16 pairs, the low 16 bits of each
// dword are a real bf16 value (exponent near bias). If data is fp32, the low
// 16 bits are random mantissa bits (uniform exponent byte -> mostly implausible).
__global__ void k_detect(const unsigned int* __restrict__ dw, const ll n_dw, int* __restrict__ flag) {
    __shared__ int sc[256];
    int tid = threadIdx.x;
    int cnt = 0;
    for (int s = 0; s < 32; s++) {
        ll idx = (ll)(s * 256 + tid);
        ll i = (idx * n_dw) / 8192;          // spread samples across the safe range
        unsigned v = dw[i];
        unsigned lo = v & 0xFFFFu;
        unsigned ex = (lo >> 7) & 0xFFu;
        bool pl = (lo == 0u) || (lo == 0x8000u) || (ex >= 0x60u && ex <= 0x8Fu);
        cnt += pl ? 1 : 0;
    }
    sc[tid] = cnt;
    __syncthreads();
    for (int o = 128; o > 0; o >>= 1) { if (tid < o) sc[tid] += sc[tid + o]; __syncthreads(); }
    if (tid == 0) *flag = (sc[0] * 2 > 8192) ? 1 : 0;   // >50% plausible => bf16
}

__device__ __forceinline__ float load_in(const void* p, ll i, int isbf16) {
    if (isbf16) return __bfloat162float(((const __hip_bfloat16*)p)[i]);
    return ((const float*)p)[i];
}

// ---------------- weight conversion (to fp32 ws) ----------------
__global__ void k_cvt(const void* __restrict__ src, float* __restrict__ dst, const int n,
                      const int* __restrict__ flag) {
    int i = blockIdx.x * blockDim.x + threadIdx.x;
    int bf = *flag;
    if (i < n) dst[i] = load_in(src, i, bf);
}

// ---------------- degree kernels ----------------
__global__ void k_deg1(const int* __restrict__ rows, const ll E, float* __restrict__ deg) {
    ll t = (ll)blockIdx.x * blockDim.x + threadIdx.x;
    if (t < E) atomicAdd(&deg[rows[t]], 1.0f);
}

__global__ void k_deg2(const int* __restrict__ src, const int* __restrict__ dst, const ll E,
                       float* __restrict__ dout, float* __restrict__ din) {
    ll t = (ll)blockIdx.x * blockDim.x + threadIdx.x;
    if (t < E) {
        atomicAdd(&dout[src[t]], 1.0f);
        atomicAdd(&din[dst[t]], 1.0f);
    }
}

// gcn_spmm norm: deg>0 ? 1/sqrt(deg) : 0
__global__ void k_fin_gcn(float* __restrict__ d, const int n) {
    int i = blockIdx.x * blockDim.x + threadIdx.x;
    if (i < n) { float v = d[i]; d[i] = (v > 0.0f) ? (1.0f / sqrtf(v)) : 0.0f; }
}

// GraphConv norm: 1/sqrt(max(deg,1))
__global__ void k_fin_conv(float* __restrict__ d, const int n) {
    int i = blockIdx.x * blockDim.x + threadIdx.x;
    if (i < n) d[i] = 1.0f / sqrtf(fmaxf(d[i], 1.0f));
}

// ---------------- init: -> f32, ui = concat(uf, itf), hu = uf, hi = itf ----
__global__ void k_init(const void* __restrict__ uf, const void* __restrict__ itf,
                       float* __restrict__ ui, float* __restrict__ hu, float* __restrict__ hi,
                       const ll nu64, const ll ntot64, const int* __restrict__ flag) {
    ll t = (ll)blockIdx.x * blockDim.x + threadIdx.x;
    int bf = *flag;
    if (t < nu64) {
        float v = load_in(uf, t, bf);
        ui[t] = v; hu[t] = v;
    } else if (t < ntot64) {
        ll j = t - nu64;
        float v = load_in(itf, j, bf);
        ui[t] = v; hi[j] = v;
    }
}

// ---------------- edge scatter: out[rows[e]] += x[cols[e]] * snorm[cols[e]] ----
__global__ void k_scatter(const int* __restrict__ rows, const int* __restrict__ cols, const ll E,
                          const float* __restrict__ x, const float* __restrict__ snorm,
                          float* __restrict__ out) {
    ll t = (ll)blockIdx.x * blockDim.x + threadIdx.x;
    ll e = t >> 6;
    int d = (int)(t & 63);
    if (e < E) {
        int r = rows[e], c = cols[e];
        atomicAdd(&out[(ll)r * 64 + d], x[(ll)c * 64 + d] * snorm[c]);
    }
}

// ---------------- row scale: out[v,:] *= s[v] ----------------
__global__ void k_scale(float* __restrict__ out, const float* __restrict__ s, const ll n64) {
    ll t = (ll)blockIdx.x * blockDim.x + threadIdx.x;
    if (t < n64) out[t] *= s[t >> 6];
}

// ---------------- semantic attention scores (fp32 weights from ws) ----------
__global__ __launch_bounds__(256) void k_attn(const float* __restrict__ z1, const float* __restrict__ z2,
                                              const float* __restrict__ W1,
                                              const float* __restrict__ b1,
                                              const float* __restrict__ w2,
                                              const int n, float* __restrict__ wsum) {
    __shared__ float W1t[64 * 128];   // transposed: [h][d]
    __shared__ float b1s[128];
    __shared__ float w2s[128];
    __shared__ float red0[4], red1[4];

    for (int i = threadIdx.x; i < 64 * 128; i += 256) {
        int d = i >> 7, h = i & 127;          // source layout W1[d*128+h]
        W1t[h * 64 + d] = W1[i];
    }
    if (threadIdx.x < 128) {
        b1s[threadIdx.x] = b1[threadIdx.x];
        w2s[threadIdx.x] = w2[threadIdx.x];
    }
    __syncthreads();

    int v = blockIdx.x * 256 + threadIdx.x;
    float w0 = 0.0f, w1 = 0.0f;
    if (v < n) {
        float4 zv[16];
        {
            const float4* zp = (const float4*)&z1[(ll)v * 64];
#pragma unroll
            for (int q = 0; q < 16; q++) zv[q] = zp[q];
            for (int h = 0; h < 128; h++) {
                float acc = b1s[h];
                const float4* wr = (const float4*)&W1t[h * 64];
#pragma unroll
                for (int q = 0; q < 16; q++) {
                    float4 wv = wr[q];
                    acc += zv[q].x * wv.x + zv[q].y * wv.y + zv[q].z * wv.z + zv[q].w * wv.w;
                }
                w0 += tanhf(acc) * w2s[h];
            }
        }
        {
            const float4* zp = (const float4*)&z2[(ll)v * 64];
#pragma unroll
            for (int q = 0; q < 16; q++) zv[q] = zp[q];
            for (int h = 0; h < 128; h++) {
                float acc = b1s[h];
                const float4* wr = (const float4*)&W1t[h * 64];
#pragma unroll
                for (int q = 0; q < 16; q++) {
                    float4 wv = wr[q];
                    acc += zv[q].x * wv.x + zv[q].y * wv.y + zv[q].z * wv.z + zv[q].w * wv.w;
                }
                w1 += tanhf(acc) * w2s[h];
            }
        }
    }
    for (int off = 32; off > 0; off >>= 1) {
        w0 += __shfl_down(w0, off);
        w1 += __shfl_down(w1, off);
    }
    int wave = threadIdx.x >> 6;
    int lane = threadIdx.x & 63;
    if (lane == 0) { red0[wave] = w0; red1[wave] = w1; }
    __syncthreads();
    if (threadIdx.x == 0) {
        float a = red0[0] + red0[1] + red0[2] + red0[3];
        float b = red1[0] + red1[1] + red1[2] + red1[3];
        atomicAdd(&wsum[0], a);
        atomicAdd(&wsum[1], b);
    }
}

// ---------------- beta = softmax(wsum / n) ----------------
__global__ void k_beta(const float* __restrict__ wsum, const float inv_n, float* __restrict__ beta) {
    if (blockIdx.x == 0 && threadIdx.x == 0) {
        float m0 = wsum[0] * inv_n, m1 = wsum[1] * inv_n;
        float mx = fmaxf(m0, m1);
        float e0 = expf(m0 - mx), e1 = expf(m1 - mx);
        float s = e0 + e1;
        beta[0] = e0 / s;
        beta[1] = e1 / s;
    }
}

// ---------------- combine: h = beta0*z1 + beta1*z2 ----------------
__global__ void k_combine(const float* __restrict__ z1, const float* __restrict__ z2,
                          const float* __restrict__ beta, float* __restrict__ h, const ll n64) {
    ll t = (ll)blockIdx.x * blockDim.x + threadIdx.x;
    if (t < n64) h[t] = beta[0] * z1[t] + beta[1] * z2[t];
}

// ---------------- final gathers (dtype-flexible output) ----------------
__device__ __forceinline__ void store_out(void* out, ll i, float v, int isbf16) {
    if (isbf16) ((__hip_bfloat16*)out)[i] = __float2bfloat16(v);
    else ((float*)out)[i] = v;
}
__device__ __forceinline__ float load_out(const void* out, ll i, int isbf16) {
    if (isbf16) return __bfloat162float(((const __hip_bfloat16*)out)[i]);
    return ((const float*)out)[i];
}

__global__ void k_out1(const float* __restrict__ hu, const float* __restrict__ hi,
                       const float* __restrict__ ui, const int* __restrict__ user_idx,
                       const int* __restrict__ item_idx, void* __restrict__ out,
                       const int B, const ll U, const int* __restrict__ flag) {
    ll t = (ll)blockIdx.x * blockDim.x + threadIdx.x;
    int bf = *flag;
    int d = (int)(t & 63);
    ll b = t >> 6;
    if (b < B) {
        int u = user_idx[b];
        float v = 0.5f * hu[(ll)u * 64 + d] + 0.5f * ui[(ll)u * 64 + d];
        store_out(out, b * 64 + d, v, bf);
    } else if (b < 2 * (ll)B) {
        ll bb = b - B;
        int it = item_idx[bb];
        float v = 0.5f * hi[(ll)it * 64 + d] + 0.5f * ui[(U + it) * 64 + d];
        store_out(out, (ll)B * 64 + bb * 64 + d, v, bf);
    }
}

__global__ void k_out2(void* __restrict__ out, const int* __restrict__ neg_idx, const int B,
                       const int* __restrict__ flag) {
    ll t = (ll)blockIdx.x * blockDim.x + threadIdx.x;
    int bf = *flag;
    if (t < (ll)B * 64) {
        ll b = t >> 6;
        int d = (int)(t & 63);
        int nb = neg_idx[b];
        float v = load_out(out, (ll)B * 64 + (ll)nb * 64 + d, bf);
        store_out(out, (ll)2 * B * 64 + t, v, bf);
    }
}

extern "C" void kernel_launch(void* const* d_in, const int* in_sizes, int n_in,
                              void* d_out, int out_size, void* d_ws, size_t ws_size,
                              hipStream_t stream) {
    const int D = 64;
    const ll U = in_sizes[0] / D;
    const ll I = in_sizes[1] / D;
    const ll N = U + I;
    const ll E2  = in_sizes[8] / 2;   // symmetrized ui edges
    const ll EU1 = in_sizes[9] / 2;
    const ll EU2 = in_sizes[10] / 2;
    const ll EI1 = in_sizes[11] / 2;
    const ll EI2 = in_sizes[12] / 2;
    const int B = in_sizes[13];

    const void* user_feat = d_in[0];
    const void* item_feat = d_in[1];
    const void* sa_u_W1 = d_in[2];
    const void* sa_u_b1 = d_in[3];
    const void* sa_u_w2 = d_in[4];
    const void* sa_i_W1 = d_in[5];
    const void* sa_i_b1 = d_in[6];
    const void* sa_i_w2 = d_in[7];
    const int* ui_e = (const int*)d_in[8];
    const int* ui_row = ui_e;
    const int* ui_col = ui_e + E2;
    const int* u1_src = (const int*)d_in[9];
    const int* u1_dst = u1_src + EU1;
    const int* u2_src = (const int*)d_in[10];
    const int* u2_dst = u2_src + EU2;
    const int* i1_src = (const int*)d_in[11];
    const int* i1_dst = i1_src + EI1;
    const int* i2_src = (const int*)d_in[12];
    const int* i2_dst = i2_src + EI2;
    const int* user_idx = (const int*)d_in[13];
    const int* item_idx = (const int*)d_in[14];
    const int* neg_idx  = (const int*)d_in[15];

    // ---------------- workspace layout (fp32) ----------------
    float* p = (float*)d_ws;
    float* ui0 = p;  p += N * 64;
    float* ui1 = p;  p += N * 64;
    float* hu  = p;  p += U * 64;
    float* hi  = p;  p += I * 64;
    float* z1  = p;  p += I * 64;   // user pass uses first U rows
    float* z2  = p;  p += I * 64;
    float* dinv = p; p += N;
    float* dconv = p;               // 8 contiguous GraphConv norm arrays
    float* su1o = p; p += U;  float* su1i = p; p += U;
    float* su2o = p; p += U;  float* su2i = p; p += U;
    float* si1o = p; p += I;  float* si1i = p; p += I;
    float* si2o = p; p += I;  float* si2i = p; p += I;
    float* wW1u = p; p += 64 * 128;
    float* wb1u = p; p += 128;
    float* ww2u = p; p += 128;
    float* wW1i = p; p += 64 * 128;
    float* wb1i = p; p += 128;
    float* ww2i = p; p += 128;
    float* scratch = p; p += 16;    // [0..1]=wsum, [2..3]=beta
    int* flag = (int*)(p); p += 4;
    size_t needed = (size_t)(p - (float*)d_ws) * sizeof(float);
    if (ws_size < needed) return;

    const int T = 256;

    // ---------------- dtype detection ----------------
    k_detect<<<1, 256, 0, stream>>>((const unsigned int*)user_feat, (ll)in_sizes[0] / 2, flag);

    // ---------------- weight conversion ----------------
    k_cvt<<<cdiv_ll(64 * 128, T), T, 0, stream>>>(sa_u_W1, wW1u, 64 * 128, flag);
    k_cvt<<<1, 128, 0, stream>>>(sa_u_b1, wb1u, 128, flag);
    k_cvt<<<1, 128, 0, stream>>>(sa_u_w2, ww2u, 128, flag);
    k_cvt<<<cdiv_ll(64 * 128, T), T, 0, stream>>>(sa_i_W1, wW1i, 64 * 128, flag);
    k_cvt<<<1, 128, 0, stream>>>(sa_i_b1, wb1i, 128, flag);
    k_cvt<<<1, 128, 0, stream>>>(sa_i_w2, ww2i, 128, flag);

    // ---------------- degrees ----------------
    hipMemsetAsync(dinv, 0, (size_t)(N + 4 * U + 4 * I) * sizeof(float), stream);
    hipMemsetAsync(scratch, 0, 16 * sizeof(float), stream);
    k_deg1<<<cdiv_ll(E2, T), T, 0, stream>>>(ui_row, E2, dinv);
    k_deg2<<<cdiv_ll(EU1, T), T, 0, stream>>>(u1_src, u1_dst, EU1, su1o, su1i);
    k_deg2<<<cdiv_ll(EU2, T), T, 0, stream>>>(u2_src, u2_dst, EU2, su2o, su2i);
    k_deg2<<<cdiv_ll(EI1, T), T, 0, stream>>>(i1_src, i1_dst, EI1, si1o, si1i);
    k_deg2<<<cdiv_ll(EI2, T), T, 0, stream>>>(i2_src, i2_dst, EI2, si2o, si2i);
    k_fin_gcn<<<cdiv_ll(N, T), T, 0, stream>>>(dinv, (int)N);
    k_fin_conv<<<cdiv_ll(4 * U + 4 * I, T), T, 0, stream>>>(dconv, (int)(4 * U + 4 * I));

    // ---------------- init features ----------------
    k_init<<<cdiv_ll(N * 64, T), T, 0, stream>>>(user_feat, item_feat, ui0, hu, hi, U * 64, N * 64, flag);

    float* uiA = ui0;
    float* uiB = ui1;

    for (int layer = 0; layer < 2; layer++) {
        // ---- gcn_spmm over bipartite graph ----
        hipMemsetAsync(uiB, 0, (size_t)N * 64 * sizeof(float), stream);
        k_scatter<<<cdiv_ll(E2 * 64, T), T, 0, stream>>>(ui_row, ui_col, E2, uiA, dinv, uiB);
        k_scale<<<cdiv_ll(N * 64, T), T, 0, stream>>>(uiB, dinv, N * 64);
        { float* tmp = uiA; uiA = uiB; uiB = tmp; }

        // ---- HAN layer: users ----
        hipMemsetAsync(z1, 0, (size_t)U * 64 * sizeof(float), stream);
        hipMemsetAsync(z2, 0, (size_t)U * 64 * sizeof(float), stream);
        k_scatter<<<cdiv_ll(EU1 * 64, T), T, 0, stream>>>(u1_dst, u1_src, EU1, hu, su1o, z1);
        k_scale<<<cdiv_ll(U * 64, T), T, 0, stream>>>(z1, su1i, U * 64);
        k_scatter<<<cdiv_ll(EU2 * 64, T), T, 0, stream>>>(u2_dst, u2_src, EU2, hu, su2o, z2);
        k_scale<<<cdiv_ll(U * 64, T), T, 0, stream>>>(z2, su2i, U * 64);
        hipMemsetAsync(scratch, 0, 2 * sizeof(float), stream);
        k_attn<<<cdiv_ll(U, T), T, 0, stream>>>(z1, z2, wW1u, wb1u, ww2u, (int)U, scratch);
        k_beta<<<1, 64, 0, stream>>>(scratch, 1.0f / (float)U, scratch + 2);
        k_combine<<<cdiv_ll(U * 64, T), T, 0, stream>>>(z1, z2, scratch + 2, hu, U * 64);

        // ---- HAN layer: items ----
        hipMemsetAsync(z1, 0, (size_t)I * 64 * sizeof(float), stream);
        hipMemsetAsync(z2, 0, (size_t)I * 64 * sizeof(float), stream);
        k_scatter<<<cdiv_ll(EI1 * 64, T), T, 0, stream>>>(i1_dst, i1_src, EI1, hi, si1o, z1);
        k_scale<<<cdiv_ll(I * 64, T), T, 0, stream>>>(z1, si1i, I * 64);
        k_scatter<<<cdiv_ll(EI2 * 64, T), T, 0, stream>>>(i2_dst, i2_src, EI2, hi, si2o, z2);
        k_scale<<<cdiv_ll(I * 64, T), T, 0, stream>>>(z2, si2i, I * 64);
        hipMemsetAsync(scratch, 0, 2 * sizeof(float), stream);
        k_attn<<<cdiv_ll(I, T), T, 0, stream>>>(z1, z2, wW1i, wb1i, ww2i, (int)I, scratch);
        k_beta<<<1, 64, 0, stream>>>(scratch, 1.0f / (float)I, scratch + 2);
        k_combine<<<cdiv_ll(I * 64, T), T, 0, stream>>>(z1, z2, scratch + 2, hi, I * 64);
    }

    // ---------------- final: 0.5*h + 0.5*ui, gathers ----------------
    k_out1<<<cdiv_ll((ll)2 * B * 64, T), T, 0, stream>>>(hu, hi, uiA, user_idx, item_idx, d_out, B, U, flag);
    k_out2<<<cdiv_ll((ll)B * 64, T), T, 0, stream>>>(d_out, neg_idx, B, flag);
}

// Round 3
// 1997.264 us; speedup vs baseline: 1.7947x; 1.7947x over previous
//
#include <hip/hip_runtime.h>
#include <hip/hip_bf16.h>

typedef long long ll;

static inline int cdiv_ll(ll a, int b) { return (int)((a + (ll)b - 1) / (ll)b); }

// ---------------- dtype detection (bf16 vs fp32 inputs) ----------------
__global__ void k_detect(const unsigned int* __restrict__ dw, const ll n_dw, int* __restrict__ flag) {
    __shared__ int sc[256];
    int tid = threadIdx.x;
    int cnt = 0;
    for (int s = 0; s < 32; s++) {
        ll idx = (ll)(s * 256 + tid);
        ll i = (idx * n_dw) / 8192;
        unsigned v = dw[i];
        unsigned lo = v & 0xFFFFu;
        unsigned ex = (lo >> 7) & 0xFFu;
        bool pl = (lo == 0u) || (lo == 0x8000u) || (ex >= 0x60u && ex <= 0x8Fu);
        cnt += pl ? 1 : 0;
    }
    sc[tid] = cnt;
    __syncthreads();
    for (int o = 128; o > 0; o >>= 1) { if (tid < o) sc[tid] += sc[tid + o]; __syncthreads(); }
    if (tid == 0) *flag = (sc[0] * 2 > 8192) ? 1 : 0;
}

__device__ __forceinline__ float load_in(const void* p, ll i, int isbf16) {
    if (isbf16) return __bfloat162float(((const __hip_bfloat16*)p)[i]);
    return ((const float*)p)[i];
}

__global__ void k_cvt(const void* __restrict__ src, float* __restrict__ dst, const int n,
                      const int* __restrict__ flag) {
    int i = blockIdx.x * blockDim.x + threadIdx.x;
    int bf = *flag;
    if (i < n) dst[i] = load_in(src, i, bf);
}

// ---------------- CSR build: count ----------------
__global__ void k_count1(const int* __restrict__ rows, const ll E, int* __restrict__ cnt) {
    ll t = (ll)blockIdx.x * blockDim.x + threadIdx.x;
    if (t < E) atomicAdd(&cnt[rows[t]], 1);
}

__global__ void k_count2(const int* __restrict__ src, const int* __restrict__ dst, const ll E,
                         int* __restrict__ cnt_src, int* __restrict__ cnt_dst) {
    ll t = (ll)blockIdx.x * blockDim.x + threadIdx.x;
    if (t < E) {
        atomicAdd(&cnt_src[src[t]], 1);
        atomicAdd(&cnt_dst[dst[t]], 1);
    }
}

// ---------------- norms from int degrees ----------------
__global__ void k_norm_gcn(const int* __restrict__ cnt, float* __restrict__ o, const int n) {
    int i = blockIdx.x * blockDim.x + threadIdx.x;
    if (i < n) { int c = cnt[i]; o[i] = (c > 0) ? (1.0f / sqrtf((float)c)) : 0.0f; }
}

__global__ void k_norm_conv(const int* __restrict__ cnt, float* __restrict__ o, const int n) {
    int i = blockIdx.x * blockDim.x + threadIdx.x;
    if (i < n) o[i] = 1.0f / sqrtf(fmaxf((float)cnt[i], 1.0f));
}

// ---------------- hierarchical exclusive scan (counts -> row_ptr) ----------
#define SCAN_T 256
#define SCAN_ELEMS 8
#define SCAN_CHUNK (SCAN_T * SCAN_ELEMS)   // 2048

__global__ __launch_bounds__(256) void k_scanA(const int* __restrict__ in, const int n,
                                               int* __restrict__ out, int* __restrict__ bsum) {
    __shared__ int sh[SCAN_T];
    int t = threadIdx.x;
    ll base = (ll)blockIdx.x * SCAN_CHUNK + (ll)t * SCAN_ELEMS;
    int v[SCAN_ELEMS];
    int tot = 0;
#pragma unroll
    for (int k = 0; k < SCAN_ELEMS; k++) {
        ll i = base + k;
        v[k] = (i < n) ? in[i] : 0;
        tot += v[k];
    }
    sh[t] = tot;
    __syncthreads();
    for (int off = 1; off < SCAN_T; off <<= 1) {
        int x = (t >= off) ? sh[t - off] : 0;
        __syncthreads();
        sh[t] += x;
        __syncthreads();
    }
    int run = sh[t] - tot;   // exclusive prefix for this thread's chunk
#pragma unroll
    for (int k = 0; k < SCAN_ELEMS; k++) {
        ll i = base + k;
        if (i < n) out[i] = run;
        run += v[k];
    }
    if (t == SCAN_T - 1) bsum[blockIdx.x] = sh[SCAN_T - 1];
}

__global__ __launch_bounds__(256) void k_scanB(int* __restrict__ bsum, const int nb) {
    __shared__ int sh[256];
    int t = threadIdx.x;
    int running = 0;
    for (int base = 0; base < nb; base += 256) {
        int idx = base + t;
        int v = (idx < nb) ? bsum[idx] : 0;
        sh[t] = v;
        __syncthreads();
        for (int off = 1; off < 256; off <<= 1) {
            int x = (t >= off) ? sh[t - off] : 0;
            __syncthreads();
            sh[t] += x;
            __syncthreads();
        }
        if (idx < nb) bsum[idx] = running + sh[t] - v;
        int tot = sh[255];
        __syncthreads();
        running += tot;
    }
}

__global__ void k_scanC(int* __restrict__ out, const int n, const int* __restrict__ bsum, const int E) {
    ll i = (ll)blockIdx.x * blockDim.x + threadIdx.x;
    if (i < n) out[i] += bsum[i / SCAN_CHUNK];
    if (i == 0) out[n] = E;
}

// ---------------- CSR fill ----------------
__global__ void k_fill(const int* __restrict__ rows, const int* __restrict__ cols, const ll E,
                       const int* __restrict__ row_ptr, int* __restrict__ cursor,
                       int* __restrict__ col_idx) {
    ll t = (ll)blockIdx.x * blockDim.x + threadIdx.x;
    if (t < E) {
        int r = rows[t];
        int pos = atomicAdd(&cursor[r], 1);
        col_idx[row_ptr[r] + pos] = cols[t];
    }
}

// ---------------- init features ----------------
__global__ void k_init(const void* __restrict__ uf, const void* __restrict__ itf,
                       float* __restrict__ ui, float* __restrict__ hu, float* __restrict__ hi,
                       const ll nu64, const ll ntot64, const int* __restrict__ flag) {
    ll t = (ll)blockIdx.x * blockDim.x + threadIdx.x;
    int bf = *flag;
    if (t < nu64) {
        float v = load_in(uf, t, bf);
        ui[t] = v; hu[t] = v;
    } else if (t < ntot64) {
        ll j = t - nu64;
        float v = load_in(itf, j, bf);
        ui[t] = v; hi[j] = v;
    }
}

// ---------------- gather SpMM: out[r,:] = rnorm[r] * sum_{c in adj(r)} x[c,:]*cnorm[c] ----
__global__ __launch_bounds__(256) void k_gather(const int* __restrict__ row_ptr,
                                                const int* __restrict__ col_idx,
                                                const float* __restrict__ x,
                                                const float* __restrict__ cnorm,
                                                const float* __restrict__ rnorm,
                                                float* __restrict__ out, const int nrows) {
    ll gt = (ll)blockIdx.x * blockDim.x + threadIdx.x;
    int w = (int)(gt >> 6);
    int d = (int)(gt & 63);
    if (w >= nrows) return;
    int s = row_ptr[w], e = row_ptr[w + 1];
    float acc = 0.0f;
    int j = s;
    for (; j + 4 <= e; j += 4) {
        int c0 = col_idx[j], c1 = col_idx[j + 1], c2 = col_idx[j + 2], c3 = col_idx[j + 3];
        float n0 = cnorm[c0], n1 = cnorm[c1], n2 = cnorm[c2], n3 = cnorm[c3];
        float x0 = x[(ll)c0 * 64 + d];
        float x1 = x[(ll)c1 * 64 + d];
        float x2 = x[(ll)c2 * 64 + d];
        float x3 = x[(ll)c3 * 64 + d];
        acc += x0 * n0 + x1 * n1 + x2 * n2 + x3 * n3;
    }
    for (; j < e; j++) {
        int c = col_idx[j];
        acc += x[(ll)c * 64 + d] * cnorm[c];
    }
    out[(ll)w * 64 + d] = acc * rnorm[w];
}

// ---------------- semantic attention scores ----------------
__global__ __launch_bounds__(256) void k_attn(const float* __restrict__ z1, const float* __restrict__ z2,
                                              const float* __restrict__ W1,
                                              const float* __restrict__ b1,
                                              const float* __restrict__ w2,
                                              const int n, float* __restrict__ wsum) {
    __shared__ float W1t[64 * 128];   // transposed: [h][d]
    __shared__ float b1s[128];
    __shared__ float w2s[128];
    __shared__ float red0[4], red1[4];

    for (int i = threadIdx.x; i < 64 * 128; i += 256) {
        int d = i >> 7, h = i & 127;
        W1t[h * 64 + d] = W1[i];
    }
    if (threadIdx.x < 128) {
        b1s[threadIdx.x] = b1[threadIdx.x];
        w2s[threadIdx.x] = w2[threadIdx.x];
    }
    __syncthreads();

    int v = blockIdx.x * 256 + threadIdx.x;
    float w0 = 0.0f, w1 = 0.0f;
    if (v < n) {
        float4 zv[16];
        {
            const float4* zp = (const float4*)&z1[(ll)v * 64];
#pragma unroll
            for (int q = 0; q < 16; q++) zv[q] = zp[q];
            for (int h = 0; h < 128; h++) {
                float acc = b1s[h];
                const float4* wr = (const float4*)&W1t[h * 64];
#pragma unroll
                for (int q = 0; q < 16; q++) {
                    float4 wv = wr[q];
                    acc += zv[q].x * wv.x + zv[q].y * wv.y + zv[q].z * wv.z + zv[q].w * wv.w;
                }
                w0 += tanhf(acc) * w2s[h];
            }
        }
        {
            const float4* zp = (const float4*)&z2[(ll)v * 64];
#pragma unroll
            for (int q = 0; q < 16; q++) zv[q] = zp[q];
            for (int h = 0; h < 128; h++) {
                float acc = b1s[h];
                const float4* wr = (const float4*)&W1t[h * 64];
#pragma unroll
                for (int q = 0; q < 16; q++) {
                    float4 wv = wr[q];
                    acc += zv[q].x * wv.x + zv[q].y * wv.y + zv[q].z * wv.z + zv[q].w * wv.w;
                }
                w1 += tanhf(acc) * w2s[h];
            }
        }
    }
    for (int off = 32; off > 0; off >>= 1) {
        w0 += __shfl_down(w0, off);
        w1 += __shfl_down(w1, off);
    }
    int wave = threadIdx.x >> 6;
    int lane = threadIdx.x & 63;
    if (lane == 0) { red0[wave] = w0; red1[wave] = w1; }
    __syncthreads();
    if (threadIdx.x == 0) {
        float a = red0[0] + red0[1] + red0[2] + red0[3];
        float b = red1[0] + red1[1] + red1[2] + red1[3];
        atomicAdd(&wsum[0], a);
        atomicAdd(&wsum[1], b);
    }
}

__global__ void k_beta(const float* __restrict__ wsum, const float inv_n, float* __restrict__ beta) {
    if (blockIdx.x == 0 && threadIdx.x == 0) {
        float m0 = wsum[0] * inv_n, m1 = wsum[1] * inv_n;
        float mx = fmaxf(m0, m1);
        float e0 = expf(m0 - mx), e1 = expf(m1 - mx);
        float s = e0 + e1;
        beta[0] = e0 / s;
        beta[1] = e1 / s;
    }
}

__global__ void k_combine(const float* __restrict__ z1, const float* __restrict__ z2,
                          const float* __restrict__ beta, float* __restrict__ h, const ll n64) {
    ll t = (ll)blockIdx.x * blockDim.x + threadIdx.x;
    if (t < n64) h[t] = beta[0] * z1[t] + beta[1] * z2[t];
}

// ---------------- final gathers (dtype-flexible output) ----------------
__device__ __forceinline__ void store_out(void* out, ll i, float v, int isbf16) {
    if (isbf16) ((__hip_bfloat16*)out)[i] = __float2bfloat16(v);
    else ((float*)out)[i] = v;
}
__device__ __forceinline__ float load_out(const void* out, ll i, int isbf16) {
    if (isbf16) return __bfloat162float(((const __hip_bfloat16*)out)[i]);
    return ((const float*)out)[i];
}

__global__ void k_out1(const float* __restrict__ hu, const float* __restrict__ hi,
                       const float* __restrict__ ui, const int* __restrict__ user_idx,
                       const int* __restrict__ item_idx, void* __restrict__ out,
                       const int B, const ll U, const int* __restrict__ flag) {
    ll t = (ll)blockIdx.x * blockDim.x + threadIdx.x;
    int bf = *flag;
    int d = (int)(t & 63);
    ll b = t >> 6;
    if (b < B) {
        int u = user_idx[b];
        float v = 0.5f * hu[(ll)u * 64 + d] + 0.5f * ui[(ll)u * 64 + d];
        store_out(out, b * 64 + d, v, bf);
    } else if (b < 2 * (ll)B) {
        ll bb = b - B;
        int it = item_idx[bb];
        float v = 0.5f * hi[(ll)it * 64 + d] + 0.5f * ui[(U + it) * 64 + d];
        store_out(out, (ll)B * 64 + bb * 64 + d, v, bf);
    }
}

__global__ void k_out2(void* __restrict__ out, const int* __restrict__ neg_idx, const int B,
                       const int* __restrict__ flag) {
    ll t = (ll)blockIdx.x * blockDim.x + threadIdx.x;
    int bf = *flag;
    if (t < (ll)B * 64) {
        ll b = t >> 6;
        int d = (int)(t & 63);
        int nb = neg_idx[b];
        float v = load_out(out, (ll)B * 64 + (ll)nb * 64 + d, bf);
        store_out(out, (ll)2 * B * 64 + t, v, bf);
    }
}

extern "C" void kernel_launch(void* const* d_in, const int* in_sizes, int n_in,
                              void* d_out, int out_size, void* d_ws, size_t ws_size,
                              hipStream_t stream) {
    const int D = 64;
    const ll U = in_sizes[0] / D;
    const ll I = in_sizes[1] / D;
    const ll N = U + I;
    const ll E2  = in_sizes[8] / 2;
    const ll EU1 = in_sizes[9] / 2;
    const ll EU2 = in_sizes[10] / 2;
    const ll EI1 = in_sizes[11] / 2;
    const ll EI2 = in_sizes[12] / 2;
    const int B = in_sizes[13];

    const void* user_feat = d_in[0];
    const void* item_feat = d_in[1];
    const void* sa_u_W1 = d_in[2];
    const void* sa_u_b1 = d_in[3];
    const void* sa_u_w2 = d_in[4];
    const void* sa_i_W1 = d_in[5];
    const void* sa_i_b1 = d_in[6];
    const void* sa_i_w2 = d_in[7];
    const int* ui_row = (const int*)d_in[8];
    const int* ui_col = ui_row + E2;
    const int* u1_src = (const int*)d_in[9];
    const int* u1_dst = u1_src + EU1;
    const int* u2_src = (const int*)d_in[10];
    const int* u2_dst = u2_src + EU2;
    const int* i1_src = (const int*)d_in[11];
    const int* i1_dst = i1_src + EI1;
    const int* i2_src = (const int*)d_in[12];
    const int* i2_dst = i2_src + EI2;
    const int* user_idx = (const int*)d_in[13];
    const int* item_idx = (const int*)d_in[14];
    const int* neg_idx  = (const int*)d_in[15];

    // ---------------- workspace layout ----------------
    float* p = (float*)d_ws;
    float* ui0 = p;  p += N * 64;
    float* ui1 = p;  p += N * 64;
    float* hu  = p;  p += U * 64;
    float* hi  = p;  p += I * 64;
    float* z1  = p;  p += I * 64;   // user pass uses first U rows
    float* z2  = p;  p += I * 64;
    float* dinv = p; p += N;        // gcn norm
    float* n_u1r = p; p += U;  float* n_u1s = p; p += U;   // r: in(dst)-norm, s: out(src)-norm
    float* n_u2r = p; p += U;  float* n_u2s = p; p += U;
    float* n_i1r = p; p += I;  float* n_i1s = p; p += I;
    float* n_i2r = p; p += I;  float* n_i2s = p; p += I;
    float* wW1u = p; p += 64 * 128;
    float* wb1u = p; p += 128;
    float* ww2u = p; p += 128;
    float* wW1i = p; p += 64 * 128;
    float* wb1i = p; p += 128;
    float* ww2i = p; p += 128;
    float* scratch = p; p += 16;    // [0..1]=wsum, [2..3]=beta

    int* ip = (int*)p;
    // zero region start: counts + cursors (contiguous)
    int* cnt_ui = ip; ip += N;
    int* c_u1r = ip; ip += U;  int* c_u1s = ip; ip += U;
    int* c_u2r = ip; ip += U;  int* c_u2s = ip; ip += U;
    int* c_i1r = ip; ip += I;  int* c_i1s = ip; ip += I;
    int* c_i2r = ip; ip += I;  int* c_i2s = ip; ip += I;
    int* cur_ui = ip; ip += N;
    int* cur_u1 = ip; ip += U;  int* cur_u2 = ip; ip += U;
    int* cur_i1 = ip; ip += I;  int* cur_i2 = ip; ip += I;
    size_t zero_ints = (size_t)(ip - cnt_ui);
    // zero region end
    int* rp_ui = ip; ip += N + 1;
    int* rp_u1 = ip; ip += U + 1;  int* rp_u2 = ip; ip += U + 1;
    int* rp_i1 = ip; ip += I + 1;  int* rp_i2 = ip; ip += I + 1;
    int* ci_ui = ip; ip += E2;
    int* ci_u1 = ip; ip += EU1;  int* ci_u2 = ip; ip += EU2;
    int* ci_i1 = ip; ip += EI1;  int* ci_i2 = ip; ip += EI2;
    int* bsum = ip; ip += 256;
    int* flag = ip; ip += 4;
    size_t needed = (size_t)((char*)ip - (char*)d_ws);
    if (ws_size < needed) return;

    const int T = 256;

    // ---------------- dtype detection + weight conversion ----------------
    k_detect<<<1, 256, 0, stream>>>((const unsigned int*)user_feat, (ll)in_sizes[0] / 2, flag);
    k_cvt<<<cdiv_ll(64 * 128, T), T, 0, stream>>>(sa_u_W1, wW1u, 64 * 128, flag);
    k_cvt<<<1, 128, 0, stream>>>(sa_u_b1, wb1u, 128, flag);
    k_cvt<<<1, 128, 0, stream>>>(sa_u_w2, ww2u, 128, flag);
    k_cvt<<<cdiv_ll(64 * 128, T), T, 0, stream>>>(sa_i_W1, wW1i, 64 * 128, flag);
    k_cvt<<<1, 128, 0, stream>>>(sa_i_b1, wb1i, 128, flag);
    k_cvt<<<1, 128, 0, stream>>>(sa_i_w2, ww2i, 128, flag);

    // ---------------- counts ----------------
    hipMemsetAsync(cnt_ui, 0, zero_ints * sizeof(int), stream);
    hipMemsetAsync(scratch, 0, 16 * sizeof(float), stream);
    k_count1<<<cdiv_ll(E2, T), T, 0, stream>>>(ui_row, E2, cnt_ui);
    k_count2<<<cdiv_ll(EU1, T), T, 0, stream>>>(u1_src, u1_dst, EU1, c_u1s, c_u1r);
    k_count2<<<cdiv_ll(EU2, T), T, 0, stream>>>(u2_src, u2_dst, EU2, c_u2s, c_u2r);
    k_count2<<<cdiv_ll(EI1, T), T, 0, stream>>>(i1_src, i1_dst, EI1, c_i1s, c_i1r);
    k_count2<<<cdiv_ll(EI2, T), T, 0, stream>>>(i2_src, i2_dst, EI2, c_i2s, c_i2r);

    // ---------------- norms ----------------
    k_norm_gcn<<<cdiv_ll(N, T), T, 0, stream>>>(cnt_ui, dinv, (int)N);
    k_norm_conv<<<cdiv_ll(U, T), T, 0, stream>>>(c_u1r, n_u1r, (int)U);
    k_norm_conv<<<cdiv_ll(U, T), T, 0, stream>>>(c_u1s, n_u1s, (int)U);
    k_norm_conv<<<cdiv_ll(U, T), T, 0, stream>>>(c_u2r, n_u2r, (int)U);
    k_norm_conv<<<cdiv_ll(U, T), T, 0, stream>>>(c_u2s, n_u2s, (int)U);
    k_norm_conv<<<cdiv_ll(I, T), T, 0, stream>>>(c_i1r, n_i1r, (int)I);
    k_norm_conv<<<cdiv_ll(I, T), T, 0, stream>>>(c_i1s, n_i1s, (int)I);
    k_norm_conv<<<cdiv_ll(I, T), T, 0, stream>>>(c_i2r, n_i2r, (int)I);
    k_norm_conv<<<cdiv_ll(I, T), T, 0, stream>>>(c_i2s, n_i2s, (int)I);

    // ---------------- scans: counts -> row_ptr ----------------
    auto scan = [&](const int* cnt, int n, int* rp, int E) {
        int nb = (n + SCAN_CHUNK - 1) / SCAN_CHUNK;
        k_scanA<<<nb, SCAN_T, 0, stream>>>(cnt, n, rp, bsum);
        k_scanB<<<1, 256, 0, stream>>>(bsum, nb);
        k_scanC<<<cdiv_ll(n, T), T, 0, stream>>>(rp, n, bsum, E);
    };
    scan(cnt_ui, (int)N, rp_ui, (int)E2);
    scan(c_u1r, (int)U, rp_u1, (int)EU1);
    scan(c_u2r, (int)U, rp_u2, (int)EU2);
    scan(c_i1r, (int)I, rp_i1, (int)EI1);
    scan(c_i2r, (int)I, rp_i2, (int)EI2);

    // ---------------- fill: CSR adjacency (rows=aggregation target) ----------
    k_fill<<<cdiv_ll(E2, T), T, 0, stream>>>(ui_row, ui_col, E2, rp_ui, cur_ui, ci_ui);
    k_fill<<<cdiv_ll(EU1, T), T, 0, stream>>>(u1_dst, u1_src, EU1, rp_u1, cur_u1, ci_u1);
    k_fill<<<cdiv_ll(EU2, T), T, 0, stream>>>(u2_dst, u2_src, EU2, rp_u2, cur_u2, ci_u2);
    k_fill<<<cdiv_ll(EI1, T), T, 0, stream>>>(i1_dst, i1_src, EI1, rp_i1, cur_i1, ci_i1);
    k_fill<<<cdiv_ll(EI2, T), T, 0, stream>>>(i2_dst, i2_src, EI2, rp_i2, cur_i2, ci_i2);

    // ---------------- init features ----------------
    k_init<<<cdiv_ll(N * 64, T), T, 0, stream>>>(user_feat, item_feat, ui0, hu, hi, U * 64, N * 64, flag);

    float* uiA = ui0;
    float* uiB = ui1;

    for (int layer = 0; layer < 2; layer++) {
        // ---- gcn_spmm (gather) ----
        k_gather<<<cdiv_ll(N * 64, T), T, 0, stream>>>(rp_ui, ci_ui, uiA, dinv, dinv, uiB, (int)N);
        { float* tmp = uiA; uiA = uiB; uiB = tmp; }

        // ---- HAN: users ----
        k_gather<<<cdiv_ll(U * 64, T), T, 0, stream>>>(rp_u1, ci_u1, hu, n_u1s, n_u1r, z1, (int)U);
        k_gather<<<cdiv_ll(U * 64, T), T, 0, stream>>>(rp_u2, ci_u2, hu, n_u2s, n_u2r, z2, (int)U);
        hipMemsetAsync(scratch, 0, 2 * sizeof(float), stream);
        k_attn<<<cdiv_ll(U, T), T, 0, stream>>>(z1, z2, wW1u, wb1u, ww2u, (int)U, scratch);
        k_beta<<<1, 64, 0, stream>>>(scratch, 1.0f / (float)U, scratch + 2);
        k_combine<<<cdiv_ll(U * 64, T), T, 0, stream>>>(z1, z2, scratch + 2, hu, U * 64);

        // ---- HAN: items ----
        k_gather<<<cdiv_ll(I * 64, T), T, 0, stream>>>(rp_i1, ci_i1, hi, n_i1s, n_i1r, z1, (int)I);
        k_gather<<<cdiv_ll(I * 64, T), T, 0, stream>>>(rp_i2, ci_i2, hi, n_i2s, n_i2r, z2, (int)I);
        hipMemsetAsync(scratch, 0, 2 * sizeof(float), stream);
        k_attn<<<cdiv_ll(I, T), T, 0, stream>>>(z1, z2, wW1i, wb1i, ww2i, (int)I, scratch);
        k_beta<<<1, 64, 0, stream>>>(scratch, 1.0f / (float)I, scratch + 2);
        k_combine<<<cdiv_ll(I * 64, T), T, 0, stream>>>(z1, z2, scratch + 2, hi, I * 64);
    }

    // ---------------- final: 0.5*h + 0.5*ui, gathers ----------------
    k_out1<<<cdiv_ll((ll)2 * B * 64, T), T, 0, stream>>>(hu, hi, uiA, user_idx, item_idx, d_out, B, U, flag);
    k_out2<<<cdiv_ll((ll)B * 64, T), T, 0, stream>>>(d_out, neg_idx, B, flag);
}

// Round 4
// 1776.596 us; speedup vs baseline: 2.0176x; 1.1242x over previous
//
#include <hip/hip_runtime.h>
#include <hip/hip_bf16.h>

typedef long long ll;

static inline int cdiv_ll(ll a, int b) { return (int)((a + (ll)b - 1) / (ll)b); }

// ---------------- dtype detection (bf16 vs fp32 inputs) ----------------
__global__ void k_detect(const unsigned int* __restrict__ dw, const ll n_dw, int* __restrict__ flag) {
    __shared__ int sc[256];
    int tid = threadIdx.x;
    int cnt = 0;
    for (int s = 0; s < 32; s++) {
        ll idx = (ll)(s * 256 + tid);
        ll i = (idx * n_dw) / 8192;
        unsigned v = dw[i];
        unsigned lo = v & 0xFFFFu;
        unsigned ex = (lo >> 7) & 0xFFu;
        bool pl = (lo == 0u) || (lo == 0x8000u) || (ex >= 0x60u && ex <= 0x8Fu);
        cnt += pl ? 1 : 0;
    }
    sc[tid] = cnt;
    __syncthreads();
    for (int o = 128; o > 0; o >>= 1) { if (tid < o) sc[tid] += sc[tid + o]; __syncthreads(); }
    if (tid == 0) *flag = (sc[0] * 2 > 8192) ? 1 : 0;
}

__device__ __forceinline__ float load_in(const void* p, ll i, int isbf16) {
    if (isbf16) return __bfloat162float(((const __hip_bfloat16*)p)[i]);
    return ((const float*)p)[i];
}

__global__ void k_cvt(const void* __restrict__ src, float* __restrict__ dst, const int n,
                      const int* __restrict__ flag) {
    int i = blockIdx.x * blockDim.x + threadIdx.x;
    int bf = *flag;
    if (i < n) dst[i] = load_in(src, i, bf);
}

// transpose-convert W1 [64 x 128] -> W1t [128 x 64]
__global__ void k_cvtT(const void* __restrict__ src, float* __restrict__ dst,
                       const int* __restrict__ flag) {
    int i = blockIdx.x * blockDim.x + threadIdx.x;   // i over 64*128
    int bf = *flag;
    if (i < 64 * 128) {
        int d = i >> 7, h = i & 127;
        dst[h * 64 + d] = load_in(src, i, bf);
    }
}

// ---------------- CSR build: count ----------------
__global__ void k_count1(const int* __restrict__ rows, const ll E, int* __restrict__ cnt) {
    ll t = (ll)blockIdx.x * blockDim.x + threadIdx.x;
    if (t < E) atomicAdd(&cnt[rows[t]], 1);
}

__global__ void k_count2(const int* __restrict__ src, const int* __restrict__ dst, const ll E,
                         int* __restrict__ cnt_src, int* __restrict__ cnt_dst) {
    ll t = (ll)blockIdx.x * blockDim.x + threadIdx.x;
    if (t < E) {
        atomicAdd(&cnt_src[src[t]], 1);
        atomicAdd(&cnt_dst[dst[t]], 1);
    }
}

// ---------------- norms from int degrees ----------------
__global__ void k_norm_gcn(const int* __restrict__ cnt, float* __restrict__ o, const int n) {
    int i = blockIdx.x * blockDim.x + threadIdx.x;
    if (i < n) { int c = cnt[i]; o[i] = (c > 0) ? (1.0f / sqrtf((float)c)) : 0.0f; }
}

__global__ void k_norm_conv(const int* __restrict__ cnt, float* __restrict__ o, const int n) {
    int i = blockIdx.x * blockDim.x + threadIdx.x;
    if (i < n) o[i] = 1.0f / sqrtf(fmaxf((float)cnt[i], 1.0f));
}

// ---------------- hierarchical exclusive scan (counts -> row_ptr) ----------
#define SCAN_T 256
#define SCAN_ELEMS 8
#define SCAN_CHUNK (SCAN_T * SCAN_ELEMS)   // 2048

__global__ __launch_bounds__(256) void k_scanA(const int* __restrict__ in, const int n,
                                               int* __restrict__ out, int* __restrict__ bsum) {
    __shared__ int sh[SCAN_T];
    int t = threadIdx.x;
    ll base = (ll)blockIdx.x * SCAN_CHUNK + (ll)t * SCAN_ELEMS;
    int v[SCAN_ELEMS];
    int tot = 0;
#pragma unroll
    for (int k = 0; k < SCAN_ELEMS; k++) {
        ll i = base + k;
        v[k] = (i < n) ? in[i] : 0;
        tot += v[k];
    }
    sh[t] = tot;
    __syncthreads();
    for (int off = 1; off < SCAN_T; off <<= 1) {
        int x = (t >= off) ? sh[t - off] : 0;
        __syncthreads();
        sh[t] += x;
        __syncthreads();
    }
    int run = sh[t] - tot;
#pragma unroll
    for (int k = 0; k < SCAN_ELEMS; k++) {
        ll i = base + k;
        if (i < n) out[i] = run;
        run += v[k];
    }
    if (t == SCAN_T - 1) bsum[blockIdx.x] = sh[SCAN_T - 1];
}

__global__ __launch_bounds__(256) void k_scanB(int* __restrict__ bsum, const int nb) {
    __shared__ int sh[256];
    int t = threadIdx.x;
    int running = 0;
    for (int base = 0; base < nb; base += 256) {
        int idx = base + t;
        int v = (idx < nb) ? bsum[idx] : 0;
        sh[t] = v;
        __syncthreads();
        for (int off = 1; off < 256; off <<= 1) {
            int x = (t >= off) ? sh[t - off] : 0;
            __syncthreads();
            sh[t] += x;
            __syncthreads();
        }
        if (idx < nb) bsum[idx] = running + sh[t] - v;
        int tot = sh[255];
        __syncthreads();
        running += tot;
    }
}

__global__ void k_scanC(int* __restrict__ out, const int n, const int* __restrict__ bsum, const int E) {
    ll i = (ll)blockIdx.x * blockDim.x + threadIdx.x;
    if (i < n) out[i] += bsum[i / SCAN_CHUNK];
    if (i == 0) out[n] = E;
}

// ---------------- CSR fill ----------------
__global__ void k_fill(const int* __restrict__ rows, const int* __restrict__ cols, const ll E,
                       const int* __restrict__ row_ptr, int* __restrict__ cursor,
                       int* __restrict__ col_idx) {
    ll t = (ll)blockIdx.x * blockDim.x + threadIdx.x;
    if (t < E) {
        int r = rows[t];
        int pos = atomicAdd(&cursor[r], 1);
        col_idx[row_ptr[r] + pos] = cols[t];
    }
}

// ---------------- init features ----------------
__global__ void k_init(const void* __restrict__ uf, const void* __restrict__ itf,
                       float* __restrict__ ui, float* __restrict__ hu, float* __restrict__ hi,
                       const ll nu64, const ll ntot64, const int* __restrict__ flag) {
    ll t = (ll)blockIdx.x * blockDim.x + threadIdx.x;
    int bf = *flag;
    if (t < nu64) {
        float v = load_in(uf, t, bf);
        ui[t] = v; hu[t] = v;
    } else if (t < ntot64) {
        ll j = t - nu64;
        float v = load_in(itf, j, bf);
        ui[t] = v; hi[j] = v;
    }
}

// ---------------- gather SpMM ----------------
__global__ __launch_bounds__(256) void k_gather(const int* __restrict__ row_ptr,
                                                const int* __restrict__ col_idx,
                                                const float* __restrict__ x,
                                                const float* __restrict__ cnorm,
                                                const float* __restrict__ rnorm,
                                                float* __restrict__ out, const int nrows) {
    ll gt = (ll)blockIdx.x * blockDim.x + threadIdx.x;
    int w = (int)(gt >> 6);
    int d = (int)(gt & 63);
    if (w >= nrows) return;
    int s = row_ptr[w], e = row_ptr[w + 1];
    float acc = 0.0f;
    int j = s;
    for (; j + 4 <= e; j += 4) {
        int c0 = col_idx[j], c1 = col_idx[j + 1], c2 = col_idx[j + 2], c3 = col_idx[j + 3];
        float n0 = cnorm[c0], n1 = cnorm[c1], n2 = cnorm[c2], n3 = cnorm[c3];
        float x0 = x[(ll)c0 * 64 + d];
        float x1 = x[(ll)c1 * 64 + d];
        float x2 = x[(ll)c2 * 64 + d];
        float x3 = x[(ll)c3 * 64 + d];
        acc += x0 * n0 + x1 * n1 + x2 * n2 + x3 * n3;
    }
    for (; j < e; j++) {
        int c = col_idx[j];
        acc += x[(ll)c * 64 + d] * cnorm[c];
    }
    out[(ll)w * 64 + d] = acc * rnorm[w];
}

// ---------------- fast tanh: 1 - 2/(e^{2x}+1), exact saturation ----------
__device__ __forceinline__ float fast_tanh(float x) {
    return 1.0f - 2.0f / (__expf(2.0f * x) + 1.0f);
}

// ---------------- semantic attention scores, h-sliced ----------------
// grid = (ceil(n/256), HS); blockIdx.y selects 32-hidden-unit slice.
// W1t is pre-transposed [128][64]. Each block stages its 8KB slice in LDS;
// reads are wave-uniform broadcast (conflict-free).
__global__ __launch_bounds__(256) void k_attn(const float* __restrict__ z1, const float* __restrict__ z2,
                                              const float* __restrict__ W1t,
                                              const float* __restrict__ b1,
                                              const float* __restrict__ w2,
                                              const int n, float* __restrict__ wsum) {
    __shared__ float Ws[32 * 64];
    __shared__ float bs[32];
    __shared__ float ws2[32];
    __shared__ float red0[4], red1[4];

    int tid = threadIdx.x;
    int hs = blockIdx.y * 32;
    for (int i = tid; i < 32 * 64; i += 256) Ws[i] = W1t[hs * 64 + i];
    if (tid < 32) { bs[tid] = b1[hs + tid]; ws2[tid] = w2[hs + tid]; }
    __syncthreads();

    int v = blockIdx.x * 256 + tid;
    float w0 = 0.0f, w1 = 0.0f;
    if (v < n) {
        float4 zv[16];
        {
            const float4* zp = (const float4*)&z1[(ll)v * 64];
#pragma unroll
            for (int q = 0; q < 16; q++) zv[q] = zp[q];
#pragma unroll 4
            for (int h = 0; h < 32; h++) {
                float acc = bs[h];
                const float4* wr = (const float4*)&Ws[h * 64];
#pragma unroll
                for (int q = 0; q < 16; q++) {
                    float4 wv = wr[q];
                    acc += zv[q].x * wv.x + zv[q].y * wv.y + zv[q].z * wv.z + zv[q].w * wv.w;
                }
                w0 += fast_tanh(acc) * ws2[h];
            }
        }
        {
            const float4* zp = (const float4*)&z2[(ll)v * 64];
#pragma unroll
            for (int q = 0; q < 16; q++) zv[q] = zp[q];
#pragma unroll 4
            for (int h = 0; h < 32; h++) {
                float acc = bs[h];
                const float4* wr = (const float4*)&Ws[h * 64];
#pragma unroll
                for (int q = 0; q < 16; q++) {
                    float4 wv = wr[q];
                    acc += zv[q].x * wv.x + zv[q].y * wv.y + zv[q].z * wv.z + zv[q].w * wv.w;
                }
                w1 += fast_tanh(acc) * ws2[h];
            }
        }
    }
    for (int off = 32; off > 0; off >>= 1) {
        w0 += __shfl_down(w0, off);
        w1 += __shfl_down(w1, off);
    }
    int wave = tid >> 6;
    int lane = tid & 63;
    if (lane == 0) { red0[wave] = w0; red1[wave] = w1; }
    __syncthreads();
    if (tid == 0) {
        float a = red0[0] + red0[1] + red0[2] + red0[3];
        float b = red1[0] + red1[1] + red1[2] + red1[3];
        atomicAdd(&wsum[0], a);
        atomicAdd(&wsum[1], b);
    }
}

__global__ void k_beta(const float* __restrict__ wsum, const float inv_n, float* __restrict__ beta) {
    if (blockIdx.x == 0 && threadIdx.x == 0) {
        float m0 = wsum[0] * inv_n, m1 = wsum[1] * inv_n;
        float mx = fmaxf(m0, m1);
        float e0 = expf(m0 - mx), e1 = expf(m1 - mx);
        float s = e0 + e1;
        beta[0] = e0 / s;
        beta[1] = e1 / s;
    }
}

__global__ void k_combine(const float* __restrict__ z1, const float* __restrict__ z2,
                          const float* __restrict__ beta, float* __restrict__ h, const ll n64) {
    ll t = (ll)blockIdx.x * blockDim.x + threadIdx.x;
    if (t < n64) h[t] = beta[0] * z1[t] + beta[1] * z2[t];
}

// ---------------- final gathers (dtype-flexible output) ----------------
__device__ __forceinline__ void store_out(void* out, ll i, float v, int isbf16) {
    if (isbf16) ((__hip_bfloat16*)out)[i] = __float2bfloat16(v);
    else ((float*)out)[i] = v;
}
__device__ __forceinline__ float load_out(const void* out, ll i, int isbf16) {
    if (isbf16) return __bfloat162float(((const __hip_bfloat16*)out)[i]);
    return ((const float*)out)[i];
}

__global__ void k_out1(const float* __restrict__ hu, const float* __restrict__ hi,
                       const float* __restrict__ ui, const int* __restrict__ user_idx,
                       const int* __restrict__ item_idx, void* __restrict__ out,
                       const int B, const ll U, const int* __restrict__ flag) {
    ll t = (ll)blockIdx.x * blockDim.x + threadIdx.x;
    int bf = *flag;
    int d = (int)(t & 63);
    ll b = t >> 6;
    if (b < B) {
        int u = user_idx[b];
        float v = 0.5f * hu[(ll)u * 64 + d] + 0.5f * ui[(ll)u * 64 + d];
        store_out(out, b * 64 + d, v, bf);
    } else if (b < 2 * (ll)B) {
        ll bb = b - B;
        int it = item_idx[bb];
        float v = 0.5f * hi[(ll)it * 64 + d] + 0.5f * ui[(U + it) * 64 + d];
        store_out(out, (ll)B * 64 + bb * 64 + d, v, bf);
    }
}

__global__ void k_out2(void* __restrict__ out, const int* __restrict__ neg_idx, const int B,
                       const int* __restrict__ flag) {
    ll t = (ll)blockIdx.x * blockDim.x + threadIdx.x;
    int bf = *flag;
    if (t < (ll)B * 64) {
        ll b = t >> 6;
        int d = (int)(t & 63);
        int nb = neg_idx[b];
        float v = load_out(out, (ll)B * 64 + (ll)nb * 64 + d, bf);
        store_out(out, (ll)2 * B * 64 + t, v, bf);
    }
}

extern "C" void kernel_launch(void* const* d_in, const int* in_sizes, int n_in,
                              void* d_out, int out_size, void* d_ws, size_t ws_size,
                              hipStream_t stream) {
    const int D = 64;
    const ll U = in_sizes[0] / D;
    const ll I = in_sizes[1] / D;
    const ll N = U + I;
    const ll E2  = in_sizes[8] / 2;
    const ll EU1 = in_sizes[9] / 2;
    const ll EU2 = in_sizes[10] / 2;
    const ll EI1 = in_sizes[11] / 2;
    const ll EI2 = in_sizes[12] / 2;
    const int B = in_sizes[13];

    const void* user_feat = d_in[0];
    const void* item_feat = d_in[1];
    const void* sa_u_W1 = d_in[2];
    const void* sa_u_b1 = d_in[3];
    const void* sa_u_w2 = d_in[4];
    const void* sa_i_W1 = d_in[5];
    const void* sa_i_b1 = d_in[6];
    const void* sa_i_w2 = d_in[7];
    const int* ui_row = (const int*)d_in[8];
    const int* ui_col = ui_row + E2;
    const int* u1_src = (const int*)d_in[9];
    const int* u1_dst = u1_src + EU1;
    const int* u2_src = (const int*)d_in[10];
    const int* u2_dst = u2_src + EU2;
    const int* i1_src = (const int*)d_in[11];
    const int* i1_dst = i1_src + EI1;
    const int* i2_src = (const int*)d_in[12];
    const int* i2_dst = i2_src + EI2;
    const int* user_idx = (const int*)d_in[13];
    const int* item_idx = (const int*)d_in[14];
    const int* neg_idx  = (const int*)d_in[15];

    // ---------------- workspace layout ----------------
    float* p = (float*)d_ws;
    float* ui0 = p;  p += N * 64;
    float* ui1 = p;  p += N * 64;
    float* hu  = p;  p += U * 64;
    float* hi  = p;  p += I * 64;
    float* z1  = p;  p += I * 64;
    float* z2  = p;  p += I * 64;
    float* dinv = p; p += N;
    float* n_u1r = p; p += U;  float* n_u1s = p; p += U;
    float* n_u2r = p; p += U;  float* n_u2s = p; p += U;
    float* n_i1r = p; p += I;  float* n_i1s = p; p += I;
    float* n_i2r = p; p += I;  float* n_i2s = p; p += I;
    float* wW1u = p; p += 64 * 128;   // transposed [128][64]
    float* wb1u = p; p += 128;
    float* ww2u = p; p += 128;
    float* wW1i = p; p += 64 * 128;   // transposed [128][64]
    float* wb1i = p; p += 128;
    float* ww2i = p; p += 128;
    float* scratch = p; p += 16;

    int* ip = (int*)p;
    int* cnt_ui = ip; ip += N;
    int* c_u1r = ip; ip += U;  int* c_u1s = ip; ip += U;
    int* c_u2r = ip; ip += U;  int* c_u2s = ip; ip += U;
    int* c_i1r = ip; ip += I;  int* c_i1s = ip; ip += I;
    int* c_i2r = ip; ip += I;  int* c_i2s = ip; ip += I;
    int* cur_ui = ip; ip += N;
    int* cur_u1 = ip; ip += U;  int* cur_u2 = ip; ip += U;
    int* cur_i1 = ip; ip += I;  int* cur_i2 = ip; ip += I;
    size_t zero_ints = (size_t)(ip - cnt_ui);
    int* rp_ui = ip; ip += N + 1;
    int* rp_u1 = ip; ip += U + 1;  int* rp_u2 = ip; ip += U + 1;
    int* rp_i1 = ip; ip += I + 1;  int* rp_i2 = ip; ip += I + 1;
    int* ci_ui = ip; ip += E2;
    int* ci_u1 = ip; ip += EU1;  int* ci_u2 = ip; ip += EU2;
    int* ci_i1 = ip; ip += EI1;  int* ci_i2 = ip; ip += EI2;
    int* bsum = ip; ip += 256;
    int* flag = ip; ip += 4;
    size_t needed = (size_t)((char*)ip - (char*)d_ws);
    if (ws_size < needed) return;

    const int T = 256;

    // ---------------- dtype detection + weight conversion ----------------
    k_detect<<<1, 256, 0, stream>>>((const unsigned int*)user_feat, (ll)in_sizes[0] / 2, flag);
    k_cvtT<<<cdiv_ll(64 * 128, T), T, 0, stream>>>(sa_u_W1, wW1u, flag);
    k_cvt<<<1, 128, 0, stream>>>(sa_u_b1, wb1u, 128, flag);
    k_cvt<<<1, 128, 0, stream>>>(sa_u_w2, ww2u, 128, flag);
    k_cvtT<<<cdiv_ll(64 * 128, T), T, 0, stream>>>(sa_i_W1, wW1i, flag);
    k_cvt<<<1, 128, 0, stream>>>(sa_i_b1, wb1i, 128, flag);
    k_cvt<<<1, 128, 0, stream>>>(sa_i_w2, ww2i, 128, flag);

    // ---------------- counts ----------------
    hipMemsetAsync(cnt_ui, 0, zero_ints * sizeof(int), stream);
    hipMemsetAsync(scratch, 0, 16 * sizeof(float), stream);
    k_count1<<<cdiv_ll(E2, T), T, 0, stream>>>(ui_row, E2, cnt_ui);
    k_count2<<<cdiv_ll(EU1, T), T, 0, stream>>>(u1_src, u1_dst, EU1, c_u1s, c_u1r);
    k_count2<<<cdiv_ll(EU2, T), T, 0, stream>>>(u2_src, u2_dst, EU2, c_u2s, c_u2r);
    k_count2<<<cdiv_ll(EI1, T), T, 0, stream>>>(i1_src, i1_dst, EI1, c_i1s, c_i1r);
    k_count2<<<cdiv_ll(EI2, T), T, 0, stream>>>(i2_src, i2_dst, EI2, c_i2s, c_i2r);

    // ---------------- norms ----------------
    k_norm_gcn<<<cdiv_ll(N, T), T, 0, stream>>>(cnt_ui, dinv, (int)N);
    k_norm_conv<<<cdiv_ll(U, T), T, 0, stream>>>(c_u1r, n_u1r, (int)U);
    k_norm_conv<<<cdiv_ll(U, T), T, 0, stream>>>(c_u1s, n_u1s, (int)U);
    k_norm_conv<<<cdiv_ll(U, T), T, 0, stream>>>(c_u2r, n_u2r, (int)U);
    k_norm_conv<<<cdiv_ll(U, T), T, 0, stream>>>(c_u2s, n_u2s, (int)U);
    k_norm_conv<<<cdiv_ll(I, T), T, 0, stream>>>(c_i1r, n_i1r, (int)I);
    k_norm_conv<<<cdiv_ll(I, T), T, 0, stream>>>(c_i1s, n_i1s, (int)I);
    k_norm_conv<<<cdiv_ll(I, T), T, 0, stream>>>(c_i2r, n_i2r, (int)I);
    k_norm_conv<<<cdiv_ll(I, T), T, 0, stream>>>(c_i2s, n_i2s, (int)I);

    // ---------------- scans ----------------
    auto scan = [&](const int* cnt, int n, int* rp, int E) {
        int nb = (n + SCAN_CHUNK - 1) / SCAN_CHUNK;
        k_scanA<<<nb, SCAN_T, 0, stream>>>(cnt, n, rp, bsum);
        k_scanB<<<1, 256, 0, stream>>>(bsum, nb);
        k_scanC<<<cdiv_ll(n, T), T, 0, stream>>>(rp, n, bsum, E);
    };
    scan(cnt_ui, (int)N, rp_ui, (int)E2);
    scan(c_u1r, (int)U, rp_u1, (int)EU1);
    scan(c_u2r, (int)U, rp_u2, (int)EU2);
    scan(c_i1r, (int)I, rp_i1, (int)EI1);
    scan(c_i2r, (int)I, rp_i2, (int)EI2);

    // ---------------- fill ----------------
    k_fill<<<cdiv_ll(E2, T), T, 0, stream>>>(ui_row, ui_col, E2, rp_ui, cur_ui, ci_ui);
    k_fill<<<cdiv_ll(EU1, T), T, 0, stream>>>(u1_dst, u1_src, EU1, rp_u1, cur_u1, ci_u1);
    k_fill<<<cdiv_ll(EU2, T), T, 0, stream>>>(u2_dst, u2_src, EU2, rp_u2, cur_u2, ci_u2);
    k_fill<<<cdiv_ll(EI1, T), T, 0, stream>>>(i1_dst, i1_src, EI1, rp_i1, cur_i1, ci_i1);
    k_fill<<<cdiv_ll(EI2, T), T, 0, stream>>>(i2_dst, i2_src, EI2, rp_i2, cur_i2, ci_i2);

    // ---------------- init features ----------------
    k_init<<<cdiv_ll(N * 64, T), T, 0, stream>>>(user_feat, item_feat, ui0, hu, hi, U * 64, N * 64, flag);

    float* uiA = ui0;
    float* uiB = ui1;

    dim3 gau(cdiv_ll(U, 256), 4);
    dim3 gai(cdiv_ll(I, 256), 4);

    for (int layer = 0; layer < 2; layer++) {
        // ---- gcn_spmm ----
        k_gather<<<cdiv_ll(N * 64, T), T, 0, stream>>>(rp_ui, ci_ui, uiA, dinv, dinv, uiB, (int)N);
        { float* tmp = uiA; uiA = uiB; uiB = tmp; }

        // ---- HAN: users ----
        k_gather<<<cdiv_ll(U * 64, T), T, 0, stream>>>(rp_u1, ci_u1, hu, n_u1s, n_u1r, z1, (int)U);
        k_gather<<<cdiv_ll(U * 64, T), T, 0, stream>>>(rp_u2, ci_u2, hu, n_u2s, n_u2r, z2, (int)U);
        hipMemsetAsync(scratch, 0, 2 * sizeof(float), stream);
        k_attn<<<gau, T, 0, stream>>>(z1, z2, wW1u, wb1u, ww2u, (int)U, scratch);
        k_beta<<<1, 64, 0, stream>>>(scratch, 1.0f / (float)U, scratch + 2);
        k_combine<<<cdiv_ll(U * 64, T), T, 0, stream>>>(z1, z2, scratch + 2, hu, U * 64);

        // ---- HAN: items ----
        k_gather<<<cdiv_ll(I * 64, T), T, 0, stream>>>(rp_i1, ci_i1, hi, n_i1s, n_i1r, z1, (int)I);
        k_gather<<<cdiv_ll(I * 64, T), T, 0, stream>>>(rp_i2, ci_i2, hi, n_i2s, n_i2r, z2, (int)I);
        hipMemsetAsync(scratch, 0, 2 * sizeof(float), stream);
        k_attn<<<gai, T, 0, stream>>>(z1, z2, wW1i, wb1i, ww2i, (int)I, scratch);
        k_beta<<<1, 64, 0, stream>>>(scratch, 1.0f / (float)I, scratch + 2);
        k_combine<<<cdiv_ll(I * 64, T), T, 0, stream>>>(z1, z2, scratch + 2, hi, I * 64);
    }

    // ---------------- final ----------------
    k_out1<<<cdiv_ll((ll)2 * B * 64, T), T, 0, stream>>>(hu, hi, uiA, user_idx, item_idx, d_out, B, U, flag);
    k_out2<<<cdiv_ll((ll)B * 64, T), T, 0, stream>>>(d_out, neg_idx, B, flag);
}

// Round 5
// 1749.128 us; speedup vs baseline: 2.0493x; 1.0157x over previous
//
#include <hip/hip_runtime.h>
#include <hip/hip_bf16.h>

typedef long long ll;

static inline int cdiv_ll(ll a, int b) { return (int)((a + (ll)b - 1) / (ll)b); }

// ---------------- dtype detection (bf16 vs fp32 inputs) ----------------
__global__ void k_detect(const unsigned int* __restrict__ dw, const ll n_dw, int* __restrict__ flag) {
    __shared__ int sc[256];
    int tid = threadIdx.x;
    int cnt = 0;
    for (int s = 0; s < 32; s++) {
        ll idx = (ll)(s * 256 + tid);
        ll i = (idx * n_dw) / 8192;
        unsigned v = dw[i];
        unsigned lo = v & 0xFFFFu;
        unsigned ex = (lo >> 7) & 0xFFu;
        bool pl = (lo == 0u) || (lo == 0x8000u) || (ex >= 0x60u && ex <= 0x8Fu);
        cnt += pl ? 1 : 0;
    }
    sc[tid] = cnt;
    __syncthreads();
    for (int o = 128; o > 0; o >>= 1) { if (tid < o) sc[tid] += sc[tid + o]; __syncthreads(); }
    if (tid == 0) *flag = (sc[0] * 2 > 8192) ? 1 : 0;
}

__device__ __forceinline__ float load_in(const void* p, ll i, int isbf16) {
    if (isbf16) return __bfloat162float(((const __hip_bfloat16*)p)[i]);
    return ((const float*)p)[i];
}

__global__ void k_cvt(const void* __restrict__ src, float* __restrict__ dst, const int n,
                      const int* __restrict__ flag) {
    int i = blockIdx.x * blockDim.x + threadIdx.x;
    int bf = *flag;
    if (i < n) dst[i] = load_in(src, i, bf);
}

// transpose-convert W1 [64 x 128] -> W1t [128 x 64]
__global__ void k_cvtT(const void* __restrict__ src, float* __restrict__ dst,
                       const int* __restrict__ flag) {
    int i = blockIdx.x * blockDim.x + threadIdx.x;
    int bf = *flag;
    if (i < 64 * 128) {
        int d = i >> 7, h = i & 127;
        dst[h * 64 + d] = load_in(src, i, bf);
    }
}

// ---------------- CSR build: count ----------------
__global__ void k_count1(const int* __restrict__ rows, const ll E, int* __restrict__ cnt) {
    ll t = (ll)blockIdx.x * blockDim.x + threadIdx.x;
    if (t < E) atomicAdd(&cnt[rows[t]], 1);
}

__global__ void k_count2(const int* __restrict__ src, const int* __restrict__ dst, const ll E,
                         int* __restrict__ cnt_src, int* __restrict__ cnt_dst) {
    ll t = (ll)blockIdx.x * blockDim.x + threadIdx.x;
    if (t < E) {
        atomicAdd(&cnt_src[src[t]], 1);
        atomicAdd(&cnt_dst[dst[t]], 1);
    }
}

// ---------------- norms from int degrees ----------------
__global__ void k_norm_gcn(const int* __restrict__ cnt, float* __restrict__ o, const int n) {
    int i = blockIdx.x * blockDim.x + threadIdx.x;
    if (i < n) { int c = cnt[i]; o[i] = (c > 0) ? (1.0f / sqrtf((float)c)) : 0.0f; }
}

__global__ void k_norm_conv(const int* __restrict__ cnt, float* __restrict__ o, const int n) {
    int i = blockIdx.x * blockDim.x + threadIdx.x;
    if (i < n) o[i] = 1.0f / sqrtf(fmaxf((float)cnt[i], 1.0f));
}

// ---------------- hierarchical exclusive scan ----------
#define SCAN_T 256
#define SCAN_ELEMS 8
#define SCAN_CHUNK (SCAN_T * SCAN_ELEMS)   // 2048

__global__ __launch_bounds__(256) void k_scanA(const int* __restrict__ in, const int n,
                                               int* __restrict__ out, int* __restrict__ bsum) {
    __shared__ int sh[SCAN_T];
    int t = threadIdx.x;
    ll base = (ll)blockIdx.x * SCAN_CHUNK + (ll)t * SCAN_ELEMS;
    int v[SCAN_ELEMS];
    int tot = 0;
#pragma unroll
    for (int k = 0; k < SCAN_ELEMS; k++) {
        ll i = base + k;
        v[k] = (i < n) ? in[i] : 0;
        tot += v[k];
    }
    sh[t] = tot;
    __syncthreads();
    for (int off = 1; off < SCAN_T; off <<= 1) {
        int x = (t >= off) ? sh[t - off] : 0;
        __syncthreads();
        sh[t] += x;
        __syncthreads();
    }
    int run = sh[t] - tot;
#pragma unroll
    for (int k = 0; k < SCAN_ELEMS; k++) {
        ll i = base + k;
        if (i < n) out[i] = run;
        run += v[k];
    }
    if (t == SCAN_T - 1) bsum[blockIdx.x] = sh[SCAN_T - 1];
}

__global__ __launch_bounds__(256) void k_scanB(int* __restrict__ bsum, const int nb) {
    __shared__ int sh[256];
    int t = threadIdx.x;
    int running = 0;
    for (int base = 0; base < nb; base += 256) {
        int idx = base + t;
        int v = (idx < nb) ? bsum[idx] : 0;
        sh[t] = v;
        __syncthreads();
        for (int off = 1; off < 256; off <<= 1) {
            int x = (t >= off) ? sh[t - off] : 0;
            __syncthreads();
            sh[t] += x;
            __syncthreads();
        }
        if (idx < nb) bsum[idx] = running + sh[t] - v;
        int tot = sh[255];
        __syncthreads();
        running += tot;
    }
}

__global__ void k_scanC(int* __restrict__ out, const int n, const int* __restrict__ bsum, const int E) {
    ll i = (ll)blockIdx.x * blockDim.x + threadIdx.x;
    if (i < n) out[i] += bsum[i / SCAN_CHUNK];
    if (i == 0) out[n] = E;
}

// ---------------- CSR fill ----------------
__global__ void k_fill(const int* __restrict__ rows, const int* __restrict__ cols, const ll E,
                       const int* __restrict__ row_ptr, int* __restrict__ cursor,
                       int* __restrict__ col_idx) {
    ll t = (ll)blockIdx.x * blockDim.x + threadIdx.x;
    if (t < E) {
        int r = rows[t];
        int pos = atomicAdd(&cursor[r], 1);
        col_idx[row_ptr[r] + pos] = cols[t];
    }
}

// ---------------- init features ----------------
__global__ void k_init(const void* __restrict__ uf, const void* __restrict__ itf,
                       float* __restrict__ ui, float* __restrict__ hu, float* __restrict__ hi,
                       const ll nu64, const ll ntot64, const int* __restrict__ flag) {
    ll t = (ll)blockIdx.x * blockDim.x + threadIdx.x;
    int bf = *flag;
    if (t < nu64) {
        float v = load_in(uf, t, bf);
        ui[t] = v; hu[t] = v;
    } else if (t < ntot64) {
        ll j = t - nu64;
        float v = load_in(itf, j, bf);
        ui[t] = v; hi[j] = v;
    }
}

// ---------------- gather SpMM (2 independent acc chains, 8-unroll) ----------
__global__ __launch_bounds__(256) void k_gather(const int* __restrict__ row_ptr,
                                                const int* __restrict__ col_idx,
                                                const float* __restrict__ x,
                                                const float* __restrict__ cnorm,
                                                const float* __restrict__ rnorm,
                                                float* __restrict__ out, const int nrows) {
    ll gt = (ll)blockIdx.x * blockDim.x + threadIdx.x;
    int w = (int)(gt >> 6);
    int d = (int)(gt & 63);
    if (w >= nrows) return;
    int s = row_ptr[w], e = row_ptr[w + 1];
    float accA = 0.0f, accB = 0.0f;
    int j = s;
    for (; j + 8 <= e; j += 8) {
        int c0 = col_idx[j],     c1 = col_idx[j + 1], c2 = col_idx[j + 2], c3 = col_idx[j + 3];
        int c4 = col_idx[j + 4], c5 = col_idx[j + 5], c6 = col_idx[j + 6], c7 = col_idx[j + 7];
        float n0 = cnorm[c0], n1 = cnorm[c1], n2 = cnorm[c2], n3 = cnorm[c3];
        float n4 = cnorm[c4], n5 = cnorm[c5], n6 = cnorm[c6], n7 = cnorm[c7];
        float x0 = x[(ll)c0 * 64 + d], x1 = x[(ll)c1 * 64 + d];
        float x2 = x[(ll)c2 * 64 + d], x3 = x[(ll)c3 * 64 + d];
        float x4 = x[(ll)c4 * 64 + d], x5 = x[(ll)c5 * 64 + d];
        float x6 = x[(ll)c6 * 64 + d], x7 = x[(ll)c7 * 64 + d];
        accA += x0 * n0 + x2 * n2 + x4 * n4 + x6 * n6;
        accB += x1 * n1 + x3 * n3 + x5 * n5 + x7 * n7;
    }
    for (; j + 2 <= e; j += 2) {
        int c0 = col_idx[j], c1 = col_idx[j + 1];
        accA += x[(ll)c0 * 64 + d] * cnorm[c0];
        accB += x[(ll)c1 * 64 + d] * cnorm[c1];
    }
    if (j < e) {
        int c = col_idx[j];
        accA += x[(ll)c * 64 + d] * cnorm[c];
    }
    out[(ll)w * 64 + d] = (accA + accB) * rnorm[w];
}

// ---------------- fast tanh ----------
__device__ __forceinline__ float fast_tanh(float x) {
    return 1.0f - 2.0f / (__expf(2.0f * x) + 1.0f);
}

// ---------------- semantic attention, h-sliced, 4 ILP chains ----------------
__global__ __launch_bounds__(256) void k_attn(const float* __restrict__ z1, const float* __restrict__ z2,
                                              const float* __restrict__ W1t,
                                              const float* __restrict__ b1,
                                              const float* __restrict__ w2,
                                              const int n, float* __restrict__ wsum) {
    __shared__ float Ws[32 * 64];
    __shared__ float bs[32];
    __shared__ float ws2[32];
    __shared__ float red0[4], red1[4];

    int tid = threadIdx.x;
    int hs = blockIdx.y * 32;
    for (int i = tid; i < 32 * 64; i += 256) Ws[i] = W1t[hs * 64 + i];
    if (tid < 32) { bs[tid] = b1[hs + tid]; ws2[tid] = w2[hs + tid]; }
    __syncthreads();

    int v = blockIdx.x * 256 + tid;
    float w0 = 0.0f, w1 = 0.0f;
    if (v < n) {
        float4 zv[16];
        {
            const float4* zp = (const float4*)&z1[(ll)v * 64];
#pragma unroll
            for (int q = 0; q < 16; q++) zv[q] = zp[q];
            for (int h = 0; h < 32; h++) {
                const float4* wr = (const float4*)&Ws[h * 64];
                float p0 = bs[h], p1 = 0.0f, p2 = 0.0f, p3 = 0.0f;
#pragma unroll
                for (int q = 0; q < 16; q += 4) {
                    float4 a0 = wr[q],     a1 = wr[q + 1], a2 = wr[q + 2], a3 = wr[q + 3];
                    p0 += zv[q].x * a0.x + zv[q].y * a0.y + zv[q].z * a0.z + zv[q].w * a0.w;
                    p1 += zv[q + 1].x * a1.x + zv[q + 1].y * a1.y + zv[q + 1].z * a1.z + zv[q + 1].w * a1.w;
                    p2 += zv[q + 2].x * a2.x + zv[q + 2].y * a2.y + zv[q + 2].z * a2.z + zv[q + 2].w * a2.w;
                    p3 += zv[q + 3].x * a3.x + zv[q + 3].y * a3.y + zv[q + 3].z * a3.z + zv[q + 3].w * a3.w;
                }
                float acc = (p0 + p1) + (p2 + p3);
                w0 += fast_tanh(acc) * ws2[h];
            }
        }
        {
            const float4* zp = (const float4*)&z2[(ll)v * 64];
#pragma unroll
            for (int q = 0; q < 16; q++) zv[q] = zp[q];
            for (int h = 0; h < 32; h++) {
                const float4* wr = (const float4*)&Ws[h * 64];
                float p0 = bs[h], p1 = 0.0f, p2 = 0.0f, p3 = 0.0f;
#pragma unroll
                for (int q = 0; q < 16; q += 4) {
                    float4 a0 = wr[q],     a1 = wr[q + 1], a2 = wr[q + 2], a3 = wr[q + 3];
                    p0 += zv[q].x * a0.x + zv[q].y * a0.y + zv[q].z * a0.z + zv[q].w * a0.w;
                    p1 += zv[q + 1].x * a1.x + zv[q + 1].y * a1.y + zv[q + 1].z * a1.z + zv[q + 1].w * a1.w;
                    p2 += zv[q + 2].x * a2.x + zv[q + 2].y * a2.y + zv[q + 2].z * a2.z + zv[q + 2].w * a2.w;
                    p3 += zv[q + 3].x * a3.x + zv[q + 3].y * a3.y + zv[q + 3].z * a3.z + zv[q + 3].w * a3.w;
                }
                float acc = (p0 + p1) + (p2 + p3);
                w1 += fast_tanh(acc) * ws2[h];
            }
        }
    }
    for (int off = 32; off > 0; off >>= 1) {
        w0 += __shfl_down(w0, off);
        w1 += __shfl_down(w1, off);
    }
    int wave = tid >> 6;
    int lane = tid & 63;
    if (lane == 0) { red0[wave] = w0; red1[wave] = w1; }
    __syncthreads();
    if (tid == 0) {
        float a = red0[0] + red0[1] + red0[2] + red0[3];
        float b = red1[0] + red1[1] + red1[2] + red1[3];
        atomicAdd(&wsum[0], a);
        atomicAdd(&wsum[1], b);
    }
}

__global__ void k_beta(const float* __restrict__ wsum, const float inv_n, float* __restrict__ beta) {
    if (blockIdx.x == 0 && threadIdx.x == 0) {
        float m0 = wsum[0] * inv_n, m1 = wsum[1] * inv_n;
        float mx = fmaxf(m0, m1);
        float e0 = expf(m0 - mx), e1 = expf(m1 - mx);
        float s = e0 + e1;
        beta[0] = e0 / s;
        beta[1] = e1 / s;
    }
}

__global__ void k_combine(const float* __restrict__ z1, const float* __restrict__ z2,
                          const float* __restrict__ beta, float* __restrict__ h, const ll n64) {
    ll t = (ll)blockIdx.x * blockDim.x + threadIdx.x;
    if (t < n64) h[t] = beta[0] * z1[t] + beta[1] * z2[t];
}

// ---------------- final gathers ----------------
__device__ __forceinline__ void store_out(void* out, ll i, float v, int isbf16) {
    if (isbf16) ((__hip_bfloat16*)out)[i] = __float2bfloat16(v);
    else ((float*)out)[i] = v;
}
__device__ __forceinline__ float load_out(const void* out, ll i, int isbf16) {
    if (isbf16) return __bfloat162float(((const __hip_bfloat16*)out)[i]);
    return ((const float*)out)[i];
}

__global__ void k_out1(const float* __restrict__ hu, const float* __restrict__ hi,
                       const float* __restrict__ ui, const int* __restrict__ user_idx,
                       const int* __restrict__ item_idx, void* __restrict__ out,
                       const int B, const ll U, const int* __restrict__ flag) {
    ll t = (ll)blockIdx.x * blockDim.x + threadIdx.x;
    int bf = *flag;
    int d = (int)(t & 63);
    ll b = t >> 6;
    if (b < B) {
        int u = user_idx[b];
        float v = 0.5f * hu[(ll)u * 64 + d] + 0.5f * ui[(ll)u * 64 + d];
        store_out(out, b * 64 + d, v, bf);
    } else if (b < 2 * (ll)B) {
        ll bb = b - B;
        int it = item_idx[bb];
        float v = 0.5f * hi[(ll)it * 64 + d] + 0.5f * ui[(U + it) * 64 + d];
        store_out(out, (ll)B * 64 + bb * 64 + d, v, bf);
    }
}

__global__ void k_out2(void* __restrict__ out, const int* __restrict__ neg_idx, const int B,
                       const int* __restrict__ flag) {
    ll t = (ll)blockIdx.x * blockDim.x + threadIdx.x;
    int bf = *flag;
    if (t < (ll)B * 64) {
        ll b = t >> 6;
        int d = (int)(t & 63);
        int nb = neg_idx[b];
        float v = load_out(out, (ll)B * 64 + (ll)nb * 64 + d, bf);
        store_out(out, (ll)2 * B * 64 + t, v, bf);
    }
}

extern "C" void kernel_launch(void* const* d_in, const int* in_sizes, int n_in,
                              void* d_out, int out_size, void* d_ws, size_t ws_size,
                              hipStream_t stream) {
    const int D = 64;
    const ll U = in_sizes[0] / D;
    const ll I = in_sizes[1] / D;
    const ll N = U + I;
    const ll E2  = in_sizes[8] / 2;
    const ll EU1 = in_sizes[9] / 2;
    const ll EU2 = in_sizes[10] / 2;
    const ll EI1 = in_sizes[11] / 2;
    const ll EI2 = in_sizes[12] / 2;
    const int B = in_sizes[13];

    const void* user_feat = d_in[0];
    const void* item_feat = d_in[1];
    const void* sa_u_W1 = d_in[2];
    const void* sa_u_b1 = d_in[3];
    const void* sa_u_w2 = d_in[4];
    const void* sa_i_W1 = d_in[5];
    const void* sa_i_b1 = d_in[6];
    const void* sa_i_w2 = d_in[7];
    const int* ui_row = (const int*)d_in[8];
    const int* ui_col = ui_row + E2;
    const int* u1_src = (const int*)d_in[9];
    const int* u1_dst = u1_src + EU1;
    const int* u2_src = (const int*)d_in[10];
    const int* u2_dst = u2_src + EU2;
    const int* i1_src = (const int*)d_in[11];
    const int* i1_dst = i1_src + EI1;
    const int* i2_src = (const int*)d_in[12];
    const int* i2_dst = i2_src + EI2;
    const int* user_idx = (const int*)d_in[13];
    const int* item_idx = (const int*)d_in[14];
    const int* neg_idx  = (const int*)d_in[15];

    // ---------------- workspace layout ----------------
    float* p = (float*)d_ws;
    float* ui0 = p;  p += N * 64;
    float* ui1 = p;  p += N * 64;
    float* hu  = p;  p += U * 64;
    float* hi  = p;  p += I * 64;
    float* z1  = p;  p += I * 64;
    float* z2  = p;  p += I * 64;
    float* dinv = p; p += N;
    float* n_u1r = p; p += U;  float* n_u1s = p; p += U;
    float* n_u2r = p; p += U;  float* n_u2s = p; p += U;
    float* n_i1r = p; p += I;  float* n_i1s = p; p += I;
    float* n_i2r = p; p += I;  float* n_i2s = p; p += I;
    float* wW1u = p; p += 64 * 128;   // transposed [128][64]
    float* wb1u = p; p += 128;
    float* ww2u = p; p += 128;
    float* wW1i = p; p += 64 * 128;
    float* wb1i = p; p += 128;
    float* ww2i = p; p += 128;
    float* scratch = p; p += 16;

    int* ip = (int*)p;
    int* cnt_ui = ip; ip += N;
    int* c_u1r = ip; ip += U;  int* c_u1s = ip; ip += U;
    int* c_u2r = ip; ip += U;  int* c_u2s = ip; ip += U;
    int* c_i1r = ip; ip += I;  int* c_i1s = ip; ip += I;
    int* c_i2r = ip; ip += I;  int* c_i2s = ip; ip += I;
    int* cur_ui = ip; ip += N;
    int* cur_u1 = ip; ip += U;  int* cur_u2 = ip; ip += U;
    int* cur_i1 = ip; ip += I;  int* cur_i2 = ip; ip += I;
    size_t zero_ints = (size_t)(ip - cnt_ui);
    int* rp_ui = ip; ip += N + 1;
    int* rp_u1 = ip; ip += U + 1;  int* rp_u2 = ip; ip += U + 1;
    int* rp_i1 = ip; ip += I + 1;  int* rp_i2 = ip; ip += I + 1;
    int* ci_ui = ip; ip += E2;
    int* ci_u1 = ip; ip += EU1;  int* ci_u2 = ip; ip += EU2;
    int* ci_i1 = ip; ip += EI1;  int* ci_i2 = ip; ip += EI2;
    int* bsum = ip; ip += 256;
    int* flag = ip; ip += 4;
    size_t needed = (size_t)((char*)ip - (char*)d_ws);
    if (ws_size < needed) return;

    const int T = 256;

    // ---------------- dtype detection + weight conversion ----------------
    k_detect<<<1, 256, 0, stream>>>((const unsigned int*)user_feat, (ll)in_sizes[0] / 2, flag);
    k_cvtT<<<cdiv_ll(64 * 128, T), T, 0, stream>>>(sa_u_W1, wW1u, flag);
    k_cvt<<<1, 128, 0, stream>>>(sa_u_b1, wb1u, 128, flag);
    k_cvt<<<1, 128, 0, stream>>>(sa_u_w2, ww2u, 128, flag);
    k_cvtT<<<cdiv_ll(64 * 128, T), T, 0, stream>>>(sa_i_W1, wW1i, flag);
    k_cvt<<<1, 128, 0, stream>>>(sa_i_b1, wb1i, 128, flag);
    k_cvt<<<1, 128, 0, stream>>>(sa_i_w2, ww2i, 128, flag);

    // ---------------- counts ----------------
    hipMemsetAsync(cnt_ui, 0, zero_ints * sizeof(int), stream);
    hipMemsetAsync(scratch, 0, 16 * sizeof(float), stream);
    k_count1<<<cdiv_ll(E2, T), T, 0, stream>>>(ui_row, E2, cnt_ui);
    k_count2<<<cdiv_ll(EU1, T), T, 0, stream>>>(u1_src, u1_dst, EU1, c_u1s, c_u1r);
    k_count2<<<cdiv_ll(EU2, T), T, 0, stream>>>(u2_src, u2_dst, EU2, c_u2s, c_u2r);
    k_count2<<<cdiv_ll(EI1, T), T, 0, stream>>>(i1_src, i1_dst, EI1, c_i1s, c_i1r);
    k_count2<<<cdiv_ll(EI2, T), T, 0, stream>>>(i2_src, i2_dst, EI2, c_i2s, c_i2r);

    // ---------------- norms ----------------
    k_norm_gcn<<<cdiv_ll(N, T), T, 0, stream>>>(cnt_ui, dinv, (int)N);
    k_norm_conv<<<cdiv_ll(U, T), T, 0, stream>>>(c_u1r, n_u1r, (int)U);
    k_norm_conv<<<cdiv_ll(U, T), T, 0, stream>>>(c_u1s, n_u1s, (int)U);
    k_norm_conv<<<cdiv_ll(U, T), T, 0, stream>>>(c_u2r, n_u2r, (int)U);
    k_norm_conv<<<cdiv_ll(U, T), T, 0, stream>>>(c_u2s, n_u2s, (int)U);
    k_norm_conv<<<cdiv_ll(I, T), T, 0, stream>>>(c_i1r, n_i1r, (int)I);
    k_norm_conv<<<cdiv_ll(I, T), T, 0, stream>>>(c_i1s, n_i1s, (int)I);
    k_norm_conv<<<cdiv_ll(I, T), T, 0, stream>>>(c_i2r, n_i2r, (int)I);
    k_norm_conv<<<cdiv_ll(I, T), T, 0, stream>>>(c_i2s, n_i2s, (int)I);

    // ---------------- scans ----------------
    auto scan = [&](const int* cnt, int n, int* rp, int E) {
        int nb = (n + SCAN_CHUNK - 1) / SCAN_CHUNK;
        k_scanA<<<nb, SCAN_T, 0, stream>>>(cnt, n, rp, bsum);
        k_scanB<<<1, 256, 0, stream>>>(bsum, nb);
        k_scanC<<<cdiv_ll(n, T), T, 0, stream>>>(rp, n, bsum, E);
    };
    scan(cnt_ui, (int)N, rp_ui, (int)E2);
    scan(c_u1r, (int)U, rp_u1, (int)EU1);
    scan(c_u2r, (int)U, rp_u2, (int)EU2);
    scan(c_i1r, (int)I, rp_i1, (int)EI1);
    scan(c_i2r, (int)I, rp_i2, (int)EI2);

    // ---------------- fill ----------------
    k_fill<<<cdiv_ll(E2, T), T, 0, stream>>>(ui_row, ui_col, E2, rp_ui, cur_ui, ci_ui);
    k_fill<<<cdiv_ll(EU1, T), T, 0, stream>>>(u1_dst, u1_src, EU1, rp_u1, cur_u1, ci_u1);
    k_fill<<<cdiv_ll(EU2, T), T, 0, stream>>>(u2_dst, u2_src, EU2, rp_u2, cur_u2, ci_u2);
    k_fill<<<cdiv_ll(EI1, T), T, 0, stream>>>(i1_dst, i1_src, EI1, rp_i1, cur_i1, ci_i1);
    k_fill<<<cdiv_ll(EI2, T), T, 0, stream>>>(i2_dst, i2_src, EI2, rp_i2, cur_i2, ci_i2);

    // ---------------- init features ----------------
    k_init<<<cdiv_ll(N * 64, T), T, 0, stream>>>(user_feat, item_feat, ui0, hu, hi, U * 64, N * 64, flag);

    float* uiA = ui0;
    float* uiB = ui1;

    dim3 gau(cdiv_ll(U, 256), 4);
    dim3 gai(cdiv_ll(I, 256), 4);

    for (int layer = 0; layer < 2; layer++) {
        // ---- gcn_spmm ----
        k_gather<<<cdiv_ll(N * 64, T), T, 0, stream>>>(rp_ui, ci_ui, uiA, dinv, dinv, uiB, (int)N);
        { float* tmp = uiA; uiA = uiB; uiB = tmp; }

        // ---- HAN: users ----
        k_gather<<<cdiv_ll(U * 64, T), T, 0, stream>>>(rp_u1, ci_u1, hu, n_u1s, n_u1r, z1, (int)U);
        k_gather<<<cdiv_ll(U * 64, T), T, 0, stream>>>(rp_u2, ci_u2, hu, n_u2s, n_u2r, z2, (int)U);
        hipMemsetAsync(scratch, 0, 2 * sizeof(float), stream);
        k_attn<<<gau, T, 0, stream>>>(z1, z2, wW1u, wb1u, ww2u, (int)U, scratch);
        k_beta<<<1, 64, 0, stream>>>(scratch, 1.0f / (float)U, scratch + 2);
        k_combine<<<cdiv_ll(U * 64, T), T, 0, stream>>>(z1, z2, scratch + 2, hu, U * 64);

        // ---- HAN: items ----
        k_gather<<<cdiv_ll(I * 64, T), T, 0, stream>>>(rp_i1, ci_i1, hi, n_i1s, n_i1r, z1, (int)I);
        k_gather<<<cdiv_ll(I * 64, T), T, 0, stream>>>(rp_i2, ci_i2, hi, n_i2s, n_i2r, z2, (int)I);
        hipMemsetAsync(scratch, 0, 2 * sizeof(float), stream);
        k_attn<<<gai, T, 0, stream>>>(z1, z2, wW1i, wb1i, ww2i, (int)I, scratch);
        k_beta<<<1, 64, 0, stream>>>(scratch, 1.0f / (float)I, scratch + 2);
        k_combine<<<cdiv_ll(I * 64, T), T, 0, stream>>>(z1, z2, scratch + 2, hi, I * 64);
    }

    // ---------------- final ----------------
    k_out1<<<cdiv_ll((ll)2 * B * 64, T), T, 0, stream>>>(hu, hi, uiA, user_idx, item_idx, d_out, B, U, flag);
    k_out2<<<cdiv_ll((ll)B * 64, T), T, 0, stream>>>(d_out, neg_idx, B, flag);
}

// Round 6
// 1516.901 us; speedup vs baseline: 2.3630x; 1.1531x over previous
//
#include <hip/hip_runtime.h>
#include <hip/hip_bf16.h>

typedef long long ll;
typedef __attribute__((ext_vector_type(8))) short bf16x8;
typedef __attribute__((ext_vector_type(4))) float f32x4;

static inline int cdiv_ll(ll a, int b) { return (int)((a + (ll)b - 1) / (ll)b); }

// ---------------- dtype detection (bf16 vs fp32 inputs) ----------------
__global__ void k_detect(const unsigned int* __restrict__ dw, const ll n_dw, int* __restrict__ flag) {
    __shared__ int sc[256];
    int tid = threadIdx.x;
    int cnt = 0;
    for (int s = 0; s < 32; s++) {
        ll idx = (ll)(s * 256 + tid);
        ll i = (idx * n_dw) / 8192;
        unsigned v = dw[i];
        unsigned lo = v & 0xFFFFu;
        unsigned ex = (lo >> 7) & 0xFFu;
        bool pl = (lo == 0u) || (lo == 0x8000u) || (ex >= 0x60u && ex <= 0x8Fu);
        cnt += pl ? 1 : 0;
    }
    sc[tid] = cnt;
    __syncthreads();
    for (int o = 128; o > 0; o >>= 1) { if (tid < o) sc[tid] += sc[tid + o]; __syncthreads(); }
    if (tid == 0) *flag = (sc[0] * 2 > 8192) ? 1 : 0;
}

__device__ __forceinline__ float load_in(const void* p, ll i, int isbf16) {
    if (isbf16) return __bfloat162float(((const __hip_bfloat16*)p)[i]);
    return ((const float*)p)[i];
}

// round-to-nearest-even fp32 -> bf16 bits (finite inputs)
__device__ __forceinline__ unsigned short f2bf(float f) {
    unsigned u = __float_as_uint(f);
    unsigned r = (u + 0x7FFFu + ((u >> 16) & 1u)) >> 16;
    return (unsigned short)r;
}

__global__ void k_cvt(const void* __restrict__ src, float* __restrict__ dst, const int n,
                      const int* __restrict__ flag) {
    int i = blockIdx.x * blockDim.x + threadIdx.x;
    int bf = *flag;
    if (i < n) dst[i] = load_in(src, i, bf);
}

// transpose-convert W1 [64 x 128] -> bf16 W1t [128 x 64]
__global__ void k_cvtT(const void* __restrict__ src, unsigned short* __restrict__ dst,
                       const int* __restrict__ flag) {
    int i = blockIdx.x * blockDim.x + threadIdx.x;
    int bf = *flag;
    if (i < 64 * 128) {
        int d = i >> 7, h = i & 127;
        dst[h * 64 + d] = f2bf(load_in(src, i, bf));
    }
}

// ---------------- CSR build: count ----------------
__global__ void k_count1(const int* __restrict__ rows, const ll E, int* __restrict__ cnt) {
    ll t = (ll)blockIdx.x * blockDim.x + threadIdx.x;
    if (t < E) atomicAdd(&cnt[rows[t]], 1);
}

__global__ void k_count2(const int* __restrict__ src, const int* __restrict__ dst, const ll E,
                         int* __restrict__ cnt_src, int* __restrict__ cnt_dst) {
    ll t = (ll)blockIdx.x * blockDim.x + threadIdx.x;
    if (t < E) {
        atomicAdd(&cnt_src[src[t]], 1);
        atomicAdd(&cnt_dst[dst[t]], 1);
    }
}

// ---------------- norms from int degrees ----------------
__global__ void k_norm_gcn(const int* __restrict__ cnt, float* __restrict__ o, const int n) {
    int i = blockIdx.x * blockDim.x + threadIdx.x;
    if (i < n) { int c = cnt[i]; o[i] = (c > 0) ? (1.0f / sqrtf((float)c)) : 0.0f; }
}

__global__ void k_norm_conv(const int* __restrict__ cnt, float* __restrict__ o, const int n) {
    int i = blockIdx.x * blockDim.x + threadIdx.x;
    if (i < n) o[i] = 1.0f / sqrtf(fmaxf((float)cnt[i], 1.0f));
}

// ---------------- hierarchical exclusive scan ----------
#define SCAN_T 256
#define SCAN_ELEMS 8
#define SCAN_CHUNK (SCAN_T * SCAN_ELEMS)   // 2048

__global__ __launch_bounds__(256) void k_scanA(const int* __restrict__ in, const int n,
                                               int* __restrict__ out, int* __restrict__ bsum) {
    __shared__ int sh[SCAN_T];
    int t = threadIdx.x;
    ll base = (ll)blockIdx.x * SCAN_CHUNK + (ll)t * SCAN_ELEMS;
    int v[SCAN_ELEMS];
    int tot = 0;
#pragma unroll
    for (int k = 0; k < SCAN_ELEMS; k++) {
        ll i = base + k;
        v[k] = (i < n) ? in[i] : 0;
        tot += v[k];
    }
    sh[t] = tot;
    __syncthreads();
    for (int off = 1; off < SCAN_T; off <<= 1) {
        int x = (t >= off) ? sh[t - off] : 0;
        __syncthreads();
        sh[t] += x;
        __syncthreads();
    }
    int run = sh[t] - tot;
#pragma unroll
    for (int k = 0; k < SCAN_ELEMS; k++) {
        ll i = base + k;
        if (i < n) out[i] = run;
        run += v[k];
    }
    if (t == SCAN_T - 1) bsum[blockIdx.x] = sh[SCAN_T - 1];
}

__global__ __launch_bounds__(256) void k_scanB(int* __restrict__ bsum, const int nb) {
    __shared__ int sh[256];
    int t = threadIdx.x;
    int running = 0;
    for (int base = 0; base < nb; base += 256) {
        int idx = base + t;
        int v = (idx < nb) ? bsum[idx] : 0;
        sh[t] = v;
        __syncthreads();
        for (int off = 1; off < 256; off <<= 1) {
            int x = (t >= off) ? sh[t - off] : 0;
            __syncthreads();
            sh[t] += x;
            __syncthreads();
        }
        if (idx < nb) bsum[idx] = running + sh[t] - v;
        int tot = sh[255];
        __syncthreads();
        running += tot;
    }
}

__global__ void k_scanC(int* __restrict__ out, const int n, const int* __restrict__ bsum, const int E) {
    ll i = (ll)blockIdx.x * blockDim.x + threadIdx.x;
    if (i < n) out[i] += bsum[i / SCAN_CHUNK];
    if (i == 0) out[n] = E;
}

// ---------------- CSR fill ----------------
__global__ void k_fill(const int* __restrict__ rows, const int* __restrict__ cols, const ll E,
                       const int* __restrict__ row_ptr, int* __restrict__ cursor,
                       int* __restrict__ col_idx) {
    ll t = (ll)blockIdx.x * blockDim.x + threadIdx.x;
    if (t < E) {
        int r = rows[t];
        int pos = atomicAdd(&cursor[r], 1);
        col_idx[row_ptr[r] + pos] = cols[t];
    }
}

// ---------------- init features ----------------
__global__ void k_init(const void* __restrict__ uf, const void* __restrict__ itf,
                       float* __restrict__ ui, float* __restrict__ hu, float* __restrict__ hi,
                       const ll nu64, const ll ntot64, const int* __restrict__ flag) {
    ll t = (ll)blockIdx.x * blockDim.x + threadIdx.x;
    int bf = *flag;
    if (t < nu64) {
        float v = load_in(uf, t, bf);
        ui[t] = v; hu[t] = v;
    } else if (t < ntot64) {
        ll j = t - nu64;
        float v = load_in(itf, j, bf);
        ui[t] = v; hi[j] = v;
    }
}

// ---------------- gather SpMM (2 independent acc chains, 8-unroll) ----------
__global__ __launch_bounds__(256) void k_gather(const int* __restrict__ row_ptr,
                                                const int* __restrict__ col_idx,
                                                const float* __restrict__ x,
                                                const float* __restrict__ cnorm,
                                                const float* __restrict__ rnorm,
                                                float* __restrict__ out, const int nrows) {
    ll gt = (ll)blockIdx.x * blockDim.x + threadIdx.x;
    int w = (int)(gt >> 6);
    int d = (int)(gt & 63);
    if (w >= nrows) return;
    int s = row_ptr[w], e = row_ptr[w + 1];
    float accA = 0.0f, accB = 0.0f;
    int j = s;
    for (; j + 8 <= e; j += 8) {
        int c0 = col_idx[j],     c1 = col_idx[j + 1], c2 = col_idx[j + 2], c3 = col_idx[j + 3];
        int c4 = col_idx[j + 4], c5 = col_idx[j + 5], c6 = col_idx[j + 6], c7 = col_idx[j + 7];
        float n0 = cnorm[c0], n1 = cnorm[c1], n2 = cnorm[c2], n3 = cnorm[c3];
        float n4 = cnorm[c4], n5 = cnorm[c5], n6 = cnorm[c6], n7 = cnorm[c7];
        float x0 = x[(ll)c0 * 64 + d], x1 = x[(ll)c1 * 64 + d];
        float x2 = x[(ll)c2 * 64 + d], x3 = x[(ll)c3 * 64 + d];
        float x4 = x[(ll)c4 * 64 + d], x5 = x[(ll)c5 * 64 + d];
        float x6 = x[(ll)c6 * 64 + d], x7 = x[(ll)c7 * 64 + d];
        accA += x0 * n0 + x2 * n2 + x4 * n4 + x6 * n6;
        accB += x1 * n1 + x3 * n3 + x5 * n5 + x7 * n7;
    }
    for (; j + 2 <= e; j += 2) {
        int c0 = col_idx[j], c1 = col_idx[j + 1];
        accA += x[(ll)c0 * 64 + d] * cnorm[c0];
        accB += x[(ll)c1 * 64 + d] * cnorm[c1];
    }
    if (j < e) {
        int c = col_idx[j];
        accA += x[(ll)c * 64 + d] * cnorm[c];
    }
    out[(ll)w * 64 + d] = (accA + accB) * rnorm[w];
}

// ---------------- fast tanh ----------
__device__ __forceinline__ float fast_tanh(float x) {
    return 1.0f - 2.0f / (__expf(2.0f * x) + 1.0f);
}

// pack 8 fp32 (two float4) into bf16x8
__device__ __forceinline__ bf16x8 pack8(float4 a, float4 b) {
    bf16x8 r;
    r[0] = (short)f2bf(a.x); r[1] = (short)f2bf(a.y);
    r[2] = (short)f2bf(a.z); r[3] = (short)f2bf(a.w);
    r[4] = (short)f2bf(b.x); r[5] = (short)f2bf(b.y);
    r[6] = (short)f2bf(b.z); r[7] = (short)f2bf(b.w);
    return r;
}

// ---------------- MFMA semantic-attention scores ----------------
// Computes wsum[m] += sum_{v<n} sum_h tanh( (z_m[v,:] @ W1)[h] + b1[h] ) * w2[h]
// W held entirely in B-fragment registers (64 VGPR/lane). A-frags built from
// fp32 z via bf16 round. C/D layout (m89): col=lane&15, row=(lane>>4)*4+reg.
// A layout: A[m=lane&15][k=(lane>>4)*8+j]; B: B[k=(lane>>4)*8+j][ncol=lane&15].
__global__ __launch_bounds__(256) void k_attn_mfma(const float* __restrict__ z1,
                                                   const float* __restrict__ z2,
                                                   const unsigned short* __restrict__ Wb,  // [128][64] bf16
                                                   const float* __restrict__ b1f,
                                                   const float* __restrict__ w2f,
                                                   const int n, float* __restrict__ wsum) {
    __shared__ float red0[4], red1[4];
    int tid = threadIdx.x;
    int lane = tid & 63;
    int wid = tid >> 6;
    int col = lane & 15;
    int quad = lane >> 4;

    // B-fragments for all 8 h-tiles x 2 k-steps: W[k][h] = Wb[h*64+k]
    bf16x8 wb[8][2];
#pragma unroll
    for (int ht = 0; ht < 8; ht++) {
        int h = ht * 16 + col;
#pragma unroll
        for (int ks = 0; ks < 2; ks++) {
            wb[ht][ks] = *(const bf16x8*)&Wb[h * 64 + ks * 32 + quad * 8];
        }
    }
    float b1v[8], w2v[8];
#pragma unroll
    for (int ht = 0; ht < 8; ht++) {
        b1v[ht] = b1f[ht * 16 + col];
        w2v[ht] = w2f[ht * 16 + col];
    }

    float w0 = 0.0f, w1 = 0.0f;
    int ntiles = (n + 15) >> 4;
    int gw = blockIdx.x * 4 + wid;
    int nw = gridDim.x * 4;
    const float4 zero4 = make_float4(0.f, 0.f, 0.f, 0.f);

    for (int tile = gw; tile < ntiles; tile += nw) {
        int nodeA = tile * 16 + col;
        bool va = nodeA < n;
        bf16x8 a1[2], a2[2];
#pragma unroll
        for (int ks = 0; ks < 2; ks++) {
            const float4* p1 = (const float4*)&z1[(ll)nodeA * 64 + ks * 32 + quad * 8];
            const float4* p2 = (const float4*)&z2[(ll)nodeA * 64 + ks * 32 + quad * 8];
            float4 f0 = va ? p1[0] : zero4;
            float4 f1 = va ? p1[1] : zero4;
            float4 g0 = va ? p2[0] : zero4;
            float4 g1 = va ? p2[1] : zero4;
            a1[ks] = pack8(f0, f1);
            a2[ks] = pack8(g0, g1);
        }
#pragma unroll
        for (int ht = 0; ht < 8; ht++) {
            f32x4 c1 = {0.f, 0.f, 0.f, 0.f};
            f32x4 c2 = {0.f, 0.f, 0.f, 0.f};
            c1 = __builtin_amdgcn_mfma_f32_16x16x32_bf16(a1[0], wb[ht][0], c1, 0, 0, 0);
            c1 = __builtin_amdgcn_mfma_f32_16x16x32_bf16(a1[1], wb[ht][1], c1, 0, 0, 0);
            c2 = __builtin_amdgcn_mfma_f32_16x16x32_bf16(a2[0], wb[ht][0], c2, 0, 0, 0);
            c2 = __builtin_amdgcn_mfma_f32_16x16x32_bf16(a2[1], wb[ht][1], c2, 0, 0, 0);
#pragma unroll
            for (int r = 0; r < 4; r++) {
                int node_row = tile * 16 + quad * 4 + r;
                bool vr = node_row < n;
                float t1 = fast_tanh(c1[r] + b1v[ht]) * w2v[ht];
                float t2 = fast_tanh(c2[r] + b1v[ht]) * w2v[ht];
                w0 += vr ? t1 : 0.0f;
                w1 += vr ? t2 : 0.0f;
            }
        }
    }

    for (int off = 32; off > 0; off >>= 1) {
        w0 += __shfl_down(w0, off);
        w1 += __shfl_down(w1, off);
    }
    if (lane == 0) { red0[wid] = w0; red1[wid] = w1; }
    __syncthreads();
    if (tid == 0) {
        atomicAdd(&wsum[0], red0[0] + red0[1] + red0[2] + red0[3]);
        atomicAdd(&wsum[1], red1[0] + red1[1] + red1[2] + red1[3]);
    }
}

__global__ void k_beta(const float* __restrict__ wsum, const float inv_n, float* __restrict__ beta) {
    if (blockIdx.x == 0 && threadIdx.x == 0) {
        float m0 = wsum[0] * inv_n, m1 = wsum[1] * inv_n;
        float mx = fmaxf(m0, m1);
        float e0 = expf(m0 - mx), e1 = expf(m1 - mx);
        float s = e0 + e1;
        beta[0] = e0 / s;
        beta[1] = e1 / s;
    }
}

__global__ void k_combine(const float* __restrict__ z1, const float* __restrict__ z2,
                          const float* __restrict__ beta, float* __restrict__ h, const ll n64) {
    ll t = (ll)blockIdx.x * blockDim.x + threadIdx.x;
    if (t < n64) h[t] = beta[0] * z1[t] + beta[1] * z2[t];
}

// ---------------- final gathers ----------------
__device__ __forceinline__ void store_out(void* out, ll i, float v, int isbf16) {
    if (isbf16) ((__hip_bfloat16*)out)[i] = __float2bfloat16(v);
    else ((float*)out)[i] = v;
}
__device__ __forceinline__ float load_out(const void* out, ll i, int isbf16) {
    if (isbf16) return __bfloat162float(((const __hip_bfloat16*)out)[i]);
    return ((const float*)out)[i];
}

__global__ void k_out1(const float* __restrict__ hu, const float* __restrict__ hi,
                       const float* __restrict__ ui, const int* __restrict__ user_idx,
                       const int* __restrict__ item_idx, void* __restrict__ out,
                       const int B, const ll U, const int* __restrict__ flag) {
    ll t = (ll)blockIdx.x * blockDim.x + threadIdx.x;
    int bf = *flag;
    int d = (int)(t & 63);
    ll b = t >> 6;
    if (b < B) {
        int u = user_idx[b];
        float v = 0.5f * hu[(ll)u * 64 + d] + 0.5f * ui[(ll)u * 64 + d];
        store_out(out, b * 64 + d, v, bf);
    } else if (b < 2 * (ll)B) {
        ll bb = b - B;
        int it = item_idx[bb];
        float v = 0.5f * hi[(ll)it * 64 + d] + 0.5f * ui[(U + it) * 64 + d];
        store_out(out, (ll)B * 64 + bb * 64 + d, v, bf);
    }
}

__global__ void k_out2(void* __restrict__ out, const int* __restrict__ neg_idx, const int B,
                       const int* __restrict__ flag) {
    ll t = (ll)blockIdx.x * blockDim.x + threadIdx.x;
    int bf = *flag;
    if (t < (ll)B * 64) {
        ll b = t >> 6;
        int d = (int)(t & 63);
        int nb = neg_idx[b];
        float v = load_out(out, (ll)B * 64 + (ll)nb * 64 + d, bf);
        store_out(out, (ll)2 * B * 64 + t, v, bf);
    }
}

extern "C" void kernel_launch(void* const* d_in, const int* in_sizes, int n_in,
                              void* d_out, int out_size, void* d_ws, size_t ws_size,
                              hipStream_t stream) {
    const int D = 64;
    const ll U = in_sizes[0] / D;
    const ll I = in_sizes[1] / D;
    const ll N = U + I;
    const ll E2  = in_sizes[8] / 2;
    const ll EU1 = in_sizes[9] / 2;
    const ll EU2 = in_sizes[10] / 2;
    const ll EI1 = in_sizes[11] / 2;
    const ll EI2 = in_sizes[12] / 2;
    const int B = in_sizes[13];

    const void* user_feat = d_in[0];
    const void* item_feat = d_in[1];
    const void* sa_u_W1 = d_in[2];
    const void* sa_u_b1 = d_in[3];
    const void* sa_u_w2 = d_in[4];
    const void* sa_i_W1 = d_in[5];
    const void* sa_i_b1 = d_in[6];
    const void* sa_i_w2 = d_in[7];
    const int* ui_row = (const int*)d_in[8];
    const int* ui_col = ui_row + E2;
    const int* u1_src = (const int*)d_in[9];
    const int* u1_dst = u1_src + EU1;
    const int* u2_src = (const int*)d_in[10];
    const int* u2_dst = u2_src + EU2;
    const int* i1_src = (const int*)d_in[11];
    const int* i1_dst = i1_src + EI1;
    const int* i2_src = (const int*)d_in[12];
    const int* i2_dst = i2_src + EI2;
    const int* user_idx = (const int*)d_in[13];
    const int* item_idx = (const int*)d_in[14];
    const int* neg_idx  = (const int*)d_in[15];

    // ---------------- workspace layout ----------------
    float* p = (float*)d_ws;
    float* ui0 = p;  p += N * 64;
    float* ui1 = p;  p += N * 64;
    float* hu  = p;  p += U * 64;
    float* hi  = p;  p += I * 64;
    float* z1  = p;  p += I * 64;
    float* z2  = p;  p += I * 64;
    float* dinv = p; p += N;
    float* n_u1r = p; p += U;  float* n_u1s = p; p += U;
    float* n_u2r = p; p += U;  float* n_u2s = p; p += U;
    float* n_i1r = p; p += I;  float* n_i1s = p; p += I;
    float* n_i2r = p; p += I;  float* n_i2s = p; p += I;
    unsigned short* Wbu = (unsigned short*)p; p += 64 * 128 / 2;  // bf16 [128][64]
    unsigned short* Wbi = (unsigned short*)p; p += 64 * 128 / 2;
    float* wb1u = p; p += 128;
    float* ww2u = p; p += 128;
    float* wb1i = p; p += 128;
    float* ww2i = p; p += 128;
    float* scratch = p; p += 16;

    int* ip = (int*)p;
    int* cnt_ui = ip; ip += N;
    int* c_u1r = ip; ip += U;  int* c_u1s = ip; ip += U;
    int* c_u2r = ip; ip += U;  int* c_u2s = ip; ip += U;
    int* c_i1r = ip; ip += I;  int* c_i1s = ip; ip += I;
    int* c_i2r = ip; ip += I;  int* c_i2s = ip; ip += I;
    int* cur_ui = ip; ip += N;
    int* cur_u1 = ip; ip += U;  int* cur_u2 = ip; ip += U;
    int* cur_i1 = ip; ip += I;  int* cur_i2 = ip; ip += I;
    size_t zero_ints = (size_t)(ip - cnt_ui);
    int* rp_ui = ip; ip += N + 1;
    int* rp_u1 = ip; ip += U + 1;  int* rp_u2 = ip; ip += U + 1;
    int* rp_i1 = ip; ip += I + 1;  int* rp_i2 = ip; ip += I + 1;
    int* ci_ui = ip; ip += E2;
    int* ci_u1 = ip; ip += EU1;  int* ci_u2 = ip; ip += EU2;
    int* ci_i1 = ip; ip += EI1;  int* ci_i2 = ip; ip += EI2;
    int* bsum = ip; ip += 256;
    int* flag = ip; ip += 4;
    size_t needed = (size_t)((char*)ip - (char*)d_ws);
    if (ws_size < needed) return;

    const int T = 256;

    // ---------------- dtype detection + weight conversion ----------------
    k_detect<<<1, 256, 0, stream>>>((const unsigned int*)user_feat, (ll)in_sizes[0] / 2, flag);
    k_cvtT<<<cdiv_ll(64 * 128, T), T, 0, stream>>>(sa_u_W1, Wbu, flag);
    k_cvt<<<1, 128, 0, stream>>>(sa_u_b1, wb1u, 128, flag);
    k_cvt<<<1, 128, 0, stream>>>(sa_u_w2, ww2u, 128, flag);
    k_cvtT<<<cdiv_ll(64 * 128, T), T, 0, stream>>>(sa_i_W1, Wbi, flag);
    k_cvt<<<1, 128, 0, stream>>>(sa_i_b1, wb1i, 128, flag);
    k_cvt<<<1, 128, 0, stream>>>(sa_i_w2, ww2i, 128, flag);

    // ---------------- counts ----------------
    hipMemsetAsync(cnt_ui, 0, zero_ints * sizeof(int), stream);
    hipMemsetAsync(scratch, 0, 16 * sizeof(float), stream);
    k_count1<<<cdiv_ll(E2, T), T, 0, stream>>>(ui_row, E2, cnt_ui);
    k_count2<<<cdiv_ll(EU1, T), T, 0, stream>>>(u1_src, u1_dst, EU1, c_u1s, c_u1r);
    k_count2<<<cdiv_ll(EU2, T), T, 0, stream>>>(u2_src, u2_dst, EU2, c_u2s, c_u2r);
    k_count2<<<cdiv_ll(EI1, T), T, 0, stream>>>(i1_src, i1_dst, EI1, c_i1s, c_i1r);
    k_count2<<<cdiv_ll(EI2, T), T, 0, stream>>>(i2_src, i2_dst, EI2, c_i2s, c_i2r);

    // ---------------- norms ----------------
    k_norm_gcn<<<cdiv_ll(N, T), T, 0, stream>>>(cnt_ui, dinv, (int)N);
    k_norm_conv<<<cdiv_ll(U, T), T, 0, stream>>>(c_u1r, n_u1r, (int)U);
    k_norm_conv<<<cdiv_ll(U, T), T, 0, stream>>>(c_u1s, n_u1s, (int)U);
    k_norm_conv<<<cdiv_ll(U, T), T, 0, stream>>>(c_u2r, n_u2r, (int)U);
    k_norm_conv<<<cdiv_ll(U, T), T, 0, stream>>>(c_u2s, n_u2s, (int)U);
    k_norm_conv<<<cdiv_ll(I, T), T, 0, stream>>>(c_i1r, n_i1r, (int)I);
    k_norm_conv<<<cdiv_ll(I, T), T, 0, stream>>>(c_i1s, n_i1s, (int)I);
    k_norm_conv<<<cdiv_ll(I, T), T, 0, stream>>>(c_i2r, n_i2r, (int)I);
    k_norm_conv<<<cdiv_ll(I, T), T, 0, stream>>>(c_i2s, n_i2s, (int)I);

    // ---------------- scans ----------------
    auto scan = [&](const int* cnt, int n, int* rp, int E) {
        int nb = (n + SCAN_CHUNK - 1) / SCAN_CHUNK;
        k_scanA<<<nb, SCAN_T, 0, stream>>>(cnt, n, rp, bsum);
        k_scanB<<<1, 256, 0, stream>>>(bsum, nb);
        k_scanC<<<cdiv_ll(n, T), T, 0, stream>>>(rp, n, bsum, E);
    };
    scan(cnt_ui, (int)N, rp_ui, (int)E2);
    scan(c_u1r, (int)U, rp_u1, (int)EU1);
    scan(c_u2r, (int)U, rp_u2, (int)EU2);
    scan(c_i1r, (int)I, rp_i1, (int)EI1);
    scan(c_i2r, (int)I, rp_i2, (int)EI2);

    // ---------------- fill ----------------
    k_fill<<<cdiv_ll(E2, T), T, 0, stream>>>(ui_row, ui_col, E2, rp_ui, cur_ui, ci_ui);
    k_fill<<<cdiv_ll(EU1, T), T, 0, stream>>>(u1_dst, u1_src, EU1, rp_u1, cur_u1, ci_u1);
    k_fill<<<cdiv_ll(EU2, T), T, 0, stream>>>(u2_dst, u2_src, EU2, rp_u2, cur_u2, ci_u2);
    k_fill<<<cdiv_ll(EI1, T), T, 0, stream>>>(i1_dst, i1_src, EI1, rp_i1, cur_i1, ci_i1);
    k_fill<<<cdiv_ll(EI2, T), T, 0, stream>>>(i2_dst, i2_src, EI2, rp_i2, cur_i2, ci_i2);

    // ---------------- init features ----------------
    k_init<<<cdiv_ll(N * 64, T), T, 0, stream>>>(user_feat, item_feat, ui0, hu, hi, U * 64, N * 64, flag);

    float* uiA = ui0;
    float* uiB = ui1;

    const int ATTN_BLOCKS = 512;

    for (int layer = 0; layer < 2; layer++) {
        // ---- gcn_spmm ----
        k_gather<<<cdiv_ll(N * 64, T), T, 0, stream>>>(rp_ui, ci_ui, uiA, dinv, dinv, uiB, (int)N);
        { float* tmp = uiA; uiA = uiB; uiB = tmp; }

        // ---- HAN: users ----
        k_gather<<<cdiv_ll(U * 64, T), T, 0, stream>>>(rp_u1, ci_u1, hu, n_u1s, n_u1r, z1, (int)U);
        k_gather<<<cdiv_ll(U * 64, T), T, 0, stream>>>(rp_u2, ci_u2, hu, n_u2s, n_u2r, z2, (int)U);
        hipMemsetAsync(scratch, 0, 2 * sizeof(float), stream);
        k_attn_mfma<<<ATTN_BLOCKS, T, 0, stream>>>(z1, z2, Wbu, wb1u, ww2u, (int)U, scratch);
        k_beta<<<1, 64, 0, stream>>>(scratch, 1.0f / (float)U, scratch + 2);
        k_combine<<<cdiv_ll(U * 64, T), T, 0, stream>>>(z1, z2, scratch + 2, hu, U * 64);

        // ---- HAN: items ----
        k_gather<<<cdiv_ll(I * 64, T), T, 0, stream>>>(rp_i1, ci_i1, hi, n_i1s, n_i1r, z1, (int)I);
        k_gather<<<cdiv_ll(I * 64, T), T, 0, stream>>>(rp_i2, ci_i2, hi, n_i2s, n_i2r, z2, (int)I);
        hipMemsetAsync(scratch, 0, 2 * sizeof(float), stream);
        k_attn_mfma<<<ATTN_BLOCKS, T, 0, stream>>>(z1, z2, Wbi, wb1i, ww2i, (int)I, scratch);
        k_beta<<<1, 64, 0, stream>>>(scratch, 1.0f / (float)I, scratch + 2);
        k_combine<<<cdiv_ll(I * 64, T), T, 0, stream>>>(z1, z2, scratch + 2, hi, I * 64);
    }

    // ---------------- final ----------------
    k_out1<<<cdiv_ll((ll)2 * B * 64, T), T, 0, stream>>>(hu, hi, uiA, user_idx, item_idx, d_out, B, U, flag);
    k_out2<<<cdiv_ll((ll)B * 64, T), T, 0, stream>>>(d_out, neg_idx, B, flag);
}

// Round 7
// 1314.846 us; speedup vs baseline: 2.7261x; 1.1537x over previous
//
#include <hip/hip_runtime.h>
#include <hip/hip_bf16.h>

typedef long long ll;
typedef __attribute__((ext_vector_type(8))) short bf16x8;
typedef __attribute__((ext_vector_type(4))) float f32x4;

static inline int cdiv_ll(ll a, int b) { return (int)((a + (ll)b - 1) / (ll)b); }

// ---------------- dtype detection (bf16 vs fp32 inputs) ----------------
__global__ void k_detect(const unsigned int* __restrict__ dw, const ll n_dw, int* __restrict__ flag) {
    __shared__ int sc[256];
    int tid = threadIdx.x;
    int cnt = 0;
    for (int s = 0; s < 32; s++) {
        ll idx = (ll)(s * 256 + tid);
        ll i = (idx * n_dw) / 8192;
        unsigned v = dw[i];
        unsigned lo = v & 0xFFFFu;
        unsigned ex = (lo >> 7) & 0xFFu;
        bool pl = (lo == 0u) || (lo == 0x8000u) || (ex >= 0x60u && ex <= 0x8Fu);
        cnt += pl ? 1 : 0;
    }
    sc[tid] = cnt;
    __syncthreads();
    for (int o = 128; o > 0; o >>= 1) { if (tid < o) sc[tid] += sc[tid + o]; __syncthreads(); }
    if (tid == 0) *flag = (sc[0] * 2 > 8192) ? 1 : 0;
}

__device__ __forceinline__ float load_in(const void* p, ll i, int isbf16) {
    if (isbf16) return __bfloat162float(((const __hip_bfloat16*)p)[i]);
    return ((const float*)p)[i];
}

// round-to-nearest-even fp32 -> bf16 bits (finite inputs)
__device__ __forceinline__ unsigned short f2bf(float f) {
    unsigned u = __float_as_uint(f);
    unsigned r = (u + 0x7FFFu + ((u >> 16) & 1u)) >> 16;
    return (unsigned short)r;
}

// ---------------- fused weight conversion ----------------
// layout per set: W1 [64x128] -> bf16 W^T [128][64]; b1[128] -> f32; w2[128] -> f32
__global__ void k_cvt_weights(const void* __restrict__ W1u, const void* __restrict__ b1u,
                              const void* __restrict__ w2u, const void* __restrict__ W1i,
                              const void* __restrict__ b1i, const void* __restrict__ w2i,
                              unsigned short* __restrict__ Wbu, float* __restrict__ fb1u,
                              float* __restrict__ fw2u, unsigned short* __restrict__ Wbi,
                              float* __restrict__ fb1i, float* __restrict__ fw2i,
                              const int* __restrict__ flag) {
    int i = blockIdx.x * blockDim.x + threadIdx.x;
    int bf = *flag;
    const int WSZ = 64 * 128;
    if (i < WSZ) {
        int d = i >> 7, h = i & 127;
        Wbu[h * 64 + d] = f2bf(load_in(W1u, i, bf));
    } else if (i < WSZ + 128) {
        fb1u[i - WSZ] = load_in(b1u, i - WSZ, bf);
    } else if (i < WSZ + 256) {
        fw2u[i - WSZ - 128] = load_in(w2u, i - WSZ - 128, bf);
    } else if (i < 2 * WSZ + 256) {
        int j = i - WSZ - 256;
        int d = j >> 7, h = j & 127;
        Wbi[h * 64 + d] = f2bf(load_in(W1i, j, bf));
    } else if (i < 2 * WSZ + 384) {
        fb1i[i - 2 * WSZ - 256] = load_in(b1i, i - 2 * WSZ - 256, bf);
    } else if (i < 2 * WSZ + 512) {
        fw2i[i - 2 * WSZ - 384] = load_in(w2i, i - 2 * WSZ - 384, bf);
    }
}

// ---------------- fused count (+pos capture) ----------------
// counts layout: [cnt_ui(N) | r_u1(U) | r_u2(U) | r_i1(I) | r_i2(I) | s_u1(U) | s_u2(U) | s_i1(I) | s_i2(I)]
__global__ void k_count_all(const int* __restrict__ uiR, const int* __restrict__ uiC,
                            const int* __restrict__ u1s, const int* __restrict__ u1d,
                            const int* __restrict__ u2s, const int* __restrict__ u2d,
                            const int* __restrict__ i1s, const int* __restrict__ i1d,
                            const int* __restrict__ i2s, const int* __restrict__ i2d,
                            const ll E2, const ll EU1, const ll EU2, const ll EI1, const ll EI2,
                            const int N, const int U, const int I,
                            int* __restrict__ counts, int* __restrict__ posbuf) {
    ll t = (ll)blockIdx.x * blockDim.x + threadIdx.x;
    ll b1 = E2, b2 = b1 + EU1, b3 = b2 + EU2, b4 = b3 + EI1, b5 = b4 + EI2;
    if (t >= b5) return;
    int M = N + 2 * U + 2 * I;
    int r, s, roff, soff;
    if (t < b1) {
        r = uiR[t]; roff = 0; soff = -1; s = 0;
    } else if (t < b2) {
        ll e = t - b1; r = u1d[e]; s = u1s[e]; roff = N; soff = M;
    } else if (t < b3) {
        ll e = t - b2; r = u2d[e]; s = u2s[e]; roff = N + U; soff = M + U;
    } else if (t < b4) {
        ll e = t - b3; r = i1d[e]; s = i1s[e]; roff = N + 2 * U; soff = M + 2 * U;
    } else {
        ll e = t - b4; r = i2d[e]; s = i2s[e]; roff = N + 2 * U + I; soff = M + 2 * U + I;
    }
    int pos = atomicAdd(&counts[roff + r], 1);
    posbuf[t] = pos;
    if (soff >= 0) atomicAdd(&counts[soff + s], 1);
}

// ---------------- fused norms ----------------
// i < N: gcn (0 if deg==0 else rsqrt); else: conv (rsqrt of max(deg,1))
__global__ void k_norm_all(const int* __restrict__ counts, float* __restrict__ nrm,
                           const int N, const int total) {
    int i = blockIdx.x * blockDim.x + threadIdx.x;
    if (i < total) {
        int c = counts[i];
        if (i < N) nrm[i] = (c > 0) ? (1.0f / sqrtf((float)c)) : 0.0f;
        else nrm[i] = 1.0f / sqrtf(fmaxf((float)c, 1.0f));
    }
}

// ---------------- hierarchical exclusive scan ----------
#define SCAN_T 256
#define SCAN_ELEMS 8
#define SCAN_CHUNK (SCAN_T * SCAN_ELEMS)   // 2048

__global__ __launch_bounds__(256) void k_scanA(const int* __restrict__ in, const int n,
                                               int* __restrict__ out, int* __restrict__ bsum) {
    __shared__ int sh[SCAN_T];
    int t = threadIdx.x;
    ll base = (ll)blockIdx.x * SCAN_CHUNK + (ll)t * SCAN_ELEMS;
    int v[SCAN_ELEMS];
    int tot = 0;
#pragma unroll
    for (int k = 0; k < SCAN_ELEMS; k++) {
        ll i = base + k;
        v[k] = (i < n) ? in[i] : 0;
        tot += v[k];
    }
    sh[t] = tot;
    __syncthreads();
    for (int off = 1; off < SCAN_T; off <<= 1) {
        int x = (t >= off) ? sh[t - off] : 0;
        __syncthreads();
        sh[t] += x;
        __syncthreads();
    }
    int run = sh[t] - tot;
#pragma unroll
    for (int k = 0; k < SCAN_ELEMS; k++) {
        ll i = base + k;
        if (i < n) out[i] = run;
        run += v[k];
    }
    if (t == SCAN_T - 1) bsum[blockIdx.x] = sh[SCAN_T - 1];
}

__global__ __launch_bounds__(256) void k_scanB(int* __restrict__ bsum, const int nb) {
    __shared__ int sh[256];
    int t = threadIdx.x;
    int running = 0;
    for (int base = 0; base < nb; base += 256) {
        int idx = base + t;
        int v = (idx < nb) ? bsum[idx] : 0;
        sh[t] = v;
        __syncthreads();
        for (int off = 1; off < 256; off <<= 1) {
            int x = (t >= off) ? sh[t - off] : 0;
            __syncthreads();
            sh[t] += x;
            __syncthreads();
        }
        if (idx < nb) bsum[idx] = running + sh[t] - v;
        int tot = sh[255];
        __syncthreads();
        running += tot;
    }
}

// add block bases + append total sentinel
__global__ void k_scanC(int* __restrict__ S, const int n, const int* __restrict__ bsum, const int ET) {
    ll i = (ll)blockIdx.x * blockDim.x + threadIdx.x;
    if (i < n) S[i] += bsum[i / SCAN_CHUNK];
    if (i == 0) S[n] = ET;
}

// ---------------- fused fill (atomic-free) ----------------
__global__ void k_fill_all(const int* __restrict__ uiR, const int* __restrict__ uiC,
                           const int* __restrict__ u1s, const int* __restrict__ u1d,
                           const int* __restrict__ u2s, const int* __restrict__ u2d,
                           const int* __restrict__ i1s, const int* __restrict__ i1d,
                           const int* __restrict__ i2s, const int* __restrict__ i2d,
                           const ll E2, const ll EU1, const ll EU2, const ll EI1, const ll EI2,
                           const int N, const int U, const int I,
                           const int* __restrict__ S, const int* __restrict__ posbuf,
                           int* __restrict__ ci_all) {
    ll t = (ll)blockIdx.x * blockDim.x + threadIdx.x;
    ll b1 = E2, b2 = b1 + EU1, b3 = b2 + EU2, b4 = b3 + EI1, b5 = b4 + EI2;
    if (t >= b5) return;
    int r, c, roff;
    if (t < b1) {
        r = uiR[t]; c = uiC[t]; roff = 0;
    } else if (t < b2) {
        ll e = t - b1; r = u1d[e]; c = u1s[e]; roff = N;
    } else if (t < b3) {
        ll e = t - b2; r = u2d[e]; c = u2s[e]; roff = N + U;
    } else if (t < b4) {
        ll e = t - b3; r = i1d[e]; c = i1s[e]; roff = N + 2 * U;
    } else {
        ll e = t - b4; r = i2d[e]; c = i2s[e]; roff = N + 2 * U + I;
    }
    ci_all[(ll)S[roff + r] + posbuf[t]] = c;
}

// ---------------- init features ----------------
__global__ void k_init(const void* __restrict__ uf, const void* __restrict__ itf,
                       float* __restrict__ ui, float* __restrict__ hu, float* __restrict__ hi,
                       const ll nu64, const ll ntot64, const int* __restrict__ flag) {
    ll t = (ll)blockIdx.x * blockDim.x + threadIdx.x;
    int bf = *flag;
    if (t < nu64) {
        float v = load_in(uf, t, bf);
        ui[t] = v; hu[t] = v;
    } else if (t < ntot64) {
        ll j = t - nu64;
        float v = load_in(itf, j, bf);
        ui[t] = v; hi[j] = v;
    }
}

// ---------------- gather SpMM (row_ptr = global CSR offsets into ci_all) ----
__global__ __launch_bounds__(256) void k_gather(const int* __restrict__ row_ptr,
                                                const int* __restrict__ col_idx,
                                                const float* __restrict__ x,
                                                const float* __restrict__ cnorm,
                                                const float* __restrict__ rnorm,
                                                float* __restrict__ out, const int nrows) {
    ll gt = (ll)blockIdx.x * blockDim.x + threadIdx.x;
    int w = (int)(gt >> 6);
    int d = (int)(gt & 63);
    if (w >= nrows) return;
    int s = row_ptr[w], e = row_ptr[w + 1];
    float accA = 0.0f, accB = 0.0f;
    int j = s;
    for (; j + 8 <= e; j += 8) {
        int c0 = col_idx[j],     c1 = col_idx[j + 1], c2 = col_idx[j + 2], c3 = col_idx[j + 3];
        int c4 = col_idx[j + 4], c5 = col_idx[j + 5], c6 = col_idx[j + 6], c7 = col_idx[j + 7];
        float n0 = cnorm[c0], n1 = cnorm[c1], n2 = cnorm[c2], n3 = cnorm[c3];
        float n4 = cnorm[c4], n5 = cnorm[c5], n6 = cnorm[c6], n7 = cnorm[c7];
        float x0 = x[(ll)c0 * 64 + d], x1 = x[(ll)c1 * 64 + d];
        float x2 = x[(ll)c2 * 64 + d], x3 = x[(ll)c3 * 64 + d];
        float x4 = x[(ll)c4 * 64 + d], x5 = x[(ll)c5 * 64 + d];
        float x6 = x[(ll)c6 * 64 + d], x7 = x[(ll)c7 * 64 + d];
        accA += x0 * n0 + x2 * n2 + x4 * n4 + x6 * n6;
        accB += x1 * n1 + x3 * n3 + x5 * n5 + x7 * n7;
    }
    for (; j + 2 <= e; j += 2) {
        int c0 = col_idx[j], c1 = col_idx[j + 1];
        accA += x[(ll)c0 * 64 + d] * cnorm[c0];
        accB += x[(ll)c1 * 64 + d] * cnorm[c1];
    }
    if (j < e) {
        int c = col_idx[j];
        accA += x[(ll)c * 64 + d] * cnorm[c];
    }
    out[(ll)w * 64 + d] = (accA + accB) * rnorm[w];
}

// ---------------- fast tanh ----------
__device__ __forceinline__ float fast_tanh(float x) {
    return 1.0f - 2.0f / (__expf(2.0f * x) + 1.0f);
}

__device__ __forceinline__ bf16x8 pack8(float4 a, float4 b) {
    bf16x8 r;
    r[0] = (short)f2bf(a.x); r[1] = (short)f2bf(a.y);
    r[2] = (short)f2bf(a.z); r[3] = (short)f2bf(a.w);
    r[4] = (short)f2bf(b.x); r[5] = (short)f2bf(b.y);
    r[6] = (short)f2bf(b.z); r[7] = (short)f2bf(b.w);
    return r;
}

// ---------------- MFMA semantic-attention scores ----------------
__global__ __launch_bounds__(256) void k_attn_mfma(const float* __restrict__ z1,
                                                   const float* __restrict__ z2,
                                                   const unsigned short* __restrict__ Wb,
                                                   const float* __restrict__ b1f,
                                                   const float* __restrict__ w2f,
                                                   const int n, float* __restrict__ wsum) {
    __shared__ float red0[4], red1[4];
    int tid = threadIdx.x;
    int lane = tid & 63;
    int wid = tid >> 6;
    int col = lane & 15;
    int quad = lane >> 4;

    bf16x8 wb[8][2];
#pragma unroll
    for (int ht = 0; ht < 8; ht++) {
        int h = ht * 16 + col;
#pragma unroll
        for (int ks = 0; ks < 2; ks++) {
            wb[ht][ks] = *(const bf16x8*)&Wb[h * 64 + ks * 32 + quad * 8];
        }
    }
    float b1v[8], w2v[8];
#pragma unroll
    for (int ht = 0; ht < 8; ht++) {
        b1v[ht] = b1f[ht * 16 + col];
        w2v[ht] = w2f[ht * 16 + col];
    }

    float w0 = 0.0f, w1 = 0.0f;
    int ntiles = (n + 15) >> 4;
    int gw = blockIdx.x * 4 + wid;
    int nw = gridDim.x * 4;
    const float4 zero4 = make_float4(0.f, 0.f, 0.f, 0.f);

    for (int tile = gw; tile < ntiles; tile += nw) {
        int nodeA = tile * 16 + col;
        bool va = nodeA < n;
        bf16x8 a1[2], a2[2];
#pragma unroll
        for (int ks = 0; ks < 2; ks++) {
            const float4* p1 = (const float4*)&z1[(ll)nodeA * 64 + ks * 32 + quad * 8];
            const float4* p2 = (const float4*)&z2[(ll)nodeA * 64 + ks * 32 + quad * 8];
            float4 f0 = va ? p1[0] : zero4;
            float4 f1 = va ? p1[1] : zero4;
            float4 g0 = va ? p2[0] : zero4;
            float4 g1 = va ? p2[1] : zero4;
            a1[ks] = pack8(f0, f1);
            a2[ks] = pack8(g0, g1);
        }
#pragma unroll
        for (int ht = 0; ht < 8; ht++) {
            f32x4 c1 = {0.f, 0.f, 0.f, 0.f};
            f32x4 c2 = {0.f, 0.f, 0.f, 0.f};
            c1 = __builtin_amdgcn_mfma_f32_16x16x32_bf16(a1[0], wb[ht][0], c1, 0, 0, 0);
            c1 = __builtin_amdgcn_mfma_f32_16x16x32_bf16(a1[1], wb[ht][1], c1, 0, 0, 0);
            c2 = __builtin_amdgcn_mfma_f32_16x16x32_bf16(a2[0], wb[ht][0], c2, 0, 0, 0);
            c2 = __builtin_amdgcn_mfma_f32_16x16x32_bf16(a2[1], wb[ht][1], c2, 0, 0, 0);
#pragma unroll
            for (int r = 0; r < 4; r++) {
                int node_row = tile * 16 + quad * 4 + r;
                bool vr = node_row < n;
                float t1 = fast_tanh(c1[r] + b1v[ht]) * w2v[ht];
                float t2 = fast_tanh(c2[r] + b1v[ht]) * w2v[ht];
                w0 += vr ? t1 : 0.0f;
                w1 += vr ? t2 : 0.0f;
            }
        }
    }

    for (int off = 32; off > 0; off >>= 1) {
        w0 += __shfl_down(w0, off);
        w1 += __shfl_down(w1, off);
    }
    if (lane == 0) { red0[wid] = w0; red1[wid] = w1; }
    __syncthreads();
    if (tid == 0) {
        atomicAdd(&wsum[0], red0[0] + red0[1] + red0[2] + red0[3]);
        atomicAdd(&wsum[1], red1[0] + red1[1] + red1[2] + red1[3]);
    }
}

// ---------------- combine with inline beta softmax ----------------
__global__ void k_combine(const float* __restrict__ z1, const float* __restrict__ z2,
                          const float* __restrict__ wsum, const float inv_n,
                          float* __restrict__ h, const ll n64) {
    ll t = (ll)blockIdx.x * blockDim.x + threadIdx.x;
    if (t < n64) {
        float m0 = wsum[0] * inv_n, m1 = wsum[1] * inv_n;
        float mx = fmaxf(m0, m1);
        float e0 = __expf(m0 - mx), e1 = __expf(m1 - mx);
        float inv_s = 1.0f / (e0 + e1);
        h[t] = (e0 * z1[t] + e1 * z2[t]) * inv_s;
    }
}

// ---------------- fused output gather ----------------
__device__ __forceinline__ void store_out(void* out, ll i, float v, int isbf16) {
    if (isbf16) ((__hip_bfloat16*)out)[i] = __float2bfloat16(v);
    else ((float*)out)[i] = v;
}

__global__ void k_out(const float* __restrict__ hu, const float* __restrict__ hi,
                      const float* __restrict__ ui, const int* __restrict__ user_idx,
                      const int* __restrict__ item_idx, const int* __restrict__ neg_idx,
                      void* __restrict__ out, const int B, const ll U,
                      const int* __restrict__ flag) {
    ll t = (ll)blockIdx.x * blockDim.x + threadIdx.x;
    int bf = *flag;
    int d = (int)(t & 63);
    ll b = t >> 6;
    if (b < B) {
        int u = user_idx[b];
        float v = 0.5f * hu[(ll)u * 64 + d] + 0.5f * ui[(ll)u * 64 + d];
        store_out(out, b * 64 + d, v, bf);
    } else if (b < 2 * (ll)B) {
        ll bb = b - B;
        int it = item_idx[bb];
        float v = 0.5f * hi[(ll)it * 64 + d] + 0.5f * ui[(U + it) * 64 + d];
        store_out(out, (ll)B * 64 + bb * 64 + d, v, bf);
    } else if (b < 3 * (ll)B) {
        ll bb = b - 2 * (ll)B;
        int it = item_idx[neg_idx[bb]];
        float v = 0.5f * hi[(ll)it * 64 + d] + 0.5f * ui[(U + it) * 64 + d];
        store_out(out, (ll)2 * B * 64 + bb * 64 + d, v, bf);
    }
}

extern "C" void kernel_launch(void* const* d_in, const int* in_sizes, int n_in,
                              void* d_out, int out_size, void* d_ws, size_t ws_size,
                              hipStream_t stream) {
    const int D = 64;
    const ll U = in_sizes[0] / D;
    const ll I = in_sizes[1] / D;
    const ll N = U + I;
    const ll E2  = in_sizes[8] / 2;
    const ll EU1 = in_sizes[9] / 2;
    const ll EU2 = in_sizes[10] / 2;
    const ll EI1 = in_sizes[11] / 2;
    const ll EI2 = in_sizes[12] / 2;
    const ll ET = E2 + EU1 + EU2 + EI1 + EI2;
    const int B = in_sizes[13];
    const int M = (int)(N + 2 * U + 2 * I);          // scanned region
    const int M2 = (int)(N + 4 * U + 4 * I);         // + src-count region

    const void* user_feat = d_in[0];
    const void* item_feat = d_in[1];
    const int* ui_row = (const int*)d_in[8];
    const int* ui_col = ui_row + E2;
    const int* u1_src = (const int*)d_in[9];
    const int* u1_dst = u1_src + EU1;
    const int* u2_src = (const int*)d_in[10];
    const int* u2_dst = u2_src + EU2;
    const int* i1_src = (const int*)d_in[11];
    const int* i1_dst = i1_src + EI1;
    const int* i2_src = (const int*)d_in[12];
    const int* i2_dst = i2_src + EI2;
    const int* user_idx = (const int*)d_in[13];
    const int* item_idx = (const int*)d_in[14];
    const int* neg_idx  = (const int*)d_in[15];

    // ---------------- workspace layout ----------------
    float* p = (float*)d_ws;
    float* ui0 = p;  p += N * 64;
    float* ui1 = p;  p += N * 64;
    float* hu  = p;  p += U * 64;
    float* hi  = p;  p += I * 64;
    float* z1  = p;  p += I * 64;   // also reused as posbuf (int) during CSR build
    float* z2  = p;  p += I * 64;
    float* nrm = p;  p += M2;       // [dinv(N)|r_u1|r_u2|r_i1|r_i2|s_u1|s_u2|s_i1|s_i2]
    unsigned short* Wbu = (unsigned short*)p; p += 64 * 128 / 2;
    unsigned short* Wbi = (unsigned short*)p; p += 64 * 128 / 2;
    float* wb1u = p; p += 128;
    float* ww2u = p; p += 128;
    float* wb1i = p; p += 128;
    float* ww2i = p; p += 128;
    float* scratch = p; p += 16;    // wsum slots: [0..1] u-l0, [4..5] i-l0, [8..9] u-l1, [12..13] i-l1

    int* ip = (int*)p;
    int* counts = ip; ip += M2;     // zeroed
    int* S = ip; ip += M + 1;       // global exclusive scan of counts[0..M)
    int* ci_all = ip; ip += ET;
    int* bsum = ip; ip += 256;
    int* flag = ip; ip += 4;
    size_t needed = (size_t)((char*)ip - (char*)d_ws);
    if (ws_size < needed) return;
    int* posbuf = (int*)z1;         // ET ints <= I*64 floats

    const int T = 256;

    // ---------------- dtype detection + weight conversion ----------------
    k_detect<<<1, 256, 0, stream>>>((const unsigned int*)user_feat, (ll)in_sizes[0] / 2, flag);
    k_cvt_weights<<<cdiv_ll(2 * (64 * 128 + 256), T), T, 0, stream>>>(
        d_in[2], d_in[3], d_in[4], d_in[5], d_in[6], d_in[7],
        Wbu, wb1u, ww2u, Wbi, wb1i, ww2i, flag);

    // ---------------- CSR build ----------------
    hipMemsetAsync(counts, 0, (size_t)M2 * sizeof(int), stream);
    hipMemsetAsync(scratch, 0, 16 * sizeof(float), stream);
    k_count_all<<<cdiv_ll(ET, T), T, 0, stream>>>(
        ui_row, ui_col, u1_src, u1_dst, u2_src, u2_dst, i1_src, i1_dst, i2_src, i2_dst,
        E2, EU1, EU2, EI1, EI2, (int)N, (int)U, (int)I, counts, posbuf);
    k_norm_all<<<cdiv_ll(M2, T), T, 0, stream>>>(counts, nrm, (int)N, M2);
    {
        int nb = (M + SCAN_CHUNK - 1) / SCAN_CHUNK;
        k_scanA<<<nb, SCAN_T, 0, stream>>>(counts, M, S, bsum);
        k_scanB<<<1, 256, 0, stream>>>(bsum, nb);
        k_scanC<<<cdiv_ll(M, T), T, 0, stream>>>(S, M, bsum, (int)ET);
    }
    k_fill_all<<<cdiv_ll(ET, T), T, 0, stream>>>(
        ui_row, ui_col, u1_src, u1_dst, u2_src, u2_dst, i1_src, i1_dst, i2_src, i2_dst,
        E2, EU1, EU2, EI1, EI2, (int)N, (int)U, (int)I, S, posbuf, ci_all);

    // ---------------- init features (overwrites posbuf region via z1? no: z1 untouched here) ----
    k_init<<<cdiv_ll(N * 64, T), T, 0, stream>>>(user_feat, item_feat, ui0, hu, hi, U * 64, N * 64, flag);

    // CSR segment row_ptr views (global offsets into ci_all)
    const int* rp_ui = S;
    const int* rp_u1 = S + N;
    const int* rp_u2 = S + N + U;
    const int* rp_i1 = S + N + 2 * U;
    const int* rp_i2 = S + N + 2 * U + I;
    // norm views
    const float* dinv = nrm;
    const float* n_u1r = nrm + N;          const float* n_u2r = nrm + N + U;
    const float* n_i1r = nrm + N + 2 * U;  const float* n_i2r = nrm + N + 2 * U + I;
    const float* n_u1s = nrm + M;          const float* n_u2s = nrm + M + U;
    const float* n_i1s = nrm + M + 2 * U;  const float* n_i2s = nrm + M + 2 * U + I;

    float* uiA = ui0;
    float* uiB = ui1;
    const int ATTN_BLOCKS = 512;

    for (int layer = 0; layer < 2; layer++) {
        float* wsU = scratch + (layer ? 8 : 0);
        float* wsI = scratch + (layer ? 12 : 4);

        // ---- gcn_spmm ----
        k_gather<<<cdiv_ll(N * 64, T), T, 0, stream>>>(rp_ui, ci_all, uiA, dinv, dinv, uiB, (int)N);
        { float* tmp = uiA; uiA = uiB; uiB = tmp; }

        // ---- HAN: users ----
        k_gather<<<cdiv_ll(U * 64, T), T, 0, stream>>>(rp_u1, ci_all, hu, n_u1s, n_u1r, z1, (int)U);
        k_gather<<<cdiv_ll(U * 64, T), T, 0, stream>>>(rp_u2, ci_all, hu, n_u2s, n_u2r, z2, (int)U);
        k_attn_mfma<<<ATTN_BLOCKS, T, 0, stream>>>(z1, z2, Wbu, wb1u, ww2u, (int)U, wsU);
        k_combine<<<cdiv_ll(U * 64, T), T, 0, stream>>>(z1, z2, wsU, 1.0f / (float)U, hu, U * 64);

        // ---- HAN: items ----
        k_gather<<<cdiv_ll(I * 64, T), T, 0, stream>>>(rp_i1, ci_all, hi, n_i1s, n_i1r, z1, (int)I);
        k_gather<<<cdiv_ll(I * 64, T), T, 0, stream>>>(rp_i2, ci_all, hi, n_i2s, n_i2r, z2, (int)I);
        k_attn_mfma<<<ATTN_BLOCKS, T, 0, stream>>>(z1, z2, Wbi, wb1i, ww2i, (int)I, wsI);
        k_combine<<<cdiv_ll(I * 64, T), T, 0, stream>>>(z1, z2, wsI, 1.0f / (float)I, hi, I * 64);
    }

    // ---------------- final ----------------
    k_out<<<cdiv_ll((ll)3 * B * 64, T), T, 0, stream>>>(hu, hi, uiA, user_idx, item_idx, neg_idx,
                                                        d_out, B, U, flag);
}

// Round 8
// 1313.599 us; speedup vs baseline: 2.7287x; 1.0009x over previous
//
#include <hip/hip_runtime.h>
#include <hip/hip_bf16.h>

typedef long long ll;
typedef __attribute__((ext_vector_type(8))) short bf16x8;
typedef __attribute__((ext_vector_type(4))) float f32x4;

static inline int cdiv_ll(ll a, int b) { return (int)((a + (ll)b - 1) / (ll)b); }

// ---------------- dtype detection (bf16 vs fp32 inputs) ----------------
__global__ void k_detect(const unsigned int* __restrict__ dw, const ll n_dw, int* __restrict__ flag) {
    __shared__ int sc[256];
    int tid = threadIdx.x;
    int cnt = 0;
    for (int s = 0; s < 32; s++) {
        ll idx = (ll)(s * 256 + tid);
        ll i = (idx * n_dw) / 8192;
        unsigned v = dw[i];
        unsigned lo = v & 0xFFFFu;
        unsigned ex = (lo >> 7) & 0xFFu;
        bool pl = (lo == 0u) || (lo == 0x8000u) || (ex >= 0x60u && ex <= 0x8Fu);
        cnt += pl ? 1 : 0;
    }
    sc[tid] = cnt;
    __syncthreads();
    for (int o = 128; o > 0; o >>= 1) { if (tid < o) sc[tid] += sc[tid + o]; __syncthreads(); }
    if (tid == 0) *flag = (sc[0] * 2 > 8192) ? 1 : 0;
}

__device__ __forceinline__ float load_in(const void* p, ll i, int isbf16) {
    if (isbf16) return __bfloat162float(((const __hip_bfloat16*)p)[i]);
    return ((const float*)p)[i];
}

// round-to-nearest-even fp32 -> bf16 bits (finite inputs)
__device__ __forceinline__ unsigned short f2bf(float f) {
    unsigned u = __float_as_uint(f);
    unsigned r = (u + 0x7FFFu + ((u >> 16) & 1u)) >> 16;
    return (unsigned short)r;
}

// ---------------- fused weight conversion ----------------
__global__ void k_cvt_weights(const void* __restrict__ W1u, const void* __restrict__ b1u,
                              const void* __restrict__ w2u, const void* __restrict__ W1i,
                              const void* __restrict__ b1i, const void* __restrict__ w2i,
                              unsigned short* __restrict__ Wbu, float* __restrict__ fb1u,
                              float* __restrict__ fw2u, unsigned short* __restrict__ Wbi,
                              float* __restrict__ fb1i, float* __restrict__ fw2i,
                              const int* __restrict__ flag) {
    int i = blockIdx.x * blockDim.x + threadIdx.x;
    int bf = *flag;
    const int WSZ = 64 * 128;
    if (i < WSZ) {
        int d = i >> 7, h = i & 127;
        Wbu[h * 64 + d] = f2bf(load_in(W1u, i, bf));
    } else if (i < WSZ + 128) {
        fb1u[i - WSZ] = load_in(b1u, i - WSZ, bf);
    } else if (i < WSZ + 256) {
        fw2u[i - WSZ - 128] = load_in(w2u, i - WSZ - 128, bf);
    } else if (i < 2 * WSZ + 256) {
        int j = i - WSZ - 256;
        int d = j >> 7, h = j & 127;
        Wbi[h * 64 + d] = f2bf(load_in(W1i, j, bf));
    } else if (i < 2 * WSZ + 384) {
        fb1i[i - 2 * WSZ - 256] = load_in(b1i, i - 2 * WSZ - 256, bf);
    } else if (i < 2 * WSZ + 512) {
        fw2i[i - 2 * WSZ - 384] = load_in(w2i, i - 2 * WSZ - 384, bf);
    }
}

// ---------------- fused count, XCD-privatized (+pos capture) ----------------
// counts8: 8 private copies of the M2-entry counter array. Copy = blockIdx&7
// (de-facto XCD round-robin on MI355X: atomics stay in the local L2 copy,
// eliminating cross-XCD line ping-pong). Correct under ANY block->copy map.
// counts layout (per copy): [cnt_ui(N) | r_u1(U) | r_u2(U) | r_i1(I) | r_i2(I)
//                            | s_u1(U) | s_u2(U) | s_i1(I) | s_i2(I)]
__global__ void k_count_all(const int* __restrict__ uiR,
                            const int* __restrict__ u1s, const int* __restrict__ u1d,
                            const int* __restrict__ u2s, const int* __restrict__ u2d,
                            const int* __restrict__ i1s, const int* __restrict__ i1d,
                            const int* __restrict__ i2s, const int* __restrict__ i2d,
                            const ll E2, const ll EU1, const ll EU2, const ll EI1, const ll EI2,
                            const int N, const int U, const int I, const int M2,
                            int* __restrict__ counts8, int* __restrict__ posbuf) {
    ll t = (ll)blockIdx.x * blockDim.x + threadIdx.x;
    ll b1 = E2, b2 = b1 + EU1, b3 = b2 + EU2, b4 = b3 + EI1, b5 = b4 + EI2;
    if (t >= b5) return;
    int* cnt = counts8 + (ll)(blockIdx.x & 7) * M2;
    int M = N + 2 * U + 2 * I;
    int r, s, roff, soff;
    if (t < b1) {
        r = uiR[t]; roff = 0; soff = -1; s = 0;
    } else if (t < b2) {
        ll e = t - b1; r = u1d[e]; s = u1s[e]; roff = N; soff = M;
    } else if (t < b3) {
        ll e = t - b2; r = u2d[e]; s = u2s[e]; roff = N + U; soff = M + U;
    } else if (t < b4) {
        ll e = t - b3; r = i1d[e]; s = i1s[e]; roff = N + 2 * U; soff = M + 2 * U;
    } else {
        ll e = t - b4; r = i2d[e]; s = i2s[e]; roff = N + 2 * U + I; soff = M + 2 * U + I;
    }
    int pos = atomicAdd(&cnt[roff + r], 1);
    posbuf[t] = pos;
    if (soff >= 0) atomicAdd(&cnt[soff + s], 1);
}

// ---------------- reduce 8 copies -> totals; copies -> exclusive offsets ----
__global__ void k_reduce8(int* __restrict__ counts8, int* __restrict__ totals,
                          const int M2) {
    int i = blockIdx.x * blockDim.x + threadIdx.x;
    if (i >= M2) return;
    int run = 0;
#pragma unroll
    for (int c = 0; c < 8; c++) {
        int v = counts8[(ll)c * M2 + i];
        counts8[(ll)c * M2 + i] = run;
        run += v;
    }
    totals[i] = run;
}

// ---------------- fused norms ----------------
__global__ void k_norm_all(const int* __restrict__ counts, float* __restrict__ nrm,
                           const int N, const int total) {
    int i = blockIdx.x * blockDim.x + threadIdx.x;
    if (i < total) {
        int c = counts[i];
        if (i < N) nrm[i] = (c > 0) ? (1.0f / sqrtf((float)c)) : 0.0f;
        else nrm[i] = 1.0f / sqrtf(fmaxf((float)c, 1.0f));
    }
}

// ---------------- hierarchical exclusive scan ----------
#define SCAN_T 256
#define SCAN_ELEMS 8
#define SCAN_CHUNK (SCAN_T * SCAN_ELEMS)   // 2048

__global__ __launch_bounds__(256) void k_scanA(const int* __restrict__ in, const int n,
                                               int* __restrict__ out, int* __restrict__ bsum) {
    __shared__ int sh[SCAN_T];
    int t = threadIdx.x;
    ll base = (ll)blockIdx.x * SCAN_CHUNK + (ll)t * SCAN_ELEMS;
    int v[SCAN_ELEMS];
    int tot = 0;
#pragma unroll
    for (int k = 0; k < SCAN_ELEMS; k++) {
        ll i = base + k;
        v[k] = (i < n) ? in[i] : 0;
        tot += v[k];
    }
    sh[t] = tot;
    __syncthreads();
    for (int off = 1; off < SCAN_T; off <<= 1) {
        int x = (t >= off) ? sh[t - off] : 0;
        __syncthreads();
        sh[t] += x;
        __syncthreads();
    }
    int run = sh[t] - tot;
#pragma unroll
    for (int k = 0; k < SCAN_ELEMS; k++) {
        ll i = base + k;
        if (i < n) out[i] = run;
        run += v[k];
    }
    if (t == SCAN_T - 1) bsum[blockIdx.x] = sh[SCAN_T - 1];
}

__global__ __launch_bounds__(256) void k_scanB(int* __restrict__ bsum, const int nb) {
    __shared__ int sh[256];
    int t = threadIdx.x;
    int running = 0;
    for (int base = 0; base < nb; base += 256) {
        int idx = base + t;
        int v = (idx < nb) ? bsum[idx] : 0;
        sh[t] = v;
        __syncthreads();
        for (int off = 1; off < 256; off <<= 1) {
            int x = (t >= off) ? sh[t - off] : 0;
            __syncthreads();
            sh[t] += x;
            __syncthreads();
        }
        if (idx < nb) bsum[idx] = running + sh[t] - v;
        int tot = sh[255];
        __syncthreads();
        running += tot;
    }
}

__global__ void k_scanC(int* __restrict__ S, const int n, const int* __restrict__ bsum, const int ET) {
    ll i = (ll)blockIdx.x * blockDim.x + threadIdx.x;
    if (i < n) S[i] += bsum[i / SCAN_CHUNK];
    if (i == 0) S[n] = ET;
}

// ---------------- fused fill (atomic-free) ----------------
// Edge t was counted by block t>>8 -> copy (t>>8)&7; its global CSR slot is
// S[row] + copy_exclusive_offset[copy][row] + pos_within_copy.
__global__ void k_fill_all(const int* __restrict__ uiR, const int* __restrict__ uiC,
                           const int* __restrict__ u1s, const int* __restrict__ u1d,
                           const int* __restrict__ u2s, const int* __restrict__ u2d,
                           const int* __restrict__ i1s, const int* __restrict__ i1d,
                           const int* __restrict__ i2s, const int* __restrict__ i2d,
                           const ll E2, const ll EU1, const ll EU2, const ll EI1, const ll EI2,
                           const int N, const int U, const int I, const int M2,
                           const int* __restrict__ S, const int* __restrict__ counts8,
                           const int* __restrict__ posbuf, int* __restrict__ ci_all) {
    ll t = (ll)blockIdx.x * blockDim.x + threadIdx.x;
    ll b1 = E2, b2 = b1 + EU1, b3 = b2 + EU2, b4 = b3 + EI1, b5 = b4 + EI2;
    if (t >= b5) return;
    int r, c, roff;
    if (t < b1) {
        r = uiR[t]; c = uiC[t]; roff = 0;
    } else if (t < b2) {
        ll e = t - b1; r = u1d[e]; c = u1s[e]; roff = N;
    } else if (t < b3) {
        ll e = t - b2; r = u2d[e]; c = u2s[e]; roff = N + U;
    } else if (t < b4) {
        ll e = t - b3; r = i1d[e]; c = i1s[e]; roff = N + 2 * U;
    } else {
        ll e = t - b4; r = i2d[e]; c = i2s[e]; roff = N + 2 * U + I;
    }
    int copy = (int)((t >> 8) & 7);
    int idx = roff + r;
    ci_all[(ll)S[idx] + counts8[(ll)copy * M2 + idx] + posbuf[t]] = c;
}

// ---------------- init features ----------------
__global__ void k_init(const void* __restrict__ uf, const void* __restrict__ itf,
                       float* __restrict__ ui, float* __restrict__ hu, float* __restrict__ hi,
                       const ll nu64, const ll ntot64, const int* __restrict__ flag) {
    ll t = (ll)blockIdx.x * blockDim.x + threadIdx.x;
    int bf = *flag;
    if (t < nu64) {
        float v = load_in(uf, t, bf);
        ui[t] = v; hu[t] = v;
    } else if (t < ntot64) {
        ll j = t - nu64;
        float v = load_in(itf, j, bf);
        ui[t] = v; hi[j] = v;
    }
}

// ---------------- gather SpMM ----------------
__global__ __launch_bounds__(256) void k_gather(const int* __restrict__ row_ptr,
                                                const int* __restrict__ col_idx,
                                                const float* __restrict__ x,
                                                const float* __restrict__ cnorm,
                                                const float* __restrict__ rnorm,
                                                float* __restrict__ out, const int nrows) {
    ll gt = (ll)blockIdx.x * blockDim.x + threadIdx.x;
    int w = (int)(gt >> 6);
    int d = (int)(gt & 63);
    if (w >= nrows) return;
    int s = row_ptr[w], e = row_ptr[w + 1];
    float accA = 0.0f, accB = 0.0f;
    int j = s;
    for (; j + 8 <= e; j += 8) {
        int c0 = col_idx[j],     c1 = col_idx[j + 1], c2 = col_idx[j + 2], c3 = col_idx[j + 3];
        int c4 = col_idx[j + 4], c5 = col_idx[j + 5], c6 = col_idx[j + 6], c7 = col_idx[j + 7];
        float n0 = cnorm[c0], n1 = cnorm[c1], n2 = cnorm[c2], n3 = cnorm[c3];
        float n4 = cnorm[c4], n5 = cnorm[c5], n6 = cnorm[c6], n7 = cnorm[c7];
        float x0 = x[(ll)c0 * 64 + d], x1 = x[(ll)c1 * 64 + d];
        float x2 = x[(ll)c2 * 64 + d], x3 = x[(ll)c3 * 64 + d];
        float x4 = x[(ll)c4 * 64 + d], x5 = x[(ll)c5 * 64 + d];
        float x6 = x[(ll)c6 * 64 + d], x7 = x[(ll)c7 * 64 + d];
        accA += x0 * n0 + x2 * n2 + x4 * n4 + x6 * n6;
        accB += x1 * n1 + x3 * n3 + x5 * n5 + x7 * n7;
    }
    for (; j + 2 <= e; j += 2) {
        int c0 = col_idx[j], c1 = col_idx[j + 1];
        accA += x[(ll)c0 * 64 + d] * cnorm[c0];
        accB += x[(ll)c1 * 64 + d] * cnorm[c1];
    }
    if (j < e) {
        int c = col_idx[j];
        accA += x[(ll)c * 64 + d] * cnorm[c];
    }
    out[(ll)w * 64 + d] = (accA + accB) * rnorm[w];
}

// ---------------- fast tanh ----------
__device__ __forceinline__ float fast_tanh(float x) {
    return 1.0f - 2.0f / (__expf(2.0f * x) + 1.0f);
}

__device__ __forceinline__ bf16x8 pack8(float4 a, float4 b) {
    bf16x8 r;
    r[0] = (short)f2bf(a.x); r[1] = (short)f2bf(a.y);
    r[2] = (short)f2bf(a.z); r[3] = (short)f2bf(a.w);
    r[4] = (short)f2bf(b.x); r[5] = (short)f2bf(b.y);
    r[6] = (short)f2bf(b.z); r[7] = (short)f2bf(b.w);
    return r;
}

// ---------------- MFMA semantic-attention scores ----------------
__global__ __launch_bounds__(256) void k_attn_mfma(const float* __restrict__ z1,
                                                   const float* __restrict__ z2,
                                                   const unsigned short* __restrict__ Wb,
                                                   const float* __restrict__ b1f,
                                                   const float* __restrict__ w2f,
                                                   const int n, float* __restrict__ wsum) {
    __shared__ float red0[4], red1[4];
    int tid = threadIdx.x;
    int lane = tid & 63;
    int wid = tid >> 6;
    int col = lane & 15;
    int quad = lane >> 4;

    bf16x8 wb[8][2];
#pragma unroll
    for (int ht = 0; ht < 8; ht++) {
        int h = ht * 16 + col;
#pragma unroll
        for (int ks = 0; ks < 2; ks++) {
            wb[ht][ks] = *(const bf16x8*)&Wb[h * 64 + ks * 32 + quad * 8];
        }
    }
    float b1v[8], w2v[8];
#pragma unroll
    for (int ht = 0; ht < 8; ht++) {
        b1v[ht] = b1f[ht * 16 + col];
        w2v[ht] = w2f[ht * 16 + col];
    }

    float w0 = 0.0f, w1 = 0.0f;
    int ntiles = (n + 15) >> 4;
    int gw = blockIdx.x * 4 + wid;
    int nw = gridDim.x * 4;
    const float4 zero4 = make_float4(0.f, 0.f, 0.f, 0.f);

    for (int tile = gw; tile < ntiles; tile += nw) {
        int nodeA = tile * 16 + col;
        bool va = nodeA < n;
        bf16x8 a1[2], a2[2];
#pragma unroll
        for (int ks = 0; ks < 2; ks++) {
            const float4* p1 = (const float4*)&z1[(ll)nodeA * 64 + ks * 32 + quad * 8];
            const float4* p2 = (const float4*)&z2[(ll)nodeA * 64 + ks * 32 + quad * 8];
            float4 f0 = va ? p1[0] : zero4;
            float4 f1 = va ? p1[1] : zero4;
            float4 g0 = va ? p2[0] : zero4;
            float4 g1 = va ? p2[1] : zero4;
            a1[ks] = pack8(f0, f1);
            a2[ks] = pack8(g0, g1);
        }
#pragma unroll
        for (int ht = 0; ht < 8; ht++) {
            f32x4 c1 = {0.f, 0.f, 0.f, 0.f};
            f32x4 c2 = {0.f, 0.f, 0.f, 0.f};
            c1 = __builtin_amdgcn_mfma_f32_16x16x32_bf16(a1[0], wb[ht][0], c1, 0, 0, 0);
            c1 = __builtin_amdgcn_mfma_f32_16x16x32_bf16(a1[1], wb[ht][1], c1, 0, 0, 0);
            c2 = __builtin_amdgcn_mfma_f32_16x16x32_bf16(a2[0], wb[ht][0], c2, 0, 0, 0);
            c2 = __builtin_amdgcn_mfma_f32_16x16x32_bf16(a2[1], wb[ht][1], c2, 0, 0, 0);
#pragma unroll
            for (int r = 0; r < 4; r++) {
                int node_row = tile * 16 + quad * 4 + r;
                bool vr = node_row < n;
                float t1 = fast_tanh(c1[r] + b1v[ht]) * w2v[ht];
                float t2 = fast_tanh(c2[r] + b1v[ht]) * w2v[ht];
                w0 += vr ? t1 : 0.0f;
                w1 += vr ? t2 : 0.0f;
            }
        }
    }

    for (int off = 32; off > 0; off >>= 1) {
        w0 += __shfl_down(w0, off);
        w1 += __shfl_down(w1, off);
    }
    if (lane == 0) { red0[wid] = w0; red1[wid] = w1; }
    __syncthreads();
    if (tid == 0) {
        atomicAdd(&wsum[0], red0[0] + red0[1] + red0[2] + red0[3]);
        atomicAdd(&wsum[1], red1[0] + red1[1] + red1[2] + red1[3]);
    }
}

// ---------------- combine with inline beta softmax ----------------
__global__ void k_combine(const float* __restrict__ z1, const float* __restrict__ z2,
                          const float* __restrict__ wsum, const float inv_n,
                          float* __restrict__ h, const ll n64) {
    ll t = (ll)blockIdx.x * blockDim.x + threadIdx.x;
    if (t < n64) {
        float m0 = wsum[0] * inv_n, m1 = wsum[1] * inv_n;
        float mx = fmaxf(m0, m1);
        float e0 = __expf(m0 - mx), e1 = __expf(m1 - mx);
        float inv_s = 1.0f / (e0 + e1);
        h[t] = (e0 * z1[t] + e1 * z2[t]) * inv_s;
    }
}

// ---------------- fused output gather ----------------
__device__ __forceinline__ void store_out(void* out, ll i, float v, int isbf16) {
    if (isbf16) ((__hip_bfloat16*)out)[i] = __float2bfloat16(v);
    else ((float*)out)[i] = v;
}

__global__ void k_out(const float* __restrict__ hu, const float* __restrict__ hi,
                      const float* __restrict__ ui, const int* __restrict__ user_idx,
                      const int* __restrict__ item_idx, const int* __restrict__ neg_idx,
                      void* __restrict__ out, const int B, const ll U,
                      const int* __restrict__ flag) {
    ll t = (ll)blockIdx.x * blockDim.x + threadIdx.x;
    int bf = *flag;
    int d = (int)(t & 63);
    ll b = t >> 6;
    if (b < B) {
        int u = user_idx[b];
        float v = 0.5f * hu[(ll)u * 64 + d] + 0.5f * ui[(ll)u * 64 + d];
        store_out(out, b * 64 + d, v, bf);
    } else if (b < 2 * (ll)B) {
        ll bb = b - B;
        int it = item_idx[bb];
        float v = 0.5f * hi[(ll)it * 64 + d] + 0.5f * ui[(U + it) * 64 + d];
        store_out(out, (ll)B * 64 + bb * 64 + d, v, bf);
    } else if (b < 3 * (ll)B) {
        ll bb = b - 2 * (ll)B;
        int it = item_idx[neg_idx[bb]];
        float v = 0.5f * hi[(ll)it * 64 + d] + 0.5f * ui[(U + it) * 64 + d];
        store_out(out, (ll)2 * B * 64 + bb * 64 + d, v, bf);
    }
}

extern "C" void kernel_launch(void* const* d_in, const int* in_sizes, int n_in,
                              void* d_out, int out_size, void* d_ws, size_t ws_size,
                              hipStream_t stream) {
    const int D = 64;
    const ll U = in_sizes[0] / D;
    const ll I = in_sizes[1] / D;
    const ll N = U + I;
    const ll E2  = in_sizes[8] / 2;
    const ll EU1 = in_sizes[9] / 2;
    const ll EU2 = in_sizes[10] / 2;
    const ll EI1 = in_sizes[11] / 2;
    const ll EI2 = in_sizes[12] / 2;
    const ll ET = E2 + EU1 + EU2 + EI1 + EI2;
    const int B = in_sizes[13];
    const int M = (int)(N + 2 * U + 2 * I);          // scanned region
    const int M2 = (int)(N + 4 * U + 4 * I);         // + src-count region

    const void* user_feat = d_in[0];
    const void* item_feat = d_in[1];
    const int* ui_row = (const int*)d_in[8];
    const int* ui_col = ui_row + E2;
    const int* u1_src = (const int*)d_in[9];
    const int* u1_dst = u1_src + EU1;
    const int* u2_src = (const int*)d_in[10];
    const int* u2_dst = u2_src + EU2;
    const int* i1_src = (const int*)d_in[11];
    const int* i1_dst = i1_src + EI1;
    const int* i2_src = (const int*)d_in[12];
    const int* i2_dst = i2_src + EI2;
    const int* user_idx = (const int*)d_in[13];
    const int* item_idx = (const int*)d_in[14];
    const int* neg_idx  = (const int*)d_in[15];

    // ---------------- workspace layout ----------------
    float* p = (float*)d_ws;
    float* ui0 = p;  p += N * 64;
    float* ui1 = p;  p += N * 64;
    float* hu  = p;  p += U * 64;
    float* hi  = p;  p += I * 64;
    float* z1  = p;  p += I * 64;   // reused as posbuf (int) during CSR build
    float* z2  = p;  p += I * 64;
    float* nrm = p;  p += M2;
    unsigned short* Wbu = (unsigned short*)p; p += 64 * 128 / 2;
    unsigned short* Wbi = (unsigned short*)p; p += 64 * 128 / 2;
    float* wb1u = p; p += 128;
    float* ww2u = p; p += 128;
    float* wb1i = p; p += 128;
    float* ww2i = p; p += 128;
    float* scratch = p; p += 16;

    int* ip = (int*)p;
    int* counts8 = ip; ip += (ll)8 * M2;  // zeroed; after reduce: exclusive per-copy offsets
    int* counts = ip; ip += M2;           // totals (written by reduce)
    int* S = ip; ip += M + 1;
    int* ci_all = ip; ip += ET;
    int* bsum = ip; ip += 256;
    int* flag = ip; ip += 4;
    size_t needed = (size_t)((char*)ip - (char*)d_ws);
    if (ws_size < needed) return;
    int* posbuf = (int*)z1;               // ET ints <= I*64 floats

    const int T = 256;

    // ---------------- dtype detection + weight conversion ----------------
    k_detect<<<1, 256, 0, stream>>>((const unsigned int*)user_feat, (ll)in_sizes[0] / 2, flag);
    k_cvt_weights<<<cdiv_ll(2 * (64 * 128 + 256), T), T, 0, stream>>>(
        d_in[2], d_in[3], d_in[4], d_in[5], d_in[6], d_in[7],
        Wbu, wb1u, ww2u, Wbi, wb1i, ww2i, flag);

    // ---------------- CSR build ----------------
    hipMemsetAsync(counts8, 0, (size_t)8 * M2 * sizeof(int), stream);
    hipMemsetAsync(scratch, 0, 16 * sizeof(float), stream);
    k_count_all<<<cdiv_ll(ET, T), T, 0, stream>>>(
        ui_row, u1_src, u1_dst, u2_src, u2_dst, i1_src, i1_dst, i2_src, i2_dst,
        E2, EU1, EU2, EI1, EI2, (int)N, (int)U, (int)I, M2, counts8, posbuf);
    k_reduce8<<<cdiv_ll(M2, T), T, 0, stream>>>(counts8, counts, M2);
    k_norm_all<<<cdiv_ll(M2, T), T, 0, stream>>>(counts, nrm, (int)N, M2);
    {
        int nb = (M + SCAN_CHUNK - 1) / SCAN_CHUNK;
        k_scanA<<<nb, SCAN_T, 0, stream>>>(counts, M, S, bsum);
        k_scanB<<<1, 256, 0, stream>>>(bsum, nb);
        k_scanC<<<cdiv_ll(M, T), T, 0, stream>>>(S, M, bsum, (int)ET);
    }
    k_fill_all<<<cdiv_ll(ET, T), T, 0, stream>>>(
        ui_row, ui_col, u1_src, u1_dst, u2_src, u2_dst, i1_src, i1_dst, i2_src, i2_dst,
        E2, EU1, EU2, EI1, EI2, (int)N, (int)U, (int)I, M2, S, counts8, posbuf, ci_all);

    // ---------------- init features ----------------
    k_init<<<cdiv_ll(N * 64, T), T, 0, stream>>>(user_feat, item_feat, ui0, hu, hi, U * 64, N * 64, flag);

    // CSR segment row_ptr views
    const int* rp_ui = S;
    const int* rp_u1 = S + N;
    const int* rp_u2 = S + N + U;
    const int* rp_i1 = S + N + 2 * U;
    const int* rp_i2 = S + N + 2 * U + I;
    // norm views
    const float* dinv = nrm;
    const float* n_u1r = nrm + N;          const float* n_u2r = nrm + N + U;
    const float* n_i1r = nrm + N + 2 * U;  const float* n_i2r = nrm + N + 2 * U + I;
    const float* n_u1s = nrm + M;          const float* n_u2s = nrm + M + U;
    const float* n_i1s = nrm + M + 2 * U;  const float* n_i2s = nrm + M + 2 * U + I;

    float* uiA = ui0;
    float* uiB = ui1;
    const int ATTN_BLOCKS = 512;

    for (int layer = 0; layer < 2; layer++) {
        float* wsU = scratch + (layer ? 8 : 0);
        float* wsI = scratch + (layer ? 12 : 4);

        // ---- gcn_spmm ----
        k_gather<<<cdiv_ll(N * 64, T), T, 0, stream>>>(rp_ui, ci_all, uiA, dinv, dinv, uiB, (int)N);
        { float* tmp = uiA; uiA = uiB; uiB = tmp; }

        // ---- HAN: users ----
        k_gather<<<cdiv_ll(U * 64, T), T, 0, stream>>>(rp_u1, ci_all, hu, n_u1s, n_u1r, z1, (int)U);
        k_gather<<<cdiv_ll(U * 64, T), T, 0, stream>>>(rp_u2, ci_all, hu, n_u2s, n_u2r, z2, (int)U);
        k_attn_mfma<<<ATTN_BLOCKS, T, 0, stream>>>(z1, z2, Wbu, wb1u, ww2u, (int)U, wsU);
        k_combine<<<cdiv_ll(U * 64, T), T, 0, stream>>>(z1, z2, wsU, 1.0f / (float)U, hu, U * 64);

        // ---- HAN: items ----
        k_gather<<<cdiv_ll(I * 64, T), T, 0, stream>>>(rp_i1, ci_all, hi, n_i1s, n_i1r, z1, (int)I);
        k_gather<<<cdiv_ll(I * 64, T), T, 0, stream>>>(rp_i2, ci_all, hi, n_i2s, n_i2r, z2, (int)I);
        k_attn_mfma<<<ATTN_BLOCKS, T, 0, stream>>>(z1, z2, Wbi, wb1i, ww2i, (int)I, wsI);
        k_combine<<<cdiv_ll(I * 64, T), T, 0, stream>>>(z1, z2, wsI, 1.0f / (float)I, hi, I * 64);
    }

    // ---------------- final ----------------
    k_out<<<cdiv_ll((ll)3 * B * 64, T), T, 0, stream>>>(hu, hi, uiA, user_idx, item_idx, neg_idx,
                                                        d_out, B, U, flag);
}

// Round 9
// 1223.112 us; speedup vs baseline: 2.9306x; 1.0740x over previous
//
#include <hip/hip_runtime.h>
#include <hip/hip_bf16.h>
#include <stdint.h>

typedef long long ll;
typedef unsigned short ushort_t;
typedef __attribute__((ext_vector_type(8))) short bf16x8;
typedef __attribute__((ext_vector_type(4))) float f32x4;

static inline int cdiv_ll(ll a, int b) { return (int)((a + (ll)b - 1) / (ll)b); }

// ---------------- dtype detection (bf16 vs fp32 inputs) ----------------
__global__ void k_detect(const unsigned int* __restrict__ dw, const ll n_dw, int* __restrict__ flag) {
    __shared__ int sc[256];
    int tid = threadIdx.x;
    int cnt = 0;
    for (int s = 0; s < 32; s++) {
        ll idx = (ll)(s * 256 + tid);
        ll i = (idx * n_dw) / 8192;
        unsigned v = dw[i];
        unsigned lo = v & 0xFFFFu;
        unsigned ex = (lo >> 7) & 0xFFu;
        bool pl = (lo == 0u) || (lo == 0x8000u) || (ex >= 0x60u && ex <= 0x8Fu);
        cnt += pl ? 1 : 0;
    }
    sc[tid] = cnt;
    __syncthreads();
    for (int o = 128; o > 0; o >>= 1) { if (tid < o) sc[tid] += sc[tid + o]; __syncthreads(); }
    if (tid == 0) *flag = (sc[0] * 2 > 8192) ? 1 : 0;
}

__device__ __forceinline__ float load_in(const void* p, ll i, int isbf16) {
    if (isbf16) return __bfloat162float(((const __hip_bfloat16*)p)[i]);
    return ((const float*)p)[i];
}

// bf16 bits -> fp32
__device__ __forceinline__ float bf2f(ushort_t u) {
    return __uint_as_float(((unsigned)u) << 16);
}
// round-to-nearest-even fp32 -> bf16 bits (finite inputs)
__device__ __forceinline__ ushort_t f2bf(float f) {
    unsigned u = __float_as_uint(f);
    unsigned r = (u + 0x7FFFu + ((u >> 16) & 1u)) >> 16;
    return (ushort_t)r;
}

// ---------------- fused weight conversion ----------------
__global__ void k_cvt_weights(const void* __restrict__ W1u, const void* __restrict__ b1u,
                              const void* __restrict__ w2u, const void* __restrict__ W1i,
                              const void* __restrict__ b1i, const void* __restrict__ w2i,
                              ushort_t* __restrict__ Wbu, float* __restrict__ fb1u,
                              float* __restrict__ fw2u, ushort_t* __restrict__ Wbi,
                              float* __restrict__ fb1i, float* __restrict__ fw2i,
                              const int* __restrict__ flag) {
    int i = blockIdx.x * blockDim.x + threadIdx.x;
    int bf = *flag;
    const int WSZ = 64 * 128;
    if (i < WSZ) {
        int d = i >> 7, h = i & 127;
        Wbu[h * 64 + d] = f2bf(load_in(W1u, i, bf));
    } else if (i < WSZ + 128) {
        fb1u[i - WSZ] = load_in(b1u, i - WSZ, bf);
    } else if (i < WSZ + 256) {
        fw2u[i - WSZ - 128] = load_in(w2u, i - WSZ - 128, bf);
    } else if (i < 2 * WSZ + 256) {
        int j = i - WSZ - 256;
        int d = j >> 7, h = j & 127;
        Wbi[h * 64 + d] = f2bf(load_in(W1i, j, bf));
    } else if (i < 2 * WSZ + 384) {
        fb1i[i - 2 * WSZ - 256] = load_in(b1i, i - 2 * WSZ - 256, bf);
    } else if (i < 2 * WSZ + 512) {
        fw2i[i - 2 * WSZ - 384] = load_in(w2i, i - 2 * WSZ - 384, bf);
    }
}

// ---------------- fused count (+pos capture), 8 privatized copies ----------
__global__ void k_count_all(const int* __restrict__ uiR,
                            const int* __restrict__ u1s, const int* __restrict__ u1d,
                            const int* __restrict__ u2s, const int* __restrict__ u2d,
                            const int* __restrict__ i1s, const int* __restrict__ i1d,
                            const int* __restrict__ i2s, const int* __restrict__ i2d,
                            const ll E2, const ll EU1, const ll EU2, const ll EI1, const ll EI2,
                            const int N, const int U, const int I, const int M2,
                            int* __restrict__ counts8, int* __restrict__ posbuf) {
    ll t = (ll)blockIdx.x * blockDim.x + threadIdx.x;
    ll b1 = E2, b2 = b1 + EU1, b3 = b2 + EU2, b4 = b3 + EI1, b5 = b4 + EI2;
    if (t >= b5) return;
    int* cnt = counts8 + (ll)(blockIdx.x & 7) * M2;
    int M = N + 2 * U + 2 * I;
    int r, s, roff, soff;
    if (t < b1) {
        r = uiR[t]; roff = 0; soff = -1; s = 0;
    } else if (t < b2) {
        ll e = t - b1; r = u1d[e]; s = u1s[e]; roff = N; soff = M;
    } else if (t < b3) {
        ll e = t - b2; r = u2d[e]; s = u2s[e]; roff = N + U; soff = M + U;
    } else if (t < b4) {
        ll e = t - b3; r = i1d[e]; s = i1s[e]; roff = N + 2 * U; soff = M + 2 * U;
    } else {
        ll e = t - b4; r = i2d[e]; s = i2s[e]; roff = N + 2 * U + I; soff = M + 2 * U + I;
    }
    int pos = atomicAdd(&cnt[roff + r], 1);
    posbuf[t] = pos;
    if (soff >= 0) atomicAdd(&cnt[soff + s], 1);
}

// ---------------- reduce 8 copies -> totals; copies -> exclusive offsets ----
__global__ void k_reduce8(int* __restrict__ counts8, int* __restrict__ totals,
                          const int M2) {
    int i = blockIdx.x * blockDim.x + threadIdx.x;
    if (i >= M2) return;
    int run = 0;
#pragma unroll
    for (int c = 0; c < 8; c++) {
        int v = counts8[(ll)c * M2 + i];
        counts8[(ll)c * M2 + i] = run;
        run += v;
    }
    totals[i] = run;
}

// ---------------- fused norms ----------------
__global__ void k_norm_all(const int* __restrict__ counts, float* __restrict__ nrm,
                           const int N, const int total) {
    int i = blockIdx.x * blockDim.x + threadIdx.x;
    if (i < total) {
        int c = counts[i];
        if (i < N) nrm[i] = (c > 0) ? (1.0f / sqrtf((float)c)) : 0.0f;
        else nrm[i] = 1.0f / sqrtf(fmaxf((float)c, 1.0f));
    }
}

// ---------------- hierarchical exclusive scan ----------
#define SCAN_T 256
#define SCAN_ELEMS 8
#define SCAN_CHUNK (SCAN_T * SCAN_ELEMS)   // 2048

__global__ __launch_bounds__(256) void k_scanA(const int* __restrict__ in, const int n,
                                               int* __restrict__ out, int* __restrict__ bsum) {
    __shared__ int sh[SCAN_T];
    int t = threadIdx.x;
    ll base = (ll)blockIdx.x * SCAN_CHUNK + (ll)t * SCAN_ELEMS;
    int v[SCAN_ELEMS];
    int tot = 0;
#pragma unroll
    for (int k = 0; k < SCAN_ELEMS; k++) {
        ll i = base + k;
        v[k] = (i < n) ? in[i] : 0;
        tot += v[k];
    }
    sh[t] = tot;
    __syncthreads();
    for (int off = 1; off < SCAN_T; off <<= 1) {
        int x = (t >= off) ? sh[t - off] : 0;
        __syncthreads();
        sh[t] += x;
        __syncthreads();
    }
    int run = sh[t] - tot;
#pragma unroll
    for (int k = 0; k < SCAN_ELEMS; k++) {
        ll i = base + k;
        if (i < n) out[i] = run;
        run += v[k];
    }
    if (t == SCAN_T - 1) bsum[blockIdx.x] = sh[SCAN_T - 1];
}

__global__ __launch_bounds__(256) void k_scanB(int* __restrict__ bsum, const int nb) {
    __shared__ int sh[256];
    int t = threadIdx.x;
    int running = 0;
    for (int base = 0; base < nb; base += 256) {
        int idx = base + t;
        int v = (idx < nb) ? bsum[idx] : 0;
        sh[t] = v;
        __syncthreads();
        for (int off = 1; off < 256; off <<= 1) {
            int x = (t >= off) ? sh[t - off] : 0;
            __syncthreads();
            sh[t] += x;
            __syncthreads();
        }
        if (idx < nb) bsum[idx] = running + sh[t] - v;
        int tot = sh[255];
        __syncthreads();
        running += tot;
    }
}

__global__ void k_scanC(int* __restrict__ S, const int n, const int* __restrict__ bsum, const int ET) {
    ll i = (ll)blockIdx.x * blockDim.x + threadIdx.x;
    if (i < n) S[i] += bsum[i / SCAN_CHUNK];
    if (i == 0) S[n] = ET;
}

// ---------------- fused fill (atomic-free) ----------------
__global__ void k_fill_all(const int* __restrict__ uiR, const int* __restrict__ uiC,
                           const int* __restrict__ u1s, const int* __restrict__ u1d,
                           const int* __restrict__ u2s, const int* __restrict__ u2d,
                           const int* __restrict__ i1s, const int* __restrict__ i1d,
                           const int* __restrict__ i2s, const int* __restrict__ i2d,
                           const ll E2, const ll EU1, const ll EU2, const ll EI1, const ll EI2,
                           const int N, const int U, const int I, const int M2,
                           const int* __restrict__ S, const int* __restrict__ counts8,
                           const int* __restrict__ posbuf, int* __restrict__ ci_all) {
    ll t = (ll)blockIdx.x * blockDim.x + threadIdx.x;
    ll b1 = E2, b2 = b1 + EU1, b3 = b2 + EU2, b4 = b3 + EI1, b5 = b4 + EI2;
    if (t >= b5) return;
    int r, c, roff;
    if (t < b1) {
        r = uiR[t]; c = uiC[t]; roff = 0;
    } else if (t < b2) {
        ll e = t - b1; r = u1d[e]; c = u1s[e]; roff = N;
    } else if (t < b3) {
        ll e = t - b2; r = u2d[e]; c = u2s[e]; roff = N + U;
    } else if (t < b4) {
        ll e = t - b3; r = i1d[e]; c = i1s[e]; roff = N + 2 * U;
    } else {
        ll e = t - b4; r = i2d[e]; c = i2s[e]; roff = N + 2 * U + I;
    }
    int copy = (int)((t >> 8) & 7);
    int idx = roff + r;
    ci_all[(ll)S[idx] + counts8[(ll)copy * M2 + idx] + posbuf[t]] = c;
}

// ---------------- init features (bf16 storage) ----------------
__global__ void k_init(const void* __restrict__ uf, const void* __restrict__ itf,
                       ushort_t* __restrict__ ui, ushort_t* __restrict__ hu,
                       ushort_t* __restrict__ hi,
                       const ll nu64, const ll ntot64, const int* __restrict__ flag) {
    ll t = (ll)blockIdx.x * blockDim.x + threadIdx.x;
    int bf = *flag;
    if (t < nu64) {
        ushort_t v = bf ? ((const ushort_t*)uf)[t] : f2bf(((const float*)uf)[t]);
        ui[t] = v; hu[t] = v;
    } else if (t < ntot64) {
        ll j = t - nu64;
        ushort_t v = bf ? ((const ushort_t*)itf)[j] : f2bf(((const float*)itf)[j]);
        ui[t] = v; hi[j] = v;
    }
}

// ---------------- gather SpMM (bf16 features, fp32 accumulate) ----------
__global__ __launch_bounds__(256) void k_gather(const int* __restrict__ row_ptr,
                                                const int* __restrict__ col_idx,
                                                const ushort_t* __restrict__ x,
                                                const float* __restrict__ cnorm,
                                                const float* __restrict__ rnorm,
                                                ushort_t* __restrict__ out, const int nrows) {
    ll gt = (ll)blockIdx.x * blockDim.x + threadIdx.x;
    int w = (int)(gt >> 6);
    int d = (int)(gt & 63);
    if (w >= nrows) return;
    int s = row_ptr[w], e = row_ptr[w + 1];
    float accA = 0.0f, accB = 0.0f;
    int j = s;
    for (; j + 8 <= e; j += 8) {
        int c0 = col_idx[j],     c1 = col_idx[j + 1], c2 = col_idx[j + 2], c3 = col_idx[j + 3];
        int c4 = col_idx[j + 4], c5 = col_idx[j + 5], c6 = col_idx[j + 6], c7 = col_idx[j + 7];
        float n0 = cnorm[c0], n1 = cnorm[c1], n2 = cnorm[c2], n3 = cnorm[c3];
        float n4 = cnorm[c4], n5 = cnorm[c5], n6 = cnorm[c6], n7 = cnorm[c7];
        float x0 = bf2f(x[(ll)c0 * 64 + d]), x1 = bf2f(x[(ll)c1 * 64 + d]);
        float x2 = bf2f(x[(ll)c2 * 64 + d]), x3 = bf2f(x[(ll)c3 * 64 + d]);
        float x4 = bf2f(x[(ll)c4 * 64 + d]), x5 = bf2f(x[(ll)c5 * 64 + d]);
        float x6 = bf2f(x[(ll)c6 * 64 + d]), x7 = bf2f(x[(ll)c7 * 64 + d]);
        accA += x0 * n0 + x2 * n2 + x4 * n4 + x6 * n6;
        accB += x1 * n1 + x3 * n3 + x5 * n5 + x7 * n7;
    }
    for (; j + 2 <= e; j += 2) {
        int c0 = col_idx[j], c1 = col_idx[j + 1];
        accA += bf2f(x[(ll)c0 * 64 + d]) * cnorm[c0];
        accB += bf2f(x[(ll)c1 * 64 + d]) * cnorm[c1];
    }
    if (j < e) {
        int c = col_idx[j];
        accA += bf2f(x[(ll)c * 64 + d]) * cnorm[c];
    }
    out[(ll)w * 64 + d] = f2bf((accA + accB) * rnorm[w]);
}

// ---------------- fast tanh ----------
__device__ __forceinline__ float fast_tanh(float x) {
    return 1.0f - 2.0f / (__expf(2.0f * x) + 1.0f);
}

// ---------------- MFMA semantic-attention scores (bf16 z: direct A-frags) ----
__global__ __launch_bounds__(256) void k_attn_mfma(const ushort_t* __restrict__ z1,
                                                   const ushort_t* __restrict__ z2,
                                                   const ushort_t* __restrict__ Wb,
                                                   const float* __restrict__ b1f,
                                                   const float* __restrict__ w2f,
                                                   const int n, float* __restrict__ wsum) {
    __shared__ float red0[4], red1[4];
    int tid = threadIdx.x;
    int lane = tid & 63;
    int wid = tid >> 6;
    int col = lane & 15;
    int quad = lane >> 4;

    bf16x8 wb[8][2];
#pragma unroll
    for (int ht = 0; ht < 8; ht++) {
        int h = ht * 16 + col;
#pragma unroll
        for (int ks = 0; ks < 2; ks++) {
            wb[ht][ks] = *(const bf16x8*)&Wb[h * 64 + ks * 32 + quad * 8];
        }
    }
    float b1v[8], w2v[8];
#pragma unroll
    for (int ht = 0; ht < 8; ht++) {
        b1v[ht] = b1f[ht * 16 + col];
        w2v[ht] = w2f[ht * 16 + col];
    }

    float w0 = 0.0f, w1 = 0.0f;
    int ntiles = (n + 15) >> 4;
    int gw = blockIdx.x * 4 + wid;
    int nw = gridDim.x * 4;
    const bf16x8 zero8 = {0, 0, 0, 0, 0, 0, 0, 0};

    for (int tile = gw; tile < ntiles; tile += nw) {
        int nodeA = tile * 16 + col;
        bool va = nodeA < n;
        bf16x8 a1[2], a2[2];
#pragma unroll
        for (int ks = 0; ks < 2; ks++) {
            const bf16x8* p1 = (const bf16x8*)&z1[(ll)nodeA * 64 + ks * 32 + quad * 8];
            const bf16x8* p2 = (const bf16x8*)&z2[(ll)nodeA * 64 + ks * 32 + quad * 8];
            a1[ks] = va ? p1[0] : zero8;
            a2[ks] = va ? p2[0] : zero8;
        }
#pragma unroll
        for (int ht = 0; ht < 8; ht++) {
            f32x4 c1 = {0.f, 0.f, 0.f, 0.f};
            f32x4 c2 = {0.f, 0.f, 0.f, 0.f};
            c1 = __builtin_amdgcn_mfma_f32_16x16x32_bf16(a1[0], wb[ht][0], c1, 0, 0, 0);
            c1 = __builtin_amdgcn_mfma_f32_16x16x32_bf16(a1[1], wb[ht][1], c1, 0, 0, 0);
            c2 = __builtin_amdgcn_mfma_f32_16x16x32_bf16(a2[0], wb[ht][0], c2, 0, 0, 0);
            c2 = __builtin_amdgcn_mfma_f32_16x16x32_bf16(a2[1], wb[ht][1], c2, 0, 0, 0);
#pragma unroll
            for (int r = 0; r < 4; r++) {
                int node_row = tile * 16 + quad * 4 + r;
                bool vr = node_row < n;
                float t1 = fast_tanh(c1[r] + b1v[ht]) * w2v[ht];
                float t2 = fast_tanh(c2[r] + b1v[ht]) * w2v[ht];
                w0 += vr ? t1 : 0.0f;
                w1 += vr ? t2 : 0.0f;
            }
        }
    }

    for (int off = 32; off > 0; off >>= 1) {
        w0 += __shfl_down(w0, off);
        w1 += __shfl_down(w1, off);
    }
    if (lane == 0) { red0[wid] = w0; red1[wid] = w1; }
    __syncthreads();
    if (tid == 0) {
        atomicAdd(&wsum[0], red0[0] + red0[1] + red0[2] + red0[3]);
        atomicAdd(&wsum[1], red1[0] + red1[1] + red1[2] + red1[3]);
    }
}

// ---------------- combine with inline beta softmax (bf16 in/out) ----------
__global__ void k_combine(const ushort_t* __restrict__ z1, const ushort_t* __restrict__ z2,
                          const float* __restrict__ wsum, const float inv_n,
                          ushort_t* __restrict__ h, const ll n64) {
    ll t = (ll)blockIdx.x * blockDim.x + threadIdx.x;
    if (t < n64) {
        float m0 = wsum[0] * inv_n, m1 = wsum[1] * inv_n;
        float mx = fmaxf(m0, m1);
        float e0 = __expf(m0 - mx), e1 = __expf(m1 - mx);
        float inv_s = 1.0f / (e0 + e1);
        h[t] = f2bf((e0 * bf2f(z1[t]) + e1 * bf2f(z2[t])) * inv_s);
    }
}

// ---------------- fused output gather ----------------
__device__ __forceinline__ void store_out(void* out, ll i, float v, int isbf16) {
    if (isbf16) ((ushort_t*)out)[i] = f2bf(v);
    else ((float*)out)[i] = v;
}

__global__ void k_out(const ushort_t* __restrict__ hu, const ushort_t* __restrict__ hi,
                      const ushort_t* __restrict__ ui, const int* __restrict__ user_idx,
                      const int* __restrict__ item_idx, const int* __restrict__ neg_idx,
                      void* __restrict__ out, const int B, const ll U,
                      const int* __restrict__ flag) {
    ll t = (ll)blockIdx.x * blockDim.x + threadIdx.x;
    int bf = *flag;
    int d = (int)(t & 63);
    ll b = t >> 6;
    if (b < B) {
        int u = user_idx[b];
        float v = 0.5f * bf2f(hu[(ll)u * 64 + d]) + 0.5f * bf2f(ui[(ll)u * 64 + d]);
        store_out(out, b * 64 + d, v, bf);
    } else if (b < 2 * (ll)B) {
        ll bb = b - B;
        int it = item_idx[bb];
        float v = 0.5f * bf2f(hi[(ll)it * 64 + d]) + 0.5f * bf2f(ui[(U + it) * 64 + d]);
        store_out(out, (ll)B * 64 + bb * 64 + d, v, bf);
    } else if (b < 3 * (ll)B) {
        ll bb = b - 2 * (ll)B;
        int it = item_idx[neg_idx[bb]];
        float v = 0.5f * bf2f(hi[(ll)it * 64 + d]) + 0.5f * bf2f(ui[(U + it) * 64 + d]);
        store_out(out, (ll)2 * B * 64 + bb * 64 + d, v, bf);
    }
}

extern "C" void kernel_launch(void* const* d_in, const int* in_sizes, int n_in,
                              void* d_out, int out_size, void* d_ws, size_t ws_size,
                              hipStream_t stream) {
    const int D = 64;
    const ll U = in_sizes[0] / D;
    const ll I = in_sizes[1] / D;
    const ll N = U + I;
    const ll E2  = in_sizes[8] / 2;
    const ll EU1 = in_sizes[9] / 2;
    const ll EU2 = in_sizes[10] / 2;
    const ll EI1 = in_sizes[11] / 2;
    const ll EI2 = in_sizes[12] / 2;
    const ll ET = E2 + EU1 + EU2 + EI1 + EI2;
    const int B = in_sizes[13];
    const int M = (int)(N + 2 * U + 2 * I);
    const int M2 = (int)(N + 4 * U + 4 * I);

    const void* user_feat = d_in[0];
    const void* item_feat = d_in[1];
    const int* ui_row = (const int*)d_in[8];
    const int* ui_col = ui_row + E2;
    const int* u1_src = (const int*)d_in[9];
    const int* u1_dst = u1_src + EU1;
    const int* u2_src = (const int*)d_in[10];
    const int* u2_dst = u2_src + EU2;
    const int* i1_src = (const int*)d_in[11];
    const int* i1_dst = i1_src + EI1;
    const int* i2_src = (const int*)d_in[12];
    const int* i2_dst = i2_src + EI2;
    const int* user_idx = (const int*)d_in[13];
    const int* item_idx = (const int*)d_in[14];
    const int* neg_idx  = (const int*)d_in[15];

    // ---------------- workspace layout ----------------
    ushort_t* q = (ushort_t*)d_ws;
    ushort_t* ui0 = q; q += N * 64;
    ushort_t* ui1 = q; q += N * 64;
    ushort_t* hu  = q; q += U * 64;
    ushort_t* hi  = q; q += I * 64;
    ushort_t* z1  = q; q += I * 64;   // z1..z2 region doubles as posbuf (ET ints) pre-init
    ushort_t* z2  = q; q += I * 64;
    float* p = (float*)(((uintptr_t)q + 15) & ~(uintptr_t)15);
    float* nrm = p;  p += M2;
    ushort_t* Wbu = (ushort_t*)p; p += 64 * 128 / 2;
    ushort_t* Wbi = (ushort_t*)p; p += 64 * 128 / 2;
    float* wb1u = p; p += 128;
    float* ww2u = p; p += 128;
    float* wb1i = p; p += 128;
    float* ww2i = p; p += 128;
    float* scratch = p; p += 16;

    int* ip = (int*)p;
    int* counts8 = ip; ip += (ll)8 * M2;
    int* counts = ip; ip += M2;
    int* S = ip; ip += M + 1;
    int* ci_all = ip; ip += ET;
    int* bsum = ip; ip += 256;
    int* flag = ip; ip += 4;
    size_t needed = (size_t)((char*)ip - (char*)d_ws);
    if (ws_size < needed) return;
    int* posbuf = (int*)z1;   // ET*4 B <= 2*I*64*2 B (20MB <= 25.6MB)

    const int T = 256;

    // ---------------- dtype detection + weight conversion ----------------
    k_detect<<<1, 256, 0, stream>>>((const unsigned int*)user_feat, (ll)in_sizes[0] / 2, flag);
    k_cvt_weights<<<cdiv_ll(2 * (64 * 128 + 256), T), T, 0, stream>>>(
        d_in[2], d_in[3], d_in[4], d_in[5], d_in[6], d_in[7],
        Wbu, wb1u, ww2u, Wbi, wb1i, ww2i, flag);

    // ---------------- CSR build ----------------
    hipMemsetAsync(counts8, 0, (size_t)8 * M2 * sizeof(int), stream);
    hipMemsetAsync(scratch, 0, 16 * sizeof(float), stream);
    k_count_all<<<cdiv_ll(ET, T), T, 0, stream>>>(
        ui_row, u1_src, u1_dst, u2_src, u2_dst, i1_src, i1_dst, i2_src, i2_dst,
        E2, EU1, EU2, EI1, EI2, (int)N, (int)U, (int)I, M2, counts8, posbuf);
    k_reduce8<<<cdiv_ll(M2, T), T, 0, stream>>>(counts8, counts, M2);
    k_norm_all<<<cdiv_ll(M2, T), T, 0, stream>>>(counts, nrm, (int)N, M2);
    {
        int nb = (M + SCAN_CHUNK - 1) / SCAN_CHUNK;
        k_scanA<<<nb, SCAN_T, 0, stream>>>(counts, M, S, bsum);
        k_scanB<<<1, 256, 0, stream>>>(bsum, nb);
        k_scanC<<<cdiv_ll(M, T), T, 0, stream>>>(S, M, bsum, (int)ET);
    }
    k_fill_all<<<cdiv_ll(ET, T), T, 0, stream>>>(
        ui_row, ui_col, u1_src, u1_dst, u2_src, u2_dst, i1_src, i1_dst, i2_src, i2_dst,
        E2, EU1, EU2, EI1, EI2, (int)N, (int)U, (int)I, M2, S, counts8, posbuf, ci_all);

    // ---------------- init features ----------------
    k_init<<<cdiv_ll(N * 64, T), T, 0, stream>>>(user_feat, item_feat, ui0, hu, hi, U * 64, N * 64, flag);

    // CSR segment row_ptr views
    const int* rp_ui = S;
    const int* rp_u1 = S + N;
    const int* rp_u2 = S + N + U;
    const int* rp_i1 = S + N + 2 * U;
    const int* rp_i2 = S + N + 2 * U + I;
    // norm views
    const float* dinv = nrm;
    const float* n_u1r = nrm + N;          const float* n_u2r = nrm + N + U;
    const float* n_i1r = nrm + N + 2 * U;  const float* n_i2r = nrm + N + 2 * U + I;
    const float* n_u1s = nrm + M;          const float* n_u2s = nrm + M + U;
    const float* n_i1s = nrm + M + 2 * U;  const float* n_i2s = nrm + M + 2 * U + I;

    ushort_t* uiA = ui0;
    ushort_t* uiB = ui1;
    const int ATTN_BLOCKS = 512;

    for (int layer = 0; layer < 2; layer++) {
        float* wsU = scratch + (layer ? 8 : 0);
        float* wsI = scratch + (layer ? 12 : 4);

        // ---- gcn_spmm ----
        k_gather<<<cdiv_ll(N * 64, T), T, 0, stream>>>(rp_ui, ci_all, uiA, dinv, dinv, uiB, (int)N);
        { ushort_t* tmp = uiA; uiA = uiB; uiB = tmp; }

        // ---- HAN: users ----
        k_gather<<<cdiv_ll(U * 64, T), T, 0, stream>>>(rp_u1, ci_all, hu, n_u1s, n_u1r, z1, (int)U);
        k_gather<<<cdiv_ll(U * 64, T), T, 0, stream>>>(rp_u2, ci_all, hu, n_u2s, n_u2r, z2, (int)U);
        k_attn_mfma<<<ATTN_BLOCKS, T, 0, stream>>>(z1, z2, Wbu, wb1u, ww2u, (int)U, wsU);
        k_combine<<<cdiv_ll(U * 64, T), T, 0, stream>>>(z1, z2, wsU, 1.0f / (float)U, hu, U * 64);

        // ---- HAN: items ----
        k_gather<<<cdiv_ll(I * 64, T), T, 0, stream>>>(rp_i1, ci_all, hi, n_i1s, n_i1r, z1, (int)I);
        k_gather<<<cdiv_ll(I * 64, T), T, 0, stream>>>(rp_i2, ci_all, hi, n_i2s, n_i2r, z2, (int)I);
        k_attn_mfma<<<ATTN_BLOCKS, T, 0, stream>>>(z1, z2, Wbi, wb1i, ww2i, (int)I, wsI);
        k_combine<<<cdiv_ll(I * 64, T), T, 0, stream>>>(z1, z2, wsI, 1.0f / (float)I, hi, I * 64);
    }

    // ---------------- final ----------------
    k_out<<<cdiv_ll((ll)3 * B * 64, T), T, 0, stream>>>(hu, hi, uiA, user_idx, item_idx, neg_idx,
                                                        d_out, B, U, flag);
}

// Round 10
// 977.064 us; speedup vs baseline: 3.6686x; 1.2518x over previous
//
#include <hip/hip_runtime.h>
#include <hip/hip_bf16.h>
#include <stdint.h>

typedef long long ll;
typedef unsigned short ushort_t;
typedef __attribute__((ext_vector_type(8))) short bf16x8;
typedef __attribute__((ext_vector_type(4))) float f32x4;

static inline int cdiv_ll(ll a, int b) { return (int)((a + (ll)b - 1) / (ll)b); }

#define BIN_SHIFT 11
#define BIN_SIZE 2048
#define KMAX 512          // max buckets (M2 <= 1M)
#define CHUNK 8192        // records per workgroup in binning passes

// ---------------- dtype detection (bf16 vs fp32 inputs) ----------------
__global__ void k_detect(const unsigned int* __restrict__ dw, const ll n_dw, int* __restrict__ flag) {
    __shared__ int sc[256];
    int tid = threadIdx.x;
    int cnt = 0;
    for (int s = 0; s < 32; s++) {
        ll idx = (ll)(s * 256 + tid);
        ll i = (idx * n_dw) / 8192;
        unsigned v = dw[i];
        unsigned lo = v & 0xFFFFu;
        unsigned ex = (lo >> 7) & 0xFFu;
        bool pl = (lo == 0u) || (lo == 0x8000u) || (ex >= 0x60u && ex <= 0x8Fu);
        cnt += pl ? 1 : 0;
    }
    sc[tid] = cnt;
    __syncthreads();
    for (int o = 128; o > 0; o >>= 1) { if (tid < o) sc[tid] += sc[tid + o]; __syncthreads(); }
    if (tid == 0) *flag = (sc[0] * 2 > 8192) ? 1 : 0;
}

__device__ __forceinline__ float load_in(const void* p, ll i, int isbf16) {
    if (isbf16) return __bfloat162float(((const __hip_bfloat16*)p)[i]);
    return ((const float*)p)[i];
}

__device__ __forceinline__ float bf2f(ushort_t u) {
    return __uint_as_float(((unsigned)u) << 16);
}
__device__ __forceinline__ ushort_t f2bf(float f) {
    unsigned u = __float_as_uint(f);
    unsigned r = (u + 0x7FFFu + ((u >> 16) & 1u)) >> 16;
    return (ushort_t)r;
}

// ---------------- fused weight conversion ----------------
__global__ void k_cvt_weights(const void* __restrict__ W1u, const void* __restrict__ b1u,
                              const void* __restrict__ w2u, const void* __restrict__ W1i,
                              const void* __restrict__ b1i, const void* __restrict__ w2i,
                              ushort_t* __restrict__ Wbu, float* __restrict__ fb1u,
                              float* __restrict__ fw2u, ushort_t* __restrict__ Wbi,
                              float* __restrict__ fb1i, float* __restrict__ fw2i,
                              const int* __restrict__ flag) {
    int i = blockIdx.x * blockDim.x + threadIdx.x;
    int bf = *flag;
    const int WSZ = 64 * 128;
    if (i < WSZ) {
        int d = i >> 7, h = i & 127;
        Wbu[h * 64 + d] = f2bf(load_in(W1u, i, bf));
    } else if (i < WSZ + 128) {
        fb1u[i - WSZ] = load_in(b1u, i - WSZ, bf);
    } else if (i < WSZ + 256) {
        fw2u[i - WSZ - 128] = load_in(w2u, i - WSZ - 128, bf);
    } else if (i < 2 * WSZ + 256) {
        int j = i - WSZ - 256;
        int d = j >> 7, h = j & 127;
        Wbi[h * 64 + d] = f2bf(load_in(W1i, j, bf));
    } else if (i < 2 * WSZ + 384) {
        fb1i[i - 2 * WSZ - 256] = load_in(b1i, i - 2 * WSZ - 256, bf);
    } else if (i < 2 * WSZ + 512) {
        fw2i[i - 2 * WSZ - 384] = load_in(w2i, i - 2 * WSZ - 384, bf);
    }
}

// ---------------- record decode ----------------
// Records: [ui edges: key=row] [u1 dst|u1 src] [u2 dst|src] [i1 dst|src] [i2 dst|src]
// dst records carry col for CSR; src records (key >= M) are degree-only.
__device__ __forceinline__ void decode_rec(ll t,
    const int* __restrict__ uiR, const int* __restrict__ uiC,
    const int* __restrict__ u1s, const int* __restrict__ u1d,
    const int* __restrict__ u2s, const int* __restrict__ u2d,
    const int* __restrict__ i1s, const int* __restrict__ i1d,
    const int* __restrict__ i2s, const int* __restrict__ i2d,
    const ll E2, const ll EU1, const ll EU2, const ll EI1, const ll EI2,
    const int N, const int U, const int I, const int M,
    int& key, int& col) {
    if (t < E2) { key = uiR[t]; col = uiC[t]; return; }
    t -= E2;
    if (t < EU1) { key = N + u1d[t]; col = u1s[t]; return; }
    t -= EU1;
    if (t < EU1) { key = M + u1s[t]; col = 0; return; }
    t -= EU1;
    if (t < EU2) { key = N + U + u2d[t]; col = u2s[t]; return; }
    t -= EU2;
    if (t < EU2) { key = M + U + u2s[t]; col = 0; return; }
    t -= EU2;
    if (t < EI1) { key = N + 2 * U + i1d[t]; col = i1s[t]; return; }
    t -= EI1;
    if (t < EI1) { key = M + 2 * U + i1s[t]; col = 0; return; }
    t -= EI1;
    if (t < EI2) { key = N + 2 * U + I + i2d[t]; col = i2s[t]; return; }
    t -= EI2;
    key = M + 2 * U + I + i2s[t]; col = 0;
}

#define DECODE_ARGS uiR, uiC, u1s, u1d, u2s, u2d, i1s, i1d, i2s, i2d, \
                    E2, EU1, EU2, EI1, EI2, N, U, I, M

// ---------------- pass A1: per-WG LDS histogram -> global bucket totals ----
__global__ __launch_bounds__(256) void kA_hist(
    const int* __restrict__ uiR, const int* __restrict__ uiC,
    const int* __restrict__ u1s, const int* __restrict__ u1d,
    const int* __restrict__ u2s, const int* __restrict__ u2d,
    const int* __restrict__ i1s, const int* __restrict__ i1d,
    const int* __restrict__ i2s, const int* __restrict__ i2d,
    const ll E2, const ll EU1, const ll EU2, const ll EI1, const ll EI2,
    const int N, const int U, const int I, const int M,
    const ll RT, const int K, int* __restrict__ btot /* K*32 line-padded */) {
    __shared__ int hist[KMAX];
    for (int i = threadIdx.x; i < K; i += 256) hist[i] = 0;
    __syncthreads();
    ll base = (ll)blockIdx.x * CHUNK;
    for (int i = 0; i < CHUNK / 256; i++) {
        ll t = base + i * 256 + threadIdx.x;
        if (t < RT) {
            int key, col;
            decode_rec(t, DECODE_ARGS, key, col);
            atomicAdd(&hist[key >> BIN_SHIFT], 1);
        }
    }
    __syncthreads();
    for (int k = threadIdx.x; k < K; k += 256)
        if (hist[k]) atomicAdd(&btot[k * 32], hist[k]);
}

// ---------------- bucket scan: totals -> bases, init cursors ----------------
__global__ __launch_bounds__(512) void k_bscan(const int* __restrict__ btot,
                                               int* __restrict__ bbase,
                                               int* __restrict__ bcursor, const int K) {
    __shared__ int sh[512];
    int t = threadIdx.x;
    int v = (t < K) ? btot[t * 32] : 0;
    sh[t] = v;
    __syncthreads();
    for (int off = 1; off < 512; off <<= 1) {
        int x = (t >= off) ? sh[t - off] : 0;
        __syncthreads();
        sh[t] += x;
        __syncthreads();
    }
    if (t < K) {
        int ex = sh[t] - v;
        bbase[t] = ex;
        bcursor[t * 32] = ex;
    }
}

// ---------------- pass A2: scatter records into bucket-contiguous binned ----
__global__ __launch_bounds__(256) void kA_scatter(
    const int* __restrict__ uiR, const int* __restrict__ uiC,
    const int* __restrict__ u1s, const int* __restrict__ u1d,
    const int* __restrict__ u2s, const int* __restrict__ u2d,
    const int* __restrict__ i1s, const int* __restrict__ i1d,
    const int* __restrict__ i2s, const int* __restrict__ i2d,
    const ll E2, const ll EU1, const ll EU2, const ll EI1, const ll EI2,
    const int N, const int U, const int I, const int M,
    const ll RT, const int K, int* __restrict__ bcursor, int2* __restrict__ binned) {
    __shared__ int hist[KMAX];
    __shared__ int lcur[KMAX];
    for (int i = threadIdx.x; i < K; i += 256) hist[i] = 0;
    __syncthreads();
    ll base = (ll)blockIdx.x * CHUNK;
    for (int i = 0; i < CHUNK / 256; i++) {
        ll t = base + i * 256 + threadIdx.x;
        if (t < RT) {
            int key, col;
            decode_rec(t, DECODE_ARGS, key, col);
            atomicAdd(&hist[key >> BIN_SHIFT], 1);
        }
    }
    __syncthreads();
    for (int k = threadIdx.x; k < K; k += 256) {
        int h = hist[k];
        lcur[k] = h ? atomicAdd(&bcursor[k * 32], h) : 0;
    }
    __syncthreads();
    for (int i = 0; i < CHUNK / 256; i++) {
        ll t = base + i * 256 + threadIdx.x;
        if (t < RT) {
            int key, col;
            decode_rec(t, DECODE_ARGS, key, col);
            int pos = atomicAdd(&lcur[key >> BIN_SHIFT], 1);
            binned[pos] = make_int2(key, col);
        }
    }
}

// ---------------- pass B1: per-bucket LDS count -> counts array ----------
__global__ __launch_bounds__(256) void kB1_count(const int2* __restrict__ binned,
                                                 const int* __restrict__ bbase,
                                                 const int* __restrict__ btot,
                                                 int* __restrict__ counts, const int M2) {
    __shared__ int cnt[BIN_SIZE];
    int b = blockIdx.x;
    int lo = b << BIN_SHIFT;
    int hi = min(lo + BIN_SIZE, M2);
    for (int i = threadIdx.x; i < BIN_SIZE; i += 256) cnt[i] = 0;
    __syncthreads();
    int s = bbase[b], n = btot[b * 32];
    for (int j = s + threadIdx.x; j < s + n; j += 256) {
        atomicAdd(&cnt[binned[j].x - lo], 1);
    }
    __syncthreads();
    for (int i = threadIdx.x; i < hi - lo; i += 256) counts[lo + i] = cnt[i];
}

// ---------------- fused norms ----------------
__global__ void k_norm_all(const int* __restrict__ counts, float* __restrict__ nrm,
                           const int N, const int total) {
    int i = blockIdx.x * blockDim.x + threadIdx.x;
    if (i < total) {
        int c = counts[i];
        if (i < N) nrm[i] = (c > 0) ? (1.0f / sqrtf((float)c)) : 0.0f;
        else nrm[i] = 1.0f / sqrtf(fmaxf((float)c, 1.0f));
    }
}

// ---------------- hierarchical exclusive scan ----------
#define SCAN_T 256
#define SCAN_ELEMS 8
#define SCAN_CHUNK (SCAN_T * SCAN_ELEMS)   // 2048

__global__ __launch_bounds__(256) void k_scanA(const int* __restrict__ in, const int n,
                                               int* __restrict__ out, int* __restrict__ bsum) {
    __shared__ int sh[SCAN_T];
    int t = threadIdx.x;
    ll base = (ll)blockIdx.x * SCAN_CHUNK + (ll)t * SCAN_ELEMS;
    int v[SCAN_ELEMS];
    int tot = 0;
#pragma unroll
    for (int k = 0; k < SCAN_ELEMS; k++) {
        ll i = base + k;
        v[k] = (i < n) ? in[i] : 0;
        tot += v[k];
    }
    sh[t] = tot;
    __syncthreads();
    for (int off = 1; off < SCAN_T; off <<= 1) {
        int x = (t >= off) ? sh[t - off] : 0;
        __syncthreads();
        sh[t] += x;
        __syncthreads();
    }
    int run = sh[t] - tot;
#pragma unroll
    for (int k = 0; k < SCAN_ELEMS; k++) {
        ll i = base + k;
        if (i < n) out[i] = run;
        run += v[k];
    }
    if (t == SCAN_T - 1) bsum[blockIdx.x] = sh[SCAN_T - 1];
}

__global__ __launch_bounds__(256) void k_scanB(int* __restrict__ bsum, const int nb) {
    __shared__ int sh[256];
    int t = threadIdx.x;
    int running = 0;
    for (int base = 0; base < nb; base += 256) {
        int idx = base + t;
        int v = (idx < nb) ? bsum[idx] : 0;
        sh[t] = v;
        __syncthreads();
        for (int off = 1; off < 256; off <<= 1) {
            int x = (t >= off) ? sh[t - off] : 0;
            __syncthreads();
            sh[t] += x;
            __syncthreads();
        }
        if (idx < nb) bsum[idx] = running + sh[t] - v;
        int tot = sh[255];
        __syncthreads();
        running += tot;
    }
}

__global__ void k_scanC(int* __restrict__ S, const int n, const int* __restrict__ bsum, const int ET) {
    ll i = (ll)blockIdx.x * blockDim.x + threadIdx.x;
    if (i < n) S[i] += bsum[i / SCAN_CHUNK];
    if (i == 0) S[n] = ET;
}

// ---------------- pass B2: per-bucket CSR fill via LDS cursors ----------
__global__ __launch_bounds__(256) void kB2_fill(const int2* __restrict__ binned,
                                                const int* __restrict__ bbase,
                                                const int* __restrict__ btot,
                                                const int* __restrict__ S, const int M,
                                                int* __restrict__ ci_all) {
    __shared__ int scur[BIN_SIZE];
    int b = blockIdx.x;
    int lo = b << BIN_SHIFT;
    int hi = min(lo + BIN_SIZE, M);
    for (int i = threadIdx.x; i < hi - lo; i += 256) scur[i] = S[lo + i];
    __syncthreads();
    int s = bbase[b], n = btot[b * 32];
    for (int j = s + threadIdx.x; j < s + n; j += 256) {
        int2 rec = binned[j];
        if (rec.x < M) {
            int pos = atomicAdd(&scur[rec.x - lo], 1);
            ci_all[pos] = rec.y;
        }
    }
}

// ---------------- init features (bf16 storage) ----------------
__global__ void k_init(const void* __restrict__ uf, const void* __restrict__ itf,
                       ushort_t* __restrict__ ui, ushort_t* __restrict__ hu,
                       ushort_t* __restrict__ hi,
                       const ll nu64, const ll ntot64, const int* __restrict__ flag) {
    ll t = (ll)blockIdx.x * blockDim.x + threadIdx.x;
    int bf = *flag;
    if (t < nu64) {
        ushort_t v = bf ? ((const ushort_t*)uf)[t] : f2bf(((const float*)uf)[t]);
        ui[t] = v; hu[t] = v;
    } else if (t < ntot64) {
        ll j = t - nu64;
        ushort_t v = bf ? ((const ushort_t*)itf)[j] : f2bf(((const float*)itf)[j]);
        ui[t] = v; hi[j] = v;
    }
}

// ---------------- gather SpMM (bf16 features, fp32 accumulate) ----------
__global__ __launch_bounds__(256) void k_gather(const int* __restrict__ row_ptr,
                                                const int* __restrict__ col_idx,
                                                const ushort_t* __restrict__ x,
                                                const float* __restrict__ cnorm,
                                                const float* __restrict__ rnorm,
                                                ushort_t* __restrict__ out, const int nrows) {
    ll gt = (ll)blockIdx.x * blockDim.x + threadIdx.x;
    int w = (int)(gt >> 6);
    int d = (int)(gt & 63);
    if (w >= nrows) return;
    int s = row_ptr[w], e = row_ptr[w + 1];
    float accA = 0.0f, accB = 0.0f;
    int j = s;
    for (; j + 8 <= e; j += 8) {
        int c0 = col_idx[j],     c1 = col_idx[j + 1], c2 = col_idx[j + 2], c3 = col_idx[j + 3];
        int c4 = col_idx[j + 4], c5 = col_idx[j + 5], c6 = col_idx[j + 6], c7 = col_idx[j + 7];
        float n0 = cnorm[c0], n1 = cnorm[c1], n2 = cnorm[c2], n3 = cnorm[c3];
        float n4 = cnorm[c4], n5 = cnorm[c5], n6 = cnorm[c6], n7 = cnorm[c7];
        float x0 = bf2f(x[(ll)c0 * 64 + d]), x1 = bf2f(x[(ll)c1 * 64 + d]);
        float x2 = bf2f(x[(ll)c2 * 64 + d]), x3 = bf2f(x[(ll)c3 * 64 + d]);
        float x4 = bf2f(x[(ll)c4 * 64 + d]), x5 = bf2f(x[(ll)c5 * 64 + d]);
        float x6 = bf2f(x[(ll)c6 * 64 + d]), x7 = bf2f(x[(ll)c7 * 64 + d]);
        accA += x0 * n0 + x2 * n2 + x4 * n4 + x6 * n6;
        accB += x1 * n1 + x3 * n3 + x5 * n5 + x7 * n7;
    }
    for (; j + 2 <= e; j += 2) {
        int c0 = col_idx[j], c1 = col_idx[j + 1];
        accA += bf2f(x[(ll)c0 * 64 + d]) * cnorm[c0];
        accB += bf2f(x[(ll)c1 * 64 + d]) * cnorm[c1];
    }
    if (j < e) {
        int c = col_idx[j];
        accA += bf2f(x[(ll)c * 64 + d]) * cnorm[c];
    }
    out[(ll)w * 64 + d] = f2bf((accA + accB) * rnorm[w]);
}

// ---------------- fast tanh ----------
__device__ __forceinline__ float fast_tanh(float x) {
    return 1.0f - 2.0f / (__expf(2.0f * x) + 1.0f);
}

// ---------------- MFMA semantic-attention scores ----------------
__global__ __launch_bounds__(256) void k_attn_mfma(const ushort_t* __restrict__ z1,
                                                   const ushort_t* __restrict__ z2,
                                                   const ushort_t* __restrict__ Wb,
                                                   const float* __restrict__ b1f,
                                                   const float* __restrict__ w2f,
                                                   const int n, float* __restrict__ wsum) {
    __shared__ float red0[4], red1[4];
    int tid = threadIdx.x;
    int lane = tid & 63;
    int wid = tid >> 6;
    int col = lane & 15;
    int quad = lane >> 4;

    bf16x8 wb[8][2];
#pragma unroll
    for (int ht = 0; ht < 8; ht++) {
        int h = ht * 16 + col;
#pragma unroll
        for (int ks = 0; ks < 2; ks++) {
            wb[ht][ks] = *(const bf16x8*)&Wb[h * 64 + ks * 32 + quad * 8];
        }
    }
    float b1v[8], w2v[8];
#pragma unroll
    for (int ht = 0; ht < 8; ht++) {
        b1v[ht] = b1f[ht * 16 + col];
        w2v[ht] = w2f[ht * 16 + col];
    }

    float w0 = 0.0f, w1 = 0.0f;
    int ntiles = (n + 15) >> 4;
    int gw = blockIdx.x * 4 + wid;
    int nw = gridDim.x * 4;
    const bf16x8 zero8 = {0, 0, 0, 0, 0, 0, 0, 0};

    for (int tile = gw; tile < ntiles; tile += nw) {
        int nodeA = tile * 16 + col;
        bool va = nodeA < n;
        bf16x8 a1[2], a2[2];
#pragma unroll
        for (int ks = 0; ks < 2; ks++) {
            const bf16x8* p1 = (const bf16x8*)&z1[(ll)nodeA * 64 + ks * 32 + quad * 8];
            const bf16x8* p2 = (const bf16x8*)&z2[(ll)nodeA * 64 + ks * 32 + quad * 8];
            a1[ks] = va ? p1[0] : zero8;
            a2[ks] = va ? p2[0] : zero8;
        }
#pragma unroll
        for (int ht = 0; ht < 8; ht++) {
            f32x4 c1 = {0.f, 0.f, 0.f, 0.f};
            f32x4 c2 = {0.f, 0.f, 0.f, 0.f};
            c1 = __builtin_amdgcn_mfma_f32_16x16x32_bf16(a1[0], wb[ht][0], c1, 0, 0, 0);
            c1 = __builtin_amdgcn_mfma_f32_16x16x32_bf16(a1[1], wb[ht][1], c1, 0, 0, 0);
            c2 = __builtin_amdgcn_mfma_f32_16x16x32_bf16(a2[0], wb[ht][0], c2, 0, 0, 0);
            c2 = __builtin_amdgcn_mfma_f32_16x16x32_bf16(a2[1], wb[ht][1], c2, 0, 0, 0);
#pragma unroll
            for (int r = 0; r < 4; r++) {
                int node_row = tile * 16 + quad * 4 + r;
                bool vr = node_row < n;
                float t1 = fast_tanh(c1[r] + b1v[ht]) * w2v[ht];
                float t2 = fast_tanh(c2[r] + b1v[ht]) * w2v[ht];
                w0 += vr ? t1 : 0.0f;
                w1 += vr ? t2 : 0.0f;
            }
        }
    }

    for (int off = 32; off > 0; off >>= 1) {
        w0 += __shfl_down(w0, off);
        w1 += __shfl_down(w1, off);
    }
    if (lane == 0) { red0[wid] = w0; red1[wid] = w1; }
    __syncthreads();
    if (tid == 0) {
        atomicAdd(&wsum[0], red0[0] + red0[1] + red0[2] + red0[3]);
        atomicAdd(&wsum[1], red1[0] + red1[1] + red1[2] + red1[3]);
    }
}

// ---------------- combine with inline beta softmax (bf16 in/out) ----------
__global__ void k_combine(const ushort_t* __restrict__ z1, const ushort_t* __restrict__ z2,
                          const float* __restrict__ wsum, const float inv_n,
                          ushort_t* __restrict__ h, const ll n64) {
    ll t = (ll)blockIdx.x * blockDim.x + threadIdx.x;
    if (t < n64) {
        float m0 = wsum[0] * inv_n, m1 = wsum[1] * inv_n;
        float mx = fmaxf(m0, m1);
        float e0 = __expf(m0 - mx), e1 = __expf(m1 - mx);
        float inv_s = 1.0f / (e0 + e1);
        h[t] = f2bf((e0 * bf2f(z1[t]) + e1 * bf2f(z2[t])) * inv_s);
    }
}

// ---------------- fused output gather ----------------
__device__ __forceinline__ void store_out(void* out, ll i, float v, int isbf16) {
    if (isbf16) ((ushort_t*)out)[i] = f2bf(v);
    else ((float*)out)[i] = v;
}

__global__ void k_out(const ushort_t* __restrict__ hu, const ushort_t* __restrict__ hi,
                      const ushort_t* __restrict__ ui, const int* __restrict__ user_idx,
                      const int* __restrict__ item_idx, const int* __restrict__ neg_idx,
                      void* __restrict__ out, const int B, const ll U,
                      const int* __restrict__ flag) {
    ll t = (ll)blockIdx.x * blockDim.x + threadIdx.x;
    int bf = *flag;
    int d = (int)(t & 63);
    ll b = t >> 6;
    if (b < B) {
        int u = user_idx[b];
        float v = 0.5f * bf2f(hu[(ll)u * 64 + d]) + 0.5f * bf2f(ui[(ll)u * 64 + d]);
        store_out(out, b * 64 + d, v, bf);
    } else if (b < 2 * (ll)B) {
        ll bb = b - B;
        int it = item_idx[bb];
        float v = 0.5f * bf2f(hi[(ll)it * 64 + d]) + 0.5f * bf2f(ui[(U + it) * 64 + d]);
        store_out(out, (ll)B * 64 + bb * 64 + d, v, bf);
    } else if (b < 3 * (ll)B) {
        ll bb = b - 2 * (ll)B;
        int it = item_idx[neg_idx[bb]];
        float v = 0.5f * bf2f(hi[(ll)it * 64 + d]) + 0.5f * bf2f(ui[(U + it) * 64 + d]);
        store_out(out, (ll)2 * B * 64 + bb * 64 + d, v, bf);
    }
}

extern "C" void kernel_launch(void* const* d_in, const int* in_sizes, int n_in,
                              void* d_out, int out_size, void* d_ws, size_t ws_size,
                              hipStream_t stream) {
    const int D = 64;
    const ll U = in_sizes[0] / D;
    const ll I = in_sizes[1] / D;
    const ll N = U + I;
    const ll E2  = in_sizes[8] / 2;
    const ll EU1 = in_sizes[9] / 2;
    const ll EU2 = in_sizes[10] / 2;
    const ll EI1 = in_sizes[11] / 2;
    const ll EI2 = in_sizes[12] / 2;
    const ll ET = E2 + EU1 + EU2 + EI1 + EI2;
    const ll RT = E2 + 2 * (EU1 + EU2 + EI1 + EI2);   // binning records
    const int B = in_sizes[13];
    const int M = (int)(N + 2 * U + 2 * I);           // CSR/in-deg index space
    const int M2 = (int)(N + 4 * U + 4 * I);          // + out-deg space
    const int K = (M2 + BIN_SIZE - 1) >> BIN_SHIFT;   // buckets
    const int KM = (M + BIN_SIZE - 1) >> BIN_SHIFT;   // buckets covering [0,M)
    if (K > KMAX) return;

    const void* user_feat = d_in[0];
    const void* item_feat = d_in[1];
    const int* uiR = (const int*)d_in[8];
    const int* uiC = uiR + E2;
    const int* u1s = (const int*)d_in[9];
    const int* u1d = u1s + EU1;
    const int* u2s = (const int*)d_in[10];
    const int* u2d = u2s + EU2;
    const int* i1s = (const int*)d_in[11];
    const int* i1d = i1s + EI1;
    const int* i2s = (const int*)d_in[12];
    const int* i2d = i2s + EI2;
    const int* user_idx = (const int*)d_in[13];
    const int* item_idx = (const int*)d_in[14];
    const int* neg_idx  = (const int*)d_in[15];

    // ---------------- workspace layout ----------------
    // Feature arrays first (contiguous) — binned int2[RT] overlays them during
    // CSR build (all features are written only after the build completes).
    ushort_t* q = (ushort_t*)d_ws;
    ushort_t* ui0 = q; q += N * 64;
    ushort_t* ui1 = q; q += N * 64;
    ushort_t* z1  = q; q += I * 64;
    ushort_t* z2  = q; q += I * 64;
    ushort_t* hu  = q; q += U * 64;
    ushort_t* hi  = q; q += I * 64;
    size_t feat_bytes = (size_t)(q - (ushort_t*)d_ws) * 2;
    if (feat_bytes < (size_t)RT * 8) return;   // binned overlay must fit
    int2* binned = (int2*)d_ws;

    float* p = (float*)(((uintptr_t)q + 15) & ~(uintptr_t)15);
    float* nrm = p;  p += M2;
    ushort_t* Wbu = (ushort_t*)p; p += 64 * 128 / 2;
    ushort_t* Wbi = (ushort_t*)p; p += 64 * 128 / 2;
    float* wb1u = p; p += 128;
    float* ww2u = p; p += 128;
    float* wb1i = p; p += 128;
    float* ww2i = p; p += 128;
    float* scratch = p; p += 16;

    int* ip = (int*)p;
    int* btot = ip;    ip += KMAX * 32;   // line-padded bucket totals
    int* bbase = ip;   ip += KMAX;
    int* bcursor = ip; ip += KMAX * 32;   // line-padded claim cursors
    int* counts = ip;  ip += M2;
    int* S = ip;       ip += M + 1;
    int* ci_all = ip;  ip += ET;
    int* bsum = ip;    ip += 256;
    int* flag = ip;    ip += 4;
    size_t needed = (size_t)((char*)ip - (char*)d_ws);
    if (ws_size < needed) return;

    const int T = 256;
    const int nWG_A = cdiv_ll(RT, CHUNK);

    // ---------------- dtype detection + weight conversion ----------------
    k_detect<<<1, 256, 0, stream>>>((const unsigned int*)user_feat, (ll)in_sizes[0] / 2, flag);
    k_cvt_weights<<<cdiv_ll(2 * (64 * 128 + 256), T), T, 0, stream>>>(
        d_in[2], d_in[3], d_in[4], d_in[5], d_in[6], d_in[7],
        Wbu, wb1u, ww2u, Wbi, wb1i, ww2i, flag);

    // ---------------- CSR build via 2-level binning ----------------
    hipMemsetAsync(btot, 0, (size_t)KMAX * 32 * sizeof(int), stream);
    hipMemsetAsync(scratch, 0, 16 * sizeof(float), stream);
    kA_hist<<<nWG_A, T, 0, stream>>>(uiR, uiC, u1s, u1d, u2s, u2d, i1s, i1d, i2s, i2d,
                                     E2, EU1, EU2, EI1, EI2, (int)N, (int)U, (int)I, M,
                                     RT, K, btot);
    k_bscan<<<1, 512, 0, stream>>>(btot, bbase, bcursor, K);
    kA_scatter<<<nWG_A, T, 0, stream>>>(uiR, uiC, u1s, u1d, u2s, u2d, i1s, i1d, i2s, i2d,
                                        E2, EU1, EU2, EI1, EI2, (int)N, (int)U, (int)I, M,
                                        RT, K, bcursor, binned);
    kB1_count<<<K, T, 0, stream>>>(binned, bbase, btot, counts, M2);
    k_norm_all<<<cdiv_ll(M2, T), T, 0, stream>>>(counts, nrm, (int)N, M2);
    {
        int nb = (M + SCAN_CHUNK - 1) / SCAN_CHUNK;
        k_scanA<<<nb, SCAN_T, 0, stream>>>(counts, M, S, bsum);
        k_scanB<<<1, 256, 0, stream>>>(bsum, nb);
        k_scanC<<<cdiv_ll(M, T), T, 0, stream>>>(S, M, bsum, (int)ET);
    }
    kB2_fill<<<KM, T, 0, stream>>>(binned, bbase, btot, S, M, ci_all);

    // ---------------- init features (after binned is consumed) ----------------
    k_init<<<cdiv_ll(N * 64, T), T, 0, stream>>>(user_feat, item_feat, ui0, hu, hi, U * 64, N * 64, flag);

    // CSR segment row_ptr views
    const int* rp_ui = S;
    const int* rp_u1 = S + N;
    const int* rp_u2 = S + N + U;
    const int* rp_i1 = S + N + 2 * U;
    const int* rp_i2 = S + N + 2 * U + I;
    // norm views
    const float* dinv = nrm;
    const float* n_u1r = nrm + N;          const float* n_u2r = nrm + N + U;
    const float* n_i1r = nrm + N + 2 * U;  const float* n_i2r = nrm + N + 2 * U + I;
    const float* n_u1s = nrm + M;          const float* n_u2s = nrm + M + U;
    const float* n_i1s = nrm + M + 2 * U;  const float* n_i2s = nrm + M + 2 * U + I;

    ushort_t* uiA = ui0;
    ushort_t* uiB = ui1;
    const int ATTN_BLOCKS = 512;

    for (int layer = 0; layer < 2; layer++) {
        float* wsU = scratch + (layer ? 8 : 0);
        float* wsI = scratch + (layer ? 12 : 4);

        // ---- gcn_spmm ----
        k_gather<<<cdiv_ll(N * 64, T), T, 0, stream>>>(rp_ui, ci_all, uiA, dinv, dinv, uiB, (int)N);
        { ushort_t* tmp = uiA; uiA = uiB; uiB = tmp; }

        // ---- HAN: users ----
        k_gather<<<cdiv_ll(U * 64, T), T, 0, stream>>>(rp_u1, ci_all, hu, n_u1s, n_u1r, z1, (int)U);
        k_gather<<<cdiv_ll(U * 64, T), T, 0, stream>>>(rp_u2, ci_all, hu, n_u2s, n_u2r, z2, (int)U);
        k_attn_mfma<<<ATTN_BLOCKS, T, 0, stream>>>(z1, z2, Wbu, wb1u, ww2u, (int)U, wsU);
        k_combine<<<cdiv_ll(U * 64, T), T, 0, stream>>>(z1, z2, wsU, 1.0f / (float)U, hu, U * 64);

        // ---- HAN: items ----
        k_gather<<<cdiv_ll(I * 64, T), T, 0, stream>>>(rp_i1, ci_all, hi, n_i1s, n_i1r, z1, (int)I);
        k_gather<<<cdiv_ll(I * 64, T), T, 0, stream>>>(rp_i2, ci_all, hi, n_i2s, n_i2r, z2, (int)I);
        k_attn_mfma<<<ATTN_BLOCKS, T, 0, stream>>>(z1, z2, Wbi, wb1i, ww2i, (int)I, wsI);
        k_combine<<<cdiv_ll(I * 64, T), T, 0, stream>>>(z1, z2, wsI, 1.0f / (float)I, hi, I * 64);
    }

    // ---------------- final ----------------
    k_out<<<cdiv_ll((ll)3 * B * 64, T), T, 0, stream>>>(hu, hi, uiA, user_idx, item_idx, neg_idx,
                                                        d_out, B, U, flag);
}

// Round 11
// 976.924 us; speedup vs baseline: 3.6691x; 1.0001x over previous
//
#include <hip/hip_runtime.h>
#include <hip/hip_bf16.h>
#include <stdint.h>

typedef long long ll;
typedef unsigned short ushort_t;
typedef __attribute__((ext_vector_type(8))) short bf16x8;
typedef __attribute__((ext_vector_type(4))) float f32x4;

static inline int cdiv_ll(ll a, int b) { return (int)((a + (ll)b - 1) / (ll)b); }

#define BIN_SHIFT 9
#define BIN_SIZE 512
#define KMAX 2048         // max buckets (M2 <= 1M)
#define CHUNK 16384       // records per workgroup in binning passes

// ---------------- dtype detection (bf16 vs fp32 inputs) ----------------
__global__ void k_detect(const unsigned int* __restrict__ dw, const ll n_dw, int* __restrict__ flag) {
    __shared__ int sc[256];
    int tid = threadIdx.x;
    int cnt = 0;
    for (int s = 0; s < 32; s++) {
        ll idx = (ll)(s * 256 + tid);
        ll i = (idx * n_dw) / 8192;
        unsigned v = dw[i];
        unsigned lo = v & 0xFFFFu;
        unsigned ex = (lo >> 7) & 0xFFu;
        bool pl = (lo == 0u) || (lo == 0x8000u) || (ex >= 0x60u && ex <= 0x8Fu);
        cnt += pl ? 1 : 0;
    }
    sc[tid] = cnt;
    __syncthreads();
    for (int o = 128; o > 0; o >>= 1) { if (tid < o) sc[tid] += sc[tid + o]; __syncthreads(); }
    if (tid == 0) *flag = (sc[0] * 2 > 8192) ? 1 : 0;
}

__device__ __forceinline__ float load_in(const void* p, ll i, int isbf16) {
    if (isbf16) return __bfloat162float(((const __hip_bfloat16*)p)[i]);
    return ((const float*)p)[i];
}

__device__ __forceinline__ float bf2f(ushort_t u) {
    return __uint_as_float(((unsigned)u) << 16);
}
__device__ __forceinline__ ushort_t f2bf(float f) {
    unsigned u = __float_as_uint(f);
    unsigned r = (u + 0x7FFFu + ((u >> 16) & 1u)) >> 16;
    return (ushort_t)r;
}

// ---------------- fused weight conversion ----------------
__global__ void k_cvt_weights(const void* __restrict__ W1u, const void* __restrict__ b1u,
                              const void* __restrict__ w2u, const void* __restrict__ W1i,
                              const void* __restrict__ b1i, const void* __restrict__ w2i,
                              ushort_t* __restrict__ Wbu, float* __restrict__ fb1u,
                              float* __restrict__ fw2u, ushort_t* __restrict__ Wbi,
                              float* __restrict__ fb1i, float* __restrict__ fw2i,
                              const int* __restrict__ flag) {
    int i = blockIdx.x * blockDim.x + threadIdx.x;
    int bf = *flag;
    const int WSZ = 64 * 128;
    if (i < WSZ) {
        int d = i >> 7, h = i & 127;
        Wbu[h * 64 + d] = f2bf(load_in(W1u, i, bf));
    } else if (i < WSZ + 128) {
        fb1u[i - WSZ] = load_in(b1u, i - WSZ, bf);
    } else if (i < WSZ + 256) {
        fw2u[i - WSZ - 128] = load_in(w2u, i - WSZ - 128, bf);
    } else if (i < 2 * WSZ + 256) {
        int j = i - WSZ - 256;
        int d = j >> 7, h = j & 127;
        Wbi[h * 64 + d] = f2bf(load_in(W1i, j, bf));
    } else if (i < 2 * WSZ + 384) {
        fb1i[i - 2 * WSZ - 256] = load_in(b1i, i - 2 * WSZ - 256, bf);
    } else if (i < 2 * WSZ + 512) {
        fw2i[i - 2 * WSZ - 384] = load_in(w2i, i - 2 * WSZ - 384, bf);
    }
}

// ---------------- record decode ----------------
__device__ __forceinline__ void decode_rec(ll t,
    const int* __restrict__ uiR, const int* __restrict__ uiC,
    const int* __restrict__ u1s, const int* __restrict__ u1d,
    const int* __restrict__ u2s, const int* __restrict__ u2d,
    const int* __restrict__ i1s, const int* __restrict__ i1d,
    const int* __restrict__ i2s, const int* __restrict__ i2d,
    const ll E2, const ll EU1, const ll EU2, const ll EI1, const ll EI2,
    const int N, const int U, const int I, const int M,
    int& key, int& col) {
    if (t < E2) { key = uiR[t]; col = uiC[t]; return; }
    t -= E2;
    if (t < EU1) { key = N + u1d[t]; col = u1s[t]; return; }
    t -= EU1;
    if (t < EU1) { key = M + u1s[t]; col = 0; return; }
    t -= EU1;
    if (t < EU2) { key = N + U + u2d[t]; col = u2s[t]; return; }
    t -= EU2;
    if (t < EU2) { key = M + U + u2s[t]; col = 0; return; }
    t -= EU2;
    if (t < EI1) { key = N + 2 * U + i1d[t]; col = i1s[t]; return; }
    t -= EI1;
    if (t < EI1) { key = M + 2 * U + i1s[t]; col = 0; return; }
    t -= EI1;
    if (t < EI2) { key = N + 2 * U + I + i2d[t]; col = i2s[t]; return; }
    t -= EI2;
    key = M + 2 * U + I + i2s[t]; col = 0;
}

#define DECODE_ARGS uiR, uiC, u1s, u1d, u2s, u2d, i1s, i1d, i2s, i2d, \
                    E2, EU1, EU2, EI1, EI2, N, U, I, M

// ---------------- pass A1: per-WG LDS histogram -> global bucket totals ----
__global__ __launch_bounds__(256) void kA_hist(
    const int* __restrict__ uiR, const int* __restrict__ uiC,
    const int* __restrict__ u1s, const int* __restrict__ u1d,
    const int* __restrict__ u2s, const int* __restrict__ u2d,
    const int* __restrict__ i1s, const int* __restrict__ i1d,
    const int* __restrict__ i2s, const int* __restrict__ i2d,
    const ll E2, const ll EU1, const ll EU2, const ll EI1, const ll EI2,
    const int N, const int U, const int I, const int M,
    const ll RT, const int K, int* __restrict__ btot /* K*32 line-padded */) {
    __shared__ int hist[KMAX];
    for (int i = threadIdx.x; i < K; i += 256) hist[i] = 0;
    __syncthreads();
    ll base = (ll)blockIdx.x * CHUNK;
    for (int i = 0; i < CHUNK / 256; i++) {
        ll t = base + i * 256 + threadIdx.x;
        if (t < RT) {
            int key, col;
            decode_rec(t, DECODE_ARGS, key, col);
            atomicAdd(&hist[key >> BIN_SHIFT], 1);
        }
    }
    __syncthreads();
    for (int k = threadIdx.x; k < K; k += 256)
        if (hist[k]) atomicAdd(&btot[k * 32], hist[k]);
}

// ---------------- bucket scan: totals -> bases, init cursors ----------------
__global__ __launch_bounds__(1024) void k_bscan(const int* __restrict__ btot,
                                                int* __restrict__ bbase,
                                                int* __restrict__ bcursor, const int K) {
    __shared__ int sh[1024];
    __shared__ int carry;
    int t = threadIdx.x;
    if (t == 0) carry = 0;
    __syncthreads();
    for (int base = 0; base < K; base += 1024) {
        int idx = base + t;
        int v = (idx < K) ? btot[idx * 32] : 0;
        sh[t] = v;
        __syncthreads();
        for (int off = 1; off < 1024; off <<= 1) {
            int x = (t >= off) ? sh[t - off] : 0;
            __syncthreads();
            sh[t] += x;
            __syncthreads();
        }
        if (idx < K) {
            int ex = carry + sh[t] - v;
            bbase[idx] = ex;
            bcursor[idx * 32] = ex;
        }
        __syncthreads();
        if (t == 0) carry += sh[1023];
        __syncthreads();
    }
}

// ---------------- pass A2: scatter records into bucket-contiguous binned ----
__global__ __launch_bounds__(256) void kA_scatter(
    const int* __restrict__ uiR, const int* __restrict__ uiC,
    const int* __restrict__ u1s, const int* __restrict__ u1d,
    const int* __restrict__ u2s, const int* __restrict__ u2d,
    const int* __restrict__ i1s, const int* __restrict__ i1d,
    const int* __restrict__ i2s, const int* __restrict__ i2d,
    const ll E2, const ll EU1, const ll EU2, const ll EI1, const ll EI2,
    const int N, const int U, const int I, const int M,
    const ll RT, const int K, int* __restrict__ bcursor, int2* __restrict__ binned) {
    __shared__ int hist[KMAX];
    __shared__ int lcur[KMAX];
    for (int i = threadIdx.x; i < K; i += 256) hist[i] = 0;
    __syncthreads();
    ll base = (ll)blockIdx.x * CHUNK;
    for (int i = 0; i < CHUNK / 256; i++) {
        ll t = base + i * 256 + threadIdx.x;
        if (t < RT) {
            int key, col;
            decode_rec(t, DECODE_ARGS, key, col);
            atomicAdd(&hist[key >> BIN_SHIFT], 1);
        }
    }
    __syncthreads();
    for (int k = threadIdx.x; k < K; k += 256) {
        int h = hist[k];
        lcur[k] = h ? atomicAdd(&bcursor[k * 32], h) : 0;
    }
    __syncthreads();
    for (int i = 0; i < CHUNK / 256; i++) {
        ll t = base + i * 256 + threadIdx.x;
        if (t < RT) {
            int key, col;
            decode_rec(t, DECODE_ARGS, key, col);
            int pos = atomicAdd(&lcur[key >> BIN_SHIFT], 1);
            binned[pos] = make_int2(key, col);
        }
    }
}

// ---------------- pass B1: per-bucket LDS count -> counts array ----------
__global__ __launch_bounds__(256) void kB1_count(const int2* __restrict__ binned,
                                                 const int* __restrict__ bbase,
                                                 const int* __restrict__ btot,
                                                 int* __restrict__ counts, const int M2) {
    __shared__ int cnt[BIN_SIZE];
    int b = blockIdx.x;
    int lo = b << BIN_SHIFT;
    int hi = min(lo + BIN_SIZE, M2);
    for (int i = threadIdx.x; i < BIN_SIZE; i += 256) cnt[i] = 0;
    __syncthreads();
    int s = bbase[b], n = btot[b * 32];
    for (int j = s + threadIdx.x; j < s + n; j += 256) {
        atomicAdd(&cnt[binned[j].x - lo], 1);
    }
    __syncthreads();
    for (int i = threadIdx.x; i < hi - lo; i += 256) counts[lo + i] = cnt[i];
}

// ---------------- fused norms ----------------
__global__ void k_norm_all(const int* __restrict__ counts, float* __restrict__ nrm,
                           const int N, const int total) {
    int i = blockIdx.x * blockDim.x + threadIdx.x;
    if (i < total) {
        int c = counts[i];
        if (i < N) nrm[i] = (c > 0) ? (1.0f / sqrtf((float)c)) : 0.0f;
        else nrm[i] = 1.0f / sqrtf(fmaxf((float)c, 1.0f));
    }
}

// ---------------- hierarchical exclusive scan ----------
#define SCAN_T 256
#define SCAN_ELEMS 8
#define SCAN_CHUNK (SCAN_T * SCAN_ELEMS)   // 2048

__global__ __launch_bounds__(256) void k_scanA(const int* __restrict__ in, const int n,
                                               int* __restrict__ out, int* __restrict__ bsum) {
    __shared__ int sh[SCAN_T];
    int t = threadIdx.x;
    ll base = (ll)blockIdx.x * SCAN_CHUNK + (ll)t * SCAN_ELEMS;
    int v[SCAN_ELEMS];
    int tot = 0;
#pragma unroll
    for (int k = 0; k < SCAN_ELEMS; k++) {
        ll i = base + k;
        v[k] = (i < n) ? in[i] : 0;
        tot += v[k];
    }
    sh[t] = tot;
    __syncthreads();
    for (int off = 1; off < SCAN_T; off <<= 1) {
        int x = (t >= off) ? sh[t - off] : 0;
        __syncthreads();
        sh[t] += x;
        __syncthreads();
    }
    int run = sh[t] - tot;
#pragma unroll
    for (int k = 0; k < SCAN_ELEMS; k++) {
        ll i = base + k;
        if (i < n) out[i] = run;
        run += v[k];
    }
    if (t == SCAN_T - 1) bsum[blockIdx.x] = sh[SCAN_T - 1];
}

__global__ __launch_bounds__(256) void k_scanB(int* __restrict__ bsum, const int nb) {
    __shared__ int sh[256];
    int t = threadIdx.x;
    int running = 0;
    for (int base = 0; base < nb; base += 256) {
        int idx = base + t;
        int v = (idx < nb) ? bsum[idx] : 0;
        sh[t] = v;
        __syncthreads();
        for (int off = 1; off < 256; off <<= 1) {
            int x = (t >= off) ? sh[t - off] : 0;
            __syncthreads();
            sh[t] += x;
            __syncthreads();
        }
        if (idx < nb) bsum[idx] = running + sh[t] - v;
        int tot = sh[255];
        __syncthreads();
        running += tot;
    }
}

__global__ void k_scanC(int* __restrict__ S, const int n, const int* __restrict__ bsum, const int ET) {
    ll i = (ll)blockIdx.x * blockDim.x + threadIdx.x;
    if (i < n) S[i] += bsum[i / SCAN_CHUNK];
    if (i == 0) S[n] = ET;
}

// ---------------- pass B2: per-bucket CSR fill via LDS cursors ----------
__global__ __launch_bounds__(256) void kB2_fill(const int2* __restrict__ binned,
                                                const int* __restrict__ bbase,
                                                const int* __restrict__ btot,
                                                const int* __restrict__ S, const int M,
                                                int* __restrict__ ci_all) {
    __shared__ int scur[BIN_SIZE];
    int b = blockIdx.x;
    int lo = b << BIN_SHIFT;
    int hi = min(lo + BIN_SIZE, M);
    for (int i = threadIdx.x; i < hi - lo; i += 256) scur[i] = S[lo + i];
    __syncthreads();
    int s = bbase[b], n = btot[b * 32];
    for (int j = s + threadIdx.x; j < s + n; j += 256) {
        int2 rec = binned[j];
        if (rec.x < M) {
            int pos = atomicAdd(&scur[rec.x - lo], 1);
            ci_all[pos] = rec.y;
        }
    }
}

// ---------------- init features (bf16 storage) ----------------
__global__ void k_init(const void* __restrict__ uf, const void* __restrict__ itf,
                       ushort_t* __restrict__ ui, ushort_t* __restrict__ hu,
                       ushort_t* __restrict__ hi,
                       const ll nu64, const ll ntot64, const int* __restrict__ flag) {
    ll t = (ll)blockIdx.x * blockDim.x + threadIdx.x;
    int bf = *flag;
    if (t < nu64) {
        ushort_t v = bf ? ((const ushort_t*)uf)[t] : f2bf(((const float*)uf)[t]);
        ui[t] = v; hu[t] = v;
    } else if (t < ntot64) {
        ll j = t - nu64;
        ushort_t v = bf ? ((const ushort_t*)itf)[j] : f2bf(((const float*)itf)[j]);
        ui[t] = v; hi[j] = v;
    }
}

// ---------------- gather SpMM (bf16 features, fp32 accumulate) ----------
__global__ __launch_bounds__(256) void k_gather(const int* __restrict__ row_ptr,
                                                const int* __restrict__ col_idx,
                                                const ushort_t* __restrict__ x,
                                                const float* __restrict__ cnorm,
                                                const float* __restrict__ rnorm,
                                                ushort_t* __restrict__ out, const int nrows) {
    ll gt = (ll)blockIdx.x * blockDim.x + threadIdx.x;
    int w = (int)(gt >> 6);
    int d = (int)(gt & 63);
    if (w >= nrows) return;
    int s = row_ptr[w], e = row_ptr[w + 1];
    float accA = 0.0f, accB = 0.0f;
    int j = s;
    for (; j + 8 <= e; j += 8) {
        int c0 = col_idx[j],     c1 = col_idx[j + 1], c2 = col_idx[j + 2], c3 = col_idx[j + 3];
        int c4 = col_idx[j + 4], c5 = col_idx[j + 5], c6 = col_idx[j + 6], c7 = col_idx[j + 7];
        float n0 = cnorm[c0], n1 = cnorm[c1], n2 = cnorm[c2], n3 = cnorm[c3];
        float n4 = cnorm[c4], n5 = cnorm[c5], n6 = cnorm[c6], n7 = cnorm[c7];
        float x0 = bf2f(x[(ll)c0 * 64 + d]), x1 = bf2f(x[(ll)c1 * 64 + d]);
        float x2 = bf2f(x[(ll)c2 * 64 + d]), x3 = bf2f(x[(ll)c3 * 64 + d]);
        float x4 = bf2f(x[(ll)c4 * 64 + d]), x5 = bf2f(x[(ll)c5 * 64 + d]);
        float x6 = bf2f(x[(ll)c6 * 64 + d]), x7 = bf2f(x[(ll)c7 * 64 + d]);
        accA += x0 * n0 + x2 * n2 + x4 * n4 + x6 * n6;
        accB += x1 * n1 + x3 * n3 + x5 * n5 + x7 * n7;
    }
    for (; j + 2 <= e; j += 2) {
        int c0 = col_idx[j], c1 = col_idx[j + 1];
        accA += bf2f(x[(ll)c0 * 64 + d]) * cnorm[c0];
        accB += bf2f(x[(ll)c1 * 64 + d]) * cnorm[c1];
    }
    if (j < e) {
        int c = col_idx[j];
        accA += bf2f(x[(ll)c * 64 + d]) * cnorm[c];
    }
    out[(ll)w * 64 + d] = f2bf((accA + accB) * rnorm[w]);
}

// ---------------- fast tanh ----------
__device__ __forceinline__ float fast_tanh(float x) {
    return 1.0f - 2.0f / (__expf(2.0f * x) + 1.0f);
}

// ---------------- MFMA semantic-attention scores ----------------
__global__ __launch_bounds__(256) void k_attn_mfma(const ushort_t* __restrict__ z1,
                                                   const ushort_t* __restrict__ z2,
                                                   const ushort_t* __restrict__ Wb,
                                                   const float* __restrict__ b1f,
                                                   const float* __restrict__ w2f,
                                                   const int n, float* __restrict__ wsum) {
    __shared__ float red0[4], red1[4];
    int tid = threadIdx.x;
    int lane = tid & 63;
    int wid = tid >> 6;
    int col = lane & 15;
    int quad = lane >> 4;

    bf16x8 wb[8][2];
#pragma unroll
    for (int ht = 0; ht < 8; ht++) {
        int h = ht * 16 + col;
#pragma unroll
        for (int ks = 0; ks < 2; ks++) {
            wb[ht][ks] = *(const bf16x8*)&Wb[h * 64 + ks * 32 + quad * 8];
        }
    }
    float b1v[8], w2v[8];
#pragma unroll
    for (int ht = 0; ht < 8; ht++) {
        b1v[ht] = b1f[ht * 16 + col];
        w2v[ht] = w2f[ht * 16 + col];
    }

    float w0 = 0.0f, w1 = 0.0f;
    int ntiles = (n + 15) >> 4;
    int gw = blockIdx.x * 4 + wid;
    int nw = gridDim.x * 4;
    const bf16x8 zero8 = {0, 0, 0, 0, 0, 0, 0, 0};

    for (int tile = gw; tile < ntiles; tile += nw) {
        int nodeA = tile * 16 + col;
        bool va = nodeA < n;
        bf16x8 a1[2], a2[2];
#pragma unroll
        for (int ks = 0; ks < 2; ks++) {
            const bf16x8* p1 = (const bf16x8*)&z1[(ll)nodeA * 64 + ks * 32 + quad * 8];
            const bf16x8* p2 = (const bf16x8*)&z2[(ll)nodeA * 64 + ks * 32 + quad * 8];
            a1[ks] = va ? p1[0] : zero8;
            a2[ks] = va ? p2[0] : zero8;
        }
#pragma unroll
        for (int ht = 0; ht < 8; ht++) {
            f32x4 c1 = {0.f, 0.f, 0.f, 0.f};
            f32x4 c2 = {0.f, 0.f, 0.f, 0.f};
            c1 = __builtin_amdgcn_mfma_f32_16x16x32_bf16(a1[0], wb[ht][0], c1, 0, 0, 0);
            c1 = __builtin_amdgcn_mfma_f32_16x16x32_bf16(a1[1], wb[ht][1], c1, 0, 0, 0);
            c2 = __builtin_amdgcn_mfma_f32_16x16x32_bf16(a2[0], wb[ht][0], c2, 0, 0, 0);
            c2 = __builtin_amdgcn_mfma_f32_16x16x32_bf16(a2[1], wb[ht][1], c2, 0, 0, 0);
#pragma unroll
            for (int r = 0; r < 4; r++) {
                int node_row = tile * 16 + quad * 4 + r;
                bool vr = node_row < n;
                float t1 = fast_tanh(c1[r] + b1v[ht]) * w2v[ht];
                float t2 = fast_tanh(c2[r] + b1v[ht]) * w2v[ht];
                w0 += vr ? t1 : 0.0f;
                w1 += vr ? t2 : 0.0f;
            }
        }
    }

    for (int off = 32; off > 0; off >>= 1) {
        w0 += __shfl_down(w0, off);
        w1 += __shfl_down(w1, off);
    }
    if (lane == 0) { red0[wid] = w0; red1[wid] = w1; }
    __syncthreads();
    if (tid == 0) {
        atomicAdd(&wsum[0], red0[0] + red0[1] + red0[2] + red0[3]);
        atomicAdd(&wsum[1], red1[0] + red1[1] + red1[2] + red1[3]);
    }
}

// ---------------- combine with inline beta softmax (bf16 in/out) ----------
__global__ void k_combine(const ushort_t* __restrict__ z1, const ushort_t* __restrict__ z2,
                          const float* __restrict__ wsum, const float inv_n,
                          ushort_t* __restrict__ h, const ll n64) {
    ll t = (ll)blockIdx.x * blockDim.x + threadIdx.x;
    if (t < n64) {
        float m0 = wsum[0] * inv_n, m1 = wsum[1] * inv_n;
        float mx = fmaxf(m0, m1);
        float e0 = __expf(m0 - mx), e1 = __expf(m1 - mx);
        float inv_s = 1.0f / (e0 + e1);
        h[t] = f2bf((e0 * bf2f(z1[t]) + e1 * bf2f(z2[t])) * inv_s);
    }
}

// ---------------- fused output gather ----------------
__device__ __forceinline__ void store_out(void* out, ll i, float v, int isbf16) {
    if (isbf16) ((ushort_t*)out)[i] = f2bf(v);
    else ((float*)out)[i] = v;
}

__global__ void k_out(const ushort_t* __restrict__ hu, const ushort_t* __restrict__ hi,
                      const ushort_t* __restrict__ ui, const int* __restrict__ user_idx,
                      const int* __restrict__ item_idx, const int* __restrict__ neg_idx,
                      void* __restrict__ out, const int B, const ll U,
                      const int* __restrict__ flag) {
    ll t = (ll)blockIdx.x * blockDim.x + threadIdx.x;
    int bf = *flag;
    int d = (int)(t & 63);
    ll b = t >> 6;
    if (b < B) {
        int u = user_idx[b];
        float v = 0.5f * bf2f(hu[(ll)u * 64 + d]) + 0.5f * bf2f(ui[(ll)u * 64 + d]);
        store_out(out, b * 64 + d, v, bf);
    } else if (b < 2 * (ll)B) {
        ll bb = b - B;
        int it = item_idx[bb];
        float v = 0.5f * bf2f(hi[(ll)it * 64 + d]) + 0.5f * bf2f(ui[(U + it) * 64 + d]);
        store_out(out, (ll)B * 64 + bb * 64 + d, v, bf);
    } else if (b < 3 * (ll)B) {
        ll bb = b - 2 * (ll)B;
        int it = item_idx[neg_idx[bb]];
        float v = 0.5f * bf2f(hi[(ll)it * 64 + d]) + 0.5f * bf2f(ui[(U + it) * 64 + d]);
        store_out(out, (ll)2 * B * 64 + bb * 64 + d, v, bf);
    }
}

extern "C" void kernel_launch(void* const* d_in, const int* in_sizes, int n_in,
                              void* d_out, int out_size, void* d_ws, size_t ws_size,
                              hipStream_t stream) {
    const int D = 64;
    const ll U = in_sizes[0] / D;
    const ll I = in_sizes[1] / D;
    const ll N = U + I;
    const ll E2  = in_sizes[8] / 2;
    const ll EU1 = in_sizes[9] / 2;
    const ll EU2 = in_sizes[10] / 2;
    const ll EI1 = in_sizes[11] / 2;
    const ll EI2 = in_sizes[12] / 2;
    const ll ET = E2 + EU1 + EU2 + EI1 + EI2;
    const ll RT = E2 + 2 * (EU1 + EU2 + EI1 + EI2);   // binning records
    const int B = in_sizes[13];
    const int M = (int)(N + 2 * U + 2 * I);           // CSR/in-deg index space
    const int M2 = (int)(N + 4 * U + 4 * I);          // + out-deg space
    const int K = (M2 + BIN_SIZE - 1) >> BIN_SHIFT;   // buckets
    const int KM = (M + BIN_SIZE - 1) >> BIN_SHIFT;   // buckets covering [0,M)
    if (K > KMAX) return;

    const void* user_feat = d_in[0];
    const void* item_feat = d_in[1];
    const int* uiR = (const int*)d_in[8];
    const int* uiC = uiR + E2;
    const int* u1s = (const int*)d_in[9];
    const int* u1d = u1s + EU1;
    const int* u2s = (const int*)d_in[10];
    const int* u2d = u2s + EU2;
    const int* i1s = (const int*)d_in[11];
    const int* i1d = i1s + EI1;
    const int* i2s = (const int*)d_in[12];
    const int* i2d = i2s + EI2;
    const int* user_idx = (const int*)d_in[13];
    const int* item_idx = (const int*)d_in[14];
    const int* neg_idx  = (const int*)d_in[15];

    // ---------------- workspace layout ----------------
    ushort_t* q = (ushort_t*)d_ws;
    ushort_t* ui0 = q; q += N * 64;
    ushort_t* ui1 = q; q += N * 64;
    ushort_t* z1  = q; q += I * 64;
    ushort_t* z2  = q; q += I * 64;
    ushort_t* hu  = q; q += U * 64;
    ushort_t* hi  = q; q += I * 64;
    size_t feat_bytes = (size_t)(q - (ushort_t*)d_ws) * 2;
    if (feat_bytes < (size_t)RT * 8) return;   // binned overlay must fit
    int2* binned = (int2*)d_ws;

    float* p = (float*)(((uintptr_t)q + 15) & ~(uintptr_t)15);
    float* nrm = p;  p += M2;
    ushort_t* Wbu = (ushort_t*)p; p += 64 * 128 / 2;
    ushort_t* Wbi = (ushort_t*)p; p += 64 * 128 / 2;
    float* wb1u = p; p += 128;
    float* ww2u = p; p += 128;
    float* wb1i = p; p += 128;
    float* ww2i = p; p += 128;
    float* scratch = p; p += 16;

    int* ip = (int*)p;
    int* btot = ip;    ip += KMAX * 32;
    int* bbase = ip;   ip += KMAX;
    int* bcursor = ip; ip += KMAX * 32;
    int* counts = ip;  ip += M2;
    int* S = ip;       ip += M + 1;
    int* ci_all = ip;  ip += ET;
    int* bsum = ip;    ip += 256;
    int* flag = ip;    ip += 4;
    size_t needed = (size_t)((char*)ip - (char*)d_ws);
    if (ws_size < needed) return;

    const int T = 256;
    const int nWG_A = cdiv_ll(RT, CHUNK);

    // ---------------- dtype detection + weight conversion ----------------
    k_detect<<<1, 256, 0, stream>>>((const unsigned int*)user_feat, (ll)in_sizes[0] / 2, flag);
    k_cvt_weights<<<cdiv_ll(2 * (64 * 128 + 256), T), T, 0, stream>>>(
        d_in[2], d_in[3], d_in[4], d_in[5], d_in[6], d_in[7],
        Wbu, wb1u, ww2u, Wbi, wb1i, ww2i, flag);

    // ---------------- CSR build via 2-level binning ----------------
    hipMemsetAsync(btot, 0, (size_t)KMAX * 32 * sizeof(int), stream);
    hipMemsetAsync(scratch, 0, 16 * sizeof(float), stream);
    kA_hist<<<nWG_A, T, 0, stream>>>(uiR, uiC, u1s, u1d, u2s, u2d, i1s, i1d, i2s, i2d,
                                     E2, EU1, EU2, EI1, EI2, (int)N, (int)U, (int)I, M,
                                     RT, K, btot);
    k_bscan<<<1, 1024, 0, stream>>>(btot, bbase, bcursor, K);
    kA_scatter<<<nWG_A, T, 0, stream>>>(uiR, uiC, u1s, u1d, u2s, u2d, i1s, i1d, i2s, i2d,
                                        E2, EU1, EU2, EI1, EI2, (int)N, (int)U, (int)I, M,
                                        RT, K, bcursor, binned);
    kB1_count<<<K, T, 0, stream>>>(binned, bbase, btot, counts, M2);
    k_norm_all<<<cdiv_ll(M2, T), T, 0, stream>>>(counts, nrm, (int)N, M2);
    {
        int nb = (M + SCAN_CHUNK - 1) / SCAN_CHUNK;
        k_scanA<<<nb, SCAN_T, 0, stream>>>(counts, M, S, bsum);
        k_scanB<<<1, 256, 0, stream>>>(bsum, nb);
        k_scanC<<<cdiv_ll(M, T), T, 0, stream>>>(S, M, bsum, (int)ET);
    }
    kB2_fill<<<KM, T, 0, stream>>>(binned, bbase, btot, S, M, ci_all);

    // ---------------- init features (after binned is consumed) ----------------
    k_init<<<cdiv_ll(N * 64, T), T, 0, stream>>>(user_feat, item_feat, ui0, hu, hi, U * 64, N * 64, flag);

    // CSR segment row_ptr views
    const int* rp_ui = S;
    const int* rp_u1 = S + N;
    const int* rp_u2 = S + N + U;
    const int* rp_i1 = S + N + 2 * U;
    const int* rp_i2 = S + N + 2 * U + I;
    // norm views
    const float* dinv = nrm;
    const float* n_u1r = nrm + N;          const float* n_u2r = nrm + N + U;
    const float* n_i1r = nrm + N + 2 * U;  const float* n_i2r = nrm + N + 2 * U + I;
    const float* n_u1s = nrm + M;          const float* n_u2s = nrm + M + U;
    const float* n_i1s = nrm + M + 2 * U;  const float* n_i2s = nrm + M + 2 * U + I;

    ushort_t* uiA = ui0;
    ushort_t* uiB = ui1;
    const int ATTN_BLOCKS = 512;

    for (int layer = 0; layer < 2; layer++) {
        float* wsU = scratch + (layer ? 8 : 0);
        float* wsI = scratch + (layer ? 12 : 4);

        // ---- gcn_spmm ----
        k_gather<<<cdiv_ll(N * 64, T), T, 0, stream>>>(rp_ui, ci_all, uiA, dinv, dinv, uiB, (int)N);
        { ushort_t* tmp = uiA; uiA = uiB; uiB = tmp; }

        // ---- HAN: users ----
        k_gather<<<cdiv_ll(U * 64, T), T, 0, stream>>>(rp_u1, ci_all, hu, n_u1s, n_u1r, z1, (int)U);
        k_gather<<<cdiv_ll(U * 64, T), T, 0, stream>>>(rp_u2, ci_all, hu, n_u2s, n_u2r, z2, (int)U);
        k_attn_mfma<<<ATTN_BLOCKS, T, 0, stream>>>(z1, z2, Wbu, wb1u, ww2u, (int)U, wsU);
        k_combine<<<cdiv_ll(U * 64, T), T, 0, stream>>>(z1, z2, wsU, 1.0f / (float)U, hu, U * 64);

        // ---- HAN: items ----
        k_gather<<<cdiv_ll(I * 64, T), T, 0, stream>>>(rp_i1, ci_all, hi, n_i1s, n_i1r, z1, (int)I);
        k_gather<<<cdiv_ll(I * 64, T), T, 0, stream>>>(rp_i2, ci_all, hi, n_i2s, n_i2r, z2, (int)I);
        k_attn_mfma<<<ATTN_BLOCKS, T, 0, stream>>>(z1, z2, Wbi, wb1i, ww2i, (int)I, wsI);
        k_combine<<<cdiv_ll(I * 64, T), T, 0, stream>>>(z1, z2, wsI, 1.0f / (float)I, hi, I * 64);
    }

    // ---------------- final ----------------
    k_out<<<cdiv_ll((ll)3 * B * 64, T), T, 0, stream>>>(hu, hi, uiA, user_idx, item_idx, neg_idx,
                                                        d_out, B, U, flag);
}

// Round 12
// 904.880 us; speedup vs baseline: 3.9612x; 1.0796x over previous
//
#include <hip/hip_runtime.h>
#include <hip/hip_bf16.h>
#include <stdint.h>

typedef long long ll;
typedef unsigned short ushort_t;
typedef __attribute__((ext_vector_type(8))) short bf16x8;
typedef __attribute__((ext_vector_type(4))) float f32x4;

static inline int cdiv_ll(ll a, int b) { return (int)((a + (ll)b - 1) / (ll)b); }

#define BIN_SHIFT 9
#define BIN_SIZE 512
#define KMAX 1536         // max buckets (M2 <= 768K)
#define CHUNK 8192        // records per workgroup in binning passes
#define RPT (CHUNK / 256) // records per thread (32)

// ---------------- dtype detection (bf16 vs fp32 inputs) ----------------
__global__ void k_detect(const unsigned int* __restrict__ dw, const ll n_dw, int* __restrict__ flag) {
    __shared__ int sc[256];
    int tid = threadIdx.x;
    int cnt = 0;
    for (int s = 0; s < 32; s++) {
        ll idx = (ll)(s * 256 + tid);
        ll i = (idx * n_dw) / 8192;
        unsigned v = dw[i];
        unsigned lo = v & 0xFFFFu;
        unsigned ex = (lo >> 7) & 0xFFu;
        bool pl = (lo == 0u) || (lo == 0x8000u) || (ex >= 0x60u && ex <= 0x8Fu);
        cnt += pl ? 1 : 0;
    }
    sc[tid] = cnt;
    __syncthreads();
    for (int o = 128; o > 0; o >>= 1) { if (tid < o) sc[tid] += sc[tid + o]; __syncthreads(); }
    if (tid == 0) *flag = (sc[0] * 2 > 8192) ? 1 : 0;
}

__device__ __forceinline__ float load_in(const void* p, ll i, int isbf16) {
    if (isbf16) return __bfloat162float(((const __hip_bfloat16*)p)[i]);
    return ((const float*)p)[i];
}

__device__ __forceinline__ float bf2f(ushort_t u) {
    return __uint_as_float(((unsigned)u) << 16);
}
__device__ __forceinline__ ushort_t f2bf(float f) {
    unsigned u = __float_as_uint(f);
    unsigned r = (u + 0x7FFFu + ((u >> 16) & 1u)) >> 16;
    return (ushort_t)r;
}

// ---------------- fused weight conversion ----------------
__global__ void k_cvt_weights(const void* __restrict__ W1u, const void* __restrict__ b1u,
                              const void* __restrict__ w2u, const void* __restrict__ W1i,
                              const void* __restrict__ b1i, const void* __restrict__ w2i,
                              ushort_t* __restrict__ Wbu, float* __restrict__ fb1u,
                              float* __restrict__ fw2u, ushort_t* __restrict__ Wbi,
                              float* __restrict__ fb1i, float* __restrict__ fw2i,
                              const int* __restrict__ flag) {
    int i = blockIdx.x * blockDim.x + threadIdx.x;
    int bf = *flag;
    const int WSZ = 64 * 128;
    if (i < WSZ) {
        int d = i >> 7, h = i & 127;
        Wbu[h * 64 + d] = f2bf(load_in(W1u, i, bf));
    } else if (i < WSZ + 128) {
        fb1u[i - WSZ] = load_in(b1u, i - WSZ, bf);
    } else if (i < WSZ + 256) {
        fw2u[i - WSZ - 128] = load_in(w2u, i - WSZ - 128, bf);
    } else if (i < 2 * WSZ + 256) {
        int j = i - WSZ - 256;
        int d = j >> 7, h = j & 127;
        Wbi[h * 64 + d] = f2bf(load_in(W1i, j, bf));
    } else if (i < 2 * WSZ + 384) {
        fb1i[i - 2 * WSZ - 256] = load_in(b1i, i - 2 * WSZ - 256, bf);
    } else if (i < 2 * WSZ + 512) {
        fw2i[i - 2 * WSZ - 384] = load_in(w2i, i - 2 * WSZ - 384, bf);
    }
}

// ---------------- record decode ----------------
__device__ __forceinline__ void decode_rec(ll t,
    const int* __restrict__ uiR, const int* __restrict__ uiC,
    const int* __restrict__ u1s, const int* __restrict__ u1d,
    const int* __restrict__ u2s, const int* __restrict__ u2d,
    const int* __restrict__ i1s, const int* __restrict__ i1d,
    const int* __restrict__ i2s, const int* __restrict__ i2d,
    const ll E2, const ll EU1, const ll EU2, const ll EI1, const ll EI2,
    const int N, const int U, const int I, const int M,
    int& key, int& col) {
    if (t < E2) { key = uiR[t]; col = uiC[t]; return; }
    t -= E2;
    if (t < EU1) { key = N + u1d[t]; col = u1s[t]; return; }
    t -= EU1;
    if (t < EU1) { key = M + u1s[t]; col = 0; return; }
    t -= EU1;
    if (t < EU2) { key = N + U + u2d[t]; col = u2s[t]; return; }
    t -= EU2;
    if (t < EU2) { key = M + U + u2s[t]; col = 0; return; }
    t -= EU2;
    if (t < EI1) { key = N + 2 * U + i1d[t]; col = i1s[t]; return; }
    t -= EI1;
    if (t < EI1) { key = M + 2 * U + i1s[t]; col = 0; return; }
    t -= EI1;
    if (t < EI2) { key = N + 2 * U + I + i2d[t]; col = i2s[t]; return; }
    t -= EI2;
    key = M + 2 * U + I + i2s[t]; col = 0;
}

// key-only decode (histogram pass never needs col)
__device__ __forceinline__ int decode_key(ll t,
    const int* __restrict__ uiR,
    const int* __restrict__ u1s, const int* __restrict__ u1d,
    const int* __restrict__ u2s, const int* __restrict__ u2d,
    const int* __restrict__ i1s, const int* __restrict__ i1d,
    const int* __restrict__ i2s, const int* __restrict__ i2d,
    const ll E2, const ll EU1, const ll EU2, const ll EI1, const ll EI2,
    const int N, const int U, const int I, const int M) {
    if (t < E2) return uiR[t];
    t -= E2;
    if (t < EU1) return N + u1d[t];
    t -= EU1;
    if (t < EU1) return M + u1s[t];
    t -= EU1;
    if (t < EU2) return N + U + u2d[t];
    t -= EU2;
    if (t < EU2) return M + U + u2s[t];
    t -= EU2;
    if (t < EI1) return N + 2 * U + i1d[t];
    t -= EI1;
    if (t < EI1) return M + 2 * U + i1s[t];
    t -= EI1;
    if (t < EI2) return N + 2 * U + I + i2d[t];
    t -= EI2;
    return M + 2 * U + I + i2s[t];
}

#define DECODE_ARGS uiR, uiC, u1s, u1d, u2s, u2d, i1s, i1d, i2s, i2d, \
                    E2, EU1, EU2, EI1, EI2, N, U, I, M

// ---------------- pass A1: per-WG LDS histogram -> global bucket totals ----
__global__ __launch_bounds__(256) void kA_hist(
    const int* __restrict__ uiR,
    const int* __restrict__ u1s, const int* __restrict__ u1d,
    const int* __restrict__ u2s, const int* __restrict__ u2d,
    const int* __restrict__ i1s, const int* __restrict__ i1d,
    const int* __restrict__ i2s, const int* __restrict__ i2d,
    const ll E2, const ll EU1, const ll EU2, const ll EI1, const ll EI2,
    const int N, const int U, const int I, const int M,
    const ll RT, const int K, int* __restrict__ btot /* K*32 line-padded */) {
    __shared__ int hist[KMAX];
    for (int i = threadIdx.x; i < K; i += 256) hist[i] = 0;
    __syncthreads();
    ll base = (ll)blockIdx.x * CHUNK;
#pragma unroll
    for (int i = 0; i < RPT; i++) {
        ll t = base + i * 256 + threadIdx.x;
        if (t < RT) {
            int key = decode_key(t, uiR, u1s, u1d, u2s, u2d, i1s, i1d, i2s, i2d,
                                 E2, EU1, EU2, EI1, EI2, N, U, I, M);
            atomicAdd(&hist[key >> BIN_SHIFT], 1);
        }
    }
    __syncthreads();
    for (int k = threadIdx.x; k < K; k += 256)
        if (hist[k]) atomicAdd(&btot[k * 32], hist[k]);
}

// ---------------- bucket scan: totals -> bases, init cursors ----------------
__global__ __launch_bounds__(1024) void k_bscan(const int* __restrict__ btot,
                                                int* __restrict__ bbase,
                                                int* __restrict__ bcursor, const int K) {
    __shared__ int sh[1024];
    __shared__ int carry;
    int t = threadIdx.x;
    if (t == 0) carry = 0;
    __syncthreads();
    for (int base = 0; base < K; base += 1024) {
        int idx = base + t;
        int v = (idx < K) ? btot[idx * 32] : 0;
        sh[t] = v;
        __syncthreads();
        for (int off = 1; off < 1024; off <<= 1) {
            int x = (t >= off) ? sh[t - off] : 0;
            __syncthreads();
            sh[t] += x;
            __syncthreads();
        }
        if (idx < K) {
            int ex = carry + sh[t] - v;
            bbase[idx] = ex;
            bcursor[idx * 32] = ex;
        }
        __syncthreads();
        if (t == 0) carry += sh[1023];
        __syncthreads();
    }
}

// ---------------- pass A2: scatter, single decode (register stash) ----------
__global__ __launch_bounds__(256) void kA_scatter(
    const int* __restrict__ uiR, const int* __restrict__ uiC,
    const int* __restrict__ u1s, const int* __restrict__ u1d,
    const int* __restrict__ u2s, const int* __restrict__ u2d,
    const int* __restrict__ i1s, const int* __restrict__ i1d,
    const int* __restrict__ i2s, const int* __restrict__ i2d,
    const ll E2, const ll EU1, const ll EU2, const ll EI1, const ll EI2,
    const int N, const int U, const int I, const int M,
    const ll RT, const int K, int* __restrict__ bcursor, int2* __restrict__ binned) {
    __shared__ int hist[KMAX];
    __shared__ int lcur[KMAX];
    int keyArr[RPT];
    int colArr[RPT];
    for (int i = threadIdx.x; i < K; i += 256) hist[i] = 0;
    __syncthreads();
    ll base = (ll)blockIdx.x * CHUNK;
#pragma unroll
    for (int i = 0; i < RPT; i++) {
        ll t = base + i * 256 + threadIdx.x;
        int key = -1, col = 0;
        if (t < RT) {
            decode_rec(t, DECODE_ARGS, key, col);
            atomicAdd(&hist[key >> BIN_SHIFT], 1);
        }
        keyArr[i] = key;
        colArr[i] = col;
    }
    __syncthreads();
    for (int k = threadIdx.x; k < K; k += 256) {
        int h = hist[k];
        lcur[k] = h ? atomicAdd(&bcursor[k * 32], h) : 0;
    }
    __syncthreads();
#pragma unroll
    for (int i = 0; i < RPT; i++) {
        int key = keyArr[i];
        if (key >= 0) {
            int pos = atomicAdd(&lcur[key >> BIN_SHIFT], 1);
            binned[pos] = make_int2(key, colArr[i]);
        }
    }
}

// ---------------- pass B1: per-bucket LDS count -> counts array ----------
__global__ __launch_bounds__(256) void kB1_count(const int2* __restrict__ binned,
                                                 const int* __restrict__ bbase,
                                                 const int* __restrict__ btot,
                                                 int* __restrict__ counts, const int M2) {
    __shared__ int cnt[BIN_SIZE];
    int b = blockIdx.x;
    int lo = b << BIN_SHIFT;
    int hi = min(lo + BIN_SIZE, M2);
    for (int i = threadIdx.x; i < BIN_SIZE; i += 256) cnt[i] = 0;
    __syncthreads();
    int s = bbase[b], n = btot[b * 32];
    for (int j = s + threadIdx.x; j < s + n; j += 256) {
        atomicAdd(&cnt[binned[j].x - lo], 1);
    }
    __syncthreads();
    for (int i = threadIdx.x; i < hi - lo; i += 256) counts[lo + i] = cnt[i];
}

// ---------------- fused norms ----------------
__global__ void k_norm_all(const int* __restrict__ counts, float* __restrict__ nrm,
                           const int N, const int total) {
    int i = blockIdx.x * blockDim.x + threadIdx.x;
    if (i < total) {
        int c = counts[i];
        if (i < N) nrm[i] = (c > 0) ? (1.0f / sqrtf((float)c)) : 0.0f;
        else nrm[i] = 1.0f / sqrtf(fmaxf((float)c, 1.0f));
    }
}

// ---------------- hierarchical exclusive scan ----------
#define SCAN_T 256
#define SCAN_ELEMS 8
#define SCAN_CHUNK (SCAN_T * SCAN_ELEMS)   // 2048

__global__ __launch_bounds__(256) void k_scanA(const int* __restrict__ in, const int n,
                                               int* __restrict__ out, int* __restrict__ bsum) {
    __shared__ int sh[SCAN_T];
    int t = threadIdx.x;
    ll base = (ll)blockIdx.x * SCAN_CHUNK + (ll)t * SCAN_ELEMS;
    int v[SCAN_ELEMS];
    int tot = 0;
#pragma unroll
    for (int k = 0; k < SCAN_ELEMS; k++) {
        ll i = base + k;
        v[k] = (i < n) ? in[i] : 0;
        tot += v[k];
    }
    sh[t] = tot;
    __syncthreads();
    for (int off = 1; off < SCAN_T; off <<= 1) {
        int x = (t >= off) ? sh[t - off] : 0;
        __syncthreads();
        sh[t] += x;
        __syncthreads();
    }
    int run = sh[t] - tot;
#pragma unroll
    for (int k = 0; k < SCAN_ELEMS; k++) {
        ll i = base + k;
        if (i < n) out[i] = run;
        run += v[k];
    }
    if (t == SCAN_T - 1) bsum[blockIdx.x] = sh[SCAN_T - 1];
}

__global__ __launch_bounds__(256) void k_scanB(int* __restrict__ bsum, const int nb) {
    __shared__ int sh[256];
    int t = threadIdx.x;
    int running = 0;
    for (int base = 0; base < nb; base += 256) {
        int idx = base + t;
        int v = (idx < nb) ? bsum[idx] : 0;
        sh[t] = v;
        __syncthreads();
        for (int off = 1; off < 256; off <<= 1) {
            int x = (t >= off) ? sh[t - off] : 0;
            __syncthreads();
            sh[t] += x;
            __syncthreads();
        }
        if (idx < nb) bsum[idx] = running + sh[t] - v;
        int tot = sh[255];
        __syncthreads();
        running += tot;
    }
}

__global__ void k_scanC(int* __restrict__ S, const int n, const int* __restrict__ bsum, const int ET) {
    ll i = (ll)blockIdx.x * blockDim.x + threadIdx.x;
    if (i < n) S[i] += bsum[i / SCAN_CHUNK];
    if (i == 0) S[n] = ET;
}

// ---------------- pass B2: per-bucket CSR fill via LDS cursors ----------
__global__ __launch_bounds__(256) void kB2_fill(const int2* __restrict__ binned,
                                                const int* __restrict__ bbase,
                                                const int* __restrict__ btot,
                                                const int* __restrict__ S, const int M,
                                                int* __restrict__ ci_all) {
    __shared__ int scur[BIN_SIZE];
    int b = blockIdx.x;
    int lo = b << BIN_SHIFT;
    int hi = min(lo + BIN_SIZE, M);
    for (int i = threadIdx.x; i < hi - lo; i += 256) scur[i] = S[lo + i];
    __syncthreads();
    int s = bbase[b], n = btot[b * 32];
    for (int j = s + threadIdx.x; j < s + n; j += 256) {
        int2 rec = binned[j];
        if (rec.x < M) {
            int pos = atomicAdd(&scur[rec.x - lo], 1);
            ci_all[pos] = rec.y;
        }
    }
}

// ---------------- init features (bf16 storage) ----------------
__global__ void k_init(const void* __restrict__ uf, const void* __restrict__ itf,
                       ushort_t* __restrict__ ui, ushort_t* __restrict__ hu,
                       ushort_t* __restrict__ hi,
                       const ll nu64, const ll ntot64, const int* __restrict__ flag) {
    ll t = (ll)blockIdx.x * blockDim.x + threadIdx.x;
    int bf = *flag;
    if (t < nu64) {
        ushort_t v = bf ? ((const ushort_t*)uf)[t] : f2bf(((const float*)uf)[t]);
        ui[t] = v; hu[t] = v;
    } else if (t < ntot64) {
        ll j = t - nu64;
        ushort_t v = bf ? ((const ushort_t*)itf)[j] : f2bf(((const float*)itf)[j]);
        ui[t] = v; hi[j] = v;
    }
}

// ---------------- gather SpMM (bf16 features, fp32 accumulate) ----------
__global__ __launch_bounds__(256) void k_gather(const int* __restrict__ row_ptr,
                                                const int* __restrict__ col_idx,
                                                const ushort_t* __restrict__ x,
                                                const float* __restrict__ cnorm,
                                                const float* __restrict__ rnorm,
                                                ushort_t* __restrict__ out, const int nrows) {
    ll gt = (ll)blockIdx.x * blockDim.x + threadIdx.x;
    int w = (int)(gt >> 6);
    int d = (int)(gt & 63);
    if (w >= nrows) return;
    int s = row_ptr[w], e = row_ptr[w + 1];
    float accA = 0.0f, accB = 0.0f;
    int j = s;
    for (; j + 8 <= e; j += 8) {
        int c0 = col_idx[j],     c1 = col_idx[j + 1], c2 = col_idx[j + 2], c3 = col_idx[j + 3];
        int c4 = col_idx[j + 4], c5 = col_idx[j + 5], c6 = col_idx[j + 6], c7 = col_idx[j + 7];
        float n0 = cnorm[c0], n1 = cnorm[c1], n2 = cnorm[c2], n3 = cnorm[c3];
        float n4 = cnorm[c4], n5 = cnorm[c5], n6 = cnorm[c6], n7 = cnorm[c7];
        float x0 = bf2f(x[(ll)c0 * 64 + d]), x1 = bf2f(x[(ll)c1 * 64 + d]);
        float x2 = bf2f(x[(ll)c2 * 64 + d]), x3 = bf2f(x[(ll)c3 * 64 + d]);
        float x4 = bf2f(x[(ll)c4 * 64 + d]), x5 = bf2f(x[(ll)c5 * 64 + d]);
        float x6 = bf2f(x[(ll)c6 * 64 + d]), x7 = bf2f(x[(ll)c7 * 64 + d]);
        accA += x0 * n0 + x2 * n2 + x4 * n4 + x6 * n6;
        accB += x1 * n1 + x3 * n3 + x5 * n5 + x7 * n7;
    }
    for (; j + 2 <= e; j += 2) {
        int c0 = col_idx[j], c1 = col_idx[j + 1];
        accA += bf2f(x[(ll)c0 * 64 + d]) * cnorm[c0];
        accB += bf2f(x[(ll)c1 * 64 + d]) * cnorm[c1];
    }
    if (j < e) {
        int c = col_idx[j];
        accA += bf2f(x[(ll)c * 64 + d]) * cnorm[c];
    }
    out[(ll)w * 64 + d] = f2bf((accA + accB) * rnorm[w]);
}

// ---------------- fast tanh ----------
__device__ __forceinline__ float fast_tanh(float x) {
    return 1.0f - 2.0f / (__expf(2.0f * x) + 1.0f);
}

// ---------------- MFMA semantic-attention scores ----------------
__global__ __launch_bounds__(256) void k_attn_mfma(const ushort_t* __restrict__ z1,
                                                   const ushort_t* __restrict__ z2,
                                                   const ushort_t* __restrict__ Wb,
                                                   const float* __restrict__ b1f,
                                                   const float* __restrict__ w2f,
                                                   const int n, float* __restrict__ wsum) {
    __shared__ float red0[4], red1[4];
    int tid = threadIdx.x;
    int lane = tid & 63;
    int wid = tid >> 6;
    int col = lane & 15;
    int quad = lane >> 4;

    bf16x8 wb[8][2];
#pragma unroll
    for (int ht = 0; ht < 8; ht++) {
        int h = ht * 16 + col;
#pragma unroll
        for (int ks = 0; ks < 2; ks++) {
            wb[ht][ks] = *(const bf16x8*)&Wb[h * 64 + ks * 32 + quad * 8];
        }
    }
    float b1v[8], w2v[8];
#pragma unroll
    for (int ht = 0; ht < 8; ht++) {
        b1v[ht] = b1f[ht * 16 + col];
        w2v[ht] = w2f[ht * 16 + col];
    }

    float w0 = 0.0f, w1 = 0.0f;
    int ntiles = (n + 15) >> 4;
    int gw = blockIdx.x * 4 + wid;
    int nw = gridDim.x * 4;
    const bf16x8 zero8 = {0, 0, 0, 0, 0, 0, 0, 0};

    for (int tile = gw; tile < ntiles; tile += nw) {
        int nodeA = tile * 16 + col;
        bool va = nodeA < n;
        bf16x8 a1[2], a2[2];
#pragma unroll
        for (int ks = 0; ks < 2; ks++) {
            const bf16x8* p1 = (const bf16x8*)&z1[(ll)nodeA * 64 + ks * 32 + quad * 8];
            const bf16x8* p2 = (const bf16x8*)&z2[(ll)nodeA * 64 + ks * 32 + quad * 8];
            a1[ks] = va ? p1[0] : zero8;
            a2[ks] = va ? p2[0] : zero8;
        }
#pragma unroll
        for (int ht = 0; ht < 8; ht++) {
            f32x4 c1 = {0.f, 0.f, 0.f, 0.f};
            f32x4 c2 = {0.f, 0.f, 0.f, 0.f};
            c1 = __builtin_amdgcn_mfma_f32_16x16x32_bf16(a1[0], wb[ht][0], c1, 0, 0, 0);
            c1 = __builtin_amdgcn_mfma_f32_16x16x32_bf16(a1[1], wb[ht][1], c1, 0, 0, 0);
            c2 = __builtin_amdgcn_mfma_f32_16x16x32_bf16(a2[0], wb[ht][0], c2, 0, 0, 0);
            c2 = __builtin_amdgcn_mfma_f32_16x16x32_bf16(a2[1], wb[ht][1], c2, 0, 0, 0);
#pragma unroll
            for (int r = 0; r < 4; r++) {
                int node_row = tile * 16 + quad * 4 + r;
                bool vr = node_row < n;
                float t1 = fast_tanh(c1[r] + b1v[ht]) * w2v[ht];
                float t2 = fast_tanh(c2[r] + b1v[ht]) * w2v[ht];
                w0 += vr ? t1 : 0.0f;
                w1 += vr ? t2 : 0.0f;
            }
        }
    }

    for (int off = 32; off > 0; off >>= 1) {
        w0 += __shfl_down(w0, off);
        w1 += __shfl_down(w1, off);
    }
    if (lane == 0) { red0[wid] = w0; red1[wid] = w1; }
    __syncthreads();
    if (tid == 0) {
        atomicAdd(&wsum[0], red0[0] + red0[1] + red0[2] + red0[3]);
        atomicAdd(&wsum[1], red1[0] + red1[1] + red1[2] + red1[3]);
    }
}

// ---------------- combine with inline beta softmax (bf16 in/out) ----------
__global__ void k_combine(const ushort_t* __restrict__ z1, const ushort_t* __restrict__ z2,
                          const float* __restrict__ wsum, const float inv_n,
                          ushort_t* __restrict__ h, const ll n64) {
    ll t = (ll)blockIdx.x * blockDim.x + threadIdx.x;
    if (t < n64) {
        float m0 = wsum[0] * inv_n, m1 = wsum[1] * inv_n;
        float mx = fmaxf(m0, m1);
        float e0 = __expf(m0 - mx), e1 = __expf(m1 - mx);
        float inv_s = 1.0f / (e0 + e1);
        h[t] = f2bf((e0 * bf2f(z1[t]) + e1 * bf2f(z2[t])) * inv_s);
    }
}

// ---------------- fused output gather ----------------
__device__ __forceinline__ void store_out(void* out, ll i, float v, int isbf16) {
    if (isbf16) ((ushort_t*)out)[i] = f2bf(v);
    else ((float*)out)[i] = v;
}

__global__ void k_out(const ushort_t* __restrict__ hu, const ushort_t* __restrict__ hi,
                      const ushort_t* __restrict__ ui, const int* __restrict__ user_idx,
                      const int* __restrict__ item_idx, const int* __restrict__ neg_idx,
                      void* __restrict__ out, const int B, const ll U,
                      const int* __restrict__ flag) {
    ll t = (ll)blockIdx.x * blockDim.x + threadIdx.x;
    int bf = *flag;
    int d = (int)(t & 63);
    ll b = t >> 6;
    if (b < B) {
        int u = user_idx[b];
        float v = 0.5f * bf2f(hu[(ll)u * 64 + d]) + 0.5f * bf2f(ui[(ll)u * 64 + d]);
        store_out(out, b * 64 + d, v, bf);
    } else if (b < 2 * (ll)B) {
        ll bb = b - B;
        int it = item_idx[bb];
        float v = 0.5f * bf2f(hi[(ll)it * 64 + d]) + 0.5f * bf2f(ui[(U + it) * 64 + d]);
        store_out(out, (ll)B * 64 + bb * 64 + d, v, bf);
    } else if (b < 3 * (ll)B) {
        ll bb = b - 2 * (ll)B;
        int it = item_idx[neg_idx[bb]];
        float v = 0.5f * bf2f(hi[(ll)it * 64 + d]) + 0.5f * bf2f(ui[(U + it) * 64 + d]);
        store_out(out, (ll)2 * B * 64 + bb * 64 + d, v, bf);
    }
}

extern "C" void kernel_launch(void* const* d_in, const int* in_sizes, int n_in,
                              void* d_out, int out_size, void* d_ws, size_t ws_size,
                              hipStream_t stream) {
    const int D = 64;
    const ll U = in_sizes[0] / D;
    const ll I = in_sizes[1] / D;
    const ll N = U + I;
    const ll E2  = in_sizes[8] / 2;
    const ll EU1 = in_sizes[9] / 2;
    const ll EU2 = in_sizes[10] / 2;
    const ll EI1 = in_sizes[11] / 2;
    const ll EI2 = in_sizes[12] / 2;
    const ll ET = E2 + EU1 + EU2 + EI1 + EI2;
    const ll RT = E2 + 2 * (EU1 + EU2 + EI1 + EI2);   // binning records
    const int B = in_sizes[13];
    const int M = (int)(N + 2 * U + 2 * I);           // CSR/in-deg index space
    const int M2 = (int)(N + 4 * U + 4 * I);          // + out-deg space
    const int K = (M2 + BIN_SIZE - 1) >> BIN_SHIFT;   // buckets
    const int KM = (M + BIN_SIZE - 1) >> BIN_SHIFT;   // buckets covering [0,M)
    if (K > KMAX) return;

    const void* user_feat = d_in[0];
    const void* item_feat = d_in[1];
    const int* uiR = (const int*)d_in[8];
    const int* uiC = uiR + E2;
    const int* u1s = (const int*)d_in[9];
    const int* u1d = u1s + EU1;
    const int* u2s = (const int*)d_in[10];
    const int* u2d = u2s + EU2;
    const int* i1s = (const int*)d_in[11];
    const int* i1d = i1s + EI1;
    const int* i2s = (const int*)d_in[12];
    const int* i2d = i2s + EI2;
    const int* user_idx = (const int*)d_in[13];
    const int* item_idx = (const int*)d_in[14];
    const int* neg_idx  = (const int*)d_in[15];

    // ---------------- workspace layout ----------------
    ushort_t* q = (ushort_t*)d_ws;
    ushort_t* ui0 = q; q += N * 64;
    ushort_t* ui1 = q; q += N * 64;
    ushort_t* z1  = q; q += I * 64;
    ushort_t* z2  = q; q += I * 64;
    ushort_t* hu  = q; q += U * 64;
    ushort_t* hi  = q; q += I * 64;
    size_t feat_bytes = (size_t)(q - (ushort_t*)d_ws) * 2;
    if (feat_bytes < (size_t)RT * 8) return;   // binned overlay must fit
    int2* binned = (int2*)d_ws;

    float* p = (float*)(((uintptr_t)q + 15) & ~(uintptr_t)15);
    float* nrm = p;  p += M2;
    ushort_t* Wbu = (ushort_t*)p; p += 64 * 128 / 2;
    ushort_t* Wbi = (ushort_t*)p; p += 64 * 128 / 2;
    float* wb1u = p; p += 128;
    float* ww2u = p; p += 128;
    float* wb1i = p; p += 128;
    float* ww2i = p; p += 128;
    float* scratch = p; p += 16;

    int* ip = (int*)p;
    int* btot = ip;    ip += KMAX * 32;
    int* bbase = ip;   ip += KMAX;
    int* bcursor = ip; ip += KMAX * 32;
    int* counts = ip;  ip += M2;
    int* S = ip;       ip += M + 1;
    int* ci_all = ip;  ip += ET;
    int* bsum = ip;    ip += 256;
    int* flag = ip;    ip += 4;
    size_t needed = (size_t)((char*)ip - (char*)d_ws);
    if (ws_size < needed) return;

    const int T = 256;
    const int nWG_A = cdiv_ll(RT, CHUNK);

    // ---------------- dtype detection + weight conversion ----------------
    k_detect<<<1, 256, 0, stream>>>((const unsigned int*)user_feat, (ll)in_sizes[0] / 2, flag);
    k_cvt_weights<<<cdiv_ll(2 * (64 * 128 + 256), T), T, 0, stream>>>(
        d_in[2], d_in[3], d_in[4], d_in[5], d_in[6], d_in[7],
        Wbu, wb1u, ww2u, Wbi, wb1i, ww2i, flag);

    // ---------------- CSR build via 2-level binning ----------------
    hipMemsetAsync(btot, 0, (size_t)KMAX * 32 * sizeof(int), stream);
    hipMemsetAsync(scratch, 0, 16 * sizeof(float), stream);
    kA_hist<<<nWG_A, T, 0, stream>>>(uiR, u1s, u1d, u2s, u2d, i1s, i1d, i2s, i2d,
                                     E2, EU1, EU2, EI1, EI2, (int)N, (int)U, (int)I, M,
                                     RT, K, btot);
    k_bscan<<<1, 1024, 0, stream>>>(btot, bbase, bcursor, K);
    kA_scatter<<<nWG_A, T, 0, stream>>>(uiR, uiC, u1s, u1d, u2s, u2d, i1s, i1d, i2s, i2d,
                                        E2, EU1, EU2, EI1, EI2, (int)N, (int)U, (int)I, M,
                                        RT, K, bcursor, binned);
    kB1_count<<<K, T, 0, stream>>>(binned, bbase, btot, counts, M2);
    k_norm_all<<<cdiv_ll(M2, T), T, 0, stream>>>(counts, nrm, (int)N, M2);
    {
        int nb = (M + SCAN_CHUNK - 1) / SCAN_CHUNK;
        k_scanA<<<nb, SCAN_T, 0, stream>>>(counts, M, S, bsum);
        k_scanB<<<1, 256, 0, stream>>>(bsum, nb);
        k_scanC<<<cdiv_ll(M, T), T, 0, stream>>>(S, M, bsum, (int)ET);
    }
    kB2_fill<<<KM, T, 0, stream>>>(binned, bbase, btot, S, M, ci_all);

    // ---------------- init features (after binned is consumed) ----------------
    k_init<<<cdiv_ll(N * 64, T), T, 0, stream>>>(user_feat, item_feat, ui0, hu, hi, U * 64, N * 64, flag);

    // CSR segment row_ptr views
    const int* rp_ui = S;
    const int* rp_u1 = S + N;
    const int* rp_u2 = S + N + U;
    const int* rp_i1 = S + N + 2 * U;
    const int* rp_i2 = S + N + 2 * U + I;
    // norm views
    const float* dinv = nrm;
    const float* n_u1r = nrm + N;          const float* n_u2r = nrm + N + U;
    const float* n_i1r = nrm + N + 2 * U;  const float* n_i2r = nrm + N + 2 * U + I;
    const float* n_u1s = nrm + M;          const float* n_u2s = nrm + M + U;
    const float* n_i1s = nrm + M + 2 * U;  const float* n_i2s = nrm + M + 2 * U + I;

    ushort_t* uiA = ui0;
    ushort_t* uiB = ui1;
    const int ATTN_BLOCKS = 512;

    for (int layer = 0; layer < 2; layer++) {
        float* wsU = scratch + (layer ? 8 : 0);
        float* wsI = scratch + (layer ? 12 : 4);

        // ---- gcn_spmm ----
        k_gather<<<cdiv_ll(N * 64, T), T, 0, stream>>>(rp_ui, ci_all, uiA, dinv, dinv, uiB, (int)N);
        { ushort_t* tmp = uiA; uiA = uiB; uiB = tmp; }

        // ---- HAN: users ----
        k_gather<<<cdiv_ll(U * 64, T), T, 0, stream>>>(rp_u1, ci_all, hu, n_u1s, n_u1r, z1, (int)U);
        k_gather<<<cdiv_ll(U * 64, T), T, 0, stream>>>(rp_u2, ci_all, hu, n_u2s, n_u2r, z2, (int)U);
        k_attn_mfma<<<ATTN_BLOCKS, T, 0, stream>>>(z1, z2, Wbu, wb1u, ww2u, (int)U, wsU);
        k_combine<<<cdiv_ll(U * 64, T), T, 0, stream>>>(z1, z2, wsU, 1.0f / (float)U, hu, U * 64);

        // ---- HAN: items ----
        k_gather<<<cdiv_ll(I * 64, T), T, 0, stream>>>(rp_i1, ci_all, hi, n_i1s, n_i1r, z1, (int)I);
        k_gather<<<cdiv_ll(I * 64, T), T, 0, stream>>>(rp_i2, ci_all, hi, n_i2s, n_i2r, z2, (int)I);
        k_attn_mfma<<<ATTN_BLOCKS, T, 0, stream>>>(z1, z2, Wbi, wb1i, ww2i, (int)I, wsI);
        k_combine<<<cdiv_ll(I * 64, T), T, 0, stream>>>(z1, z2, wsI, 1.0f / (float)I, hi, I * 64);
    }

    // ---------------- final ----------------
    k_out<<<cdiv_ll((ll)3 * B * 64, T), T, 0, stream>>>(hu, hi, uiA, user_idx, item_idx, neg_idx,
                                                        d_out, B, U, flag);
}